// Round 3
// baseline (2108.534 us; speedup 1.0000x reference)
//
#include <hip/hip_runtime.h>

#define NEG_SLOPE 0.1f
__device__ __forceinline__ float lrelu(float v) { return v >= 0.f ? v : NEG_SLOPE * v; }

constexpr int CAP = 8192;   // per-bucket capacity (mean 6330, sd ~80 -> +23 sigma)
constexpr int EPB = 4096;   // edges per bin block

// ---------------------------------------------------------------------------
// Encoder: per node, conv1d(3->9,k3,s2) + lrelu, conv1d(9->1,k3,s2) + lrelu,
// concat with pose -> x[N][40].  One block (64 threads) per node.
// ---------------------------------------------------------------------------
__global__ void encoder_kernel(const float* __restrict__ pose,
                               const float* __restrict__ views,
                               const float* __restrict__ w1, const float* __restrict__ b1,
                               const float* __restrict__ w2, const float* __restrict__ b2,
                               float* __restrict__ x)
{
    __shared__ float s_in[3 * 151];   // 453
    __shared__ float s_c1[9 * 75];    // 675
    __shared__ float s_w1[81];
    __shared__ float s_b1[9];
    __shared__ float s_w2[27];
    __shared__ float s_b2;

    const int n = blockIdx.x;
    const int t = threadIdx.x;

    for (int i = t; i < 453; i += 64) s_in[i] = views[n * 453 + i];
    for (int i = t; i < 81; i += 64)  s_w1[i] = w1[i];
    if (t < 9)  s_b1[t] = b1[t];
    if (t < 27) s_w2[t] = w2[t];
    if (t == 0) s_b2 = b2[0];
    __syncthreads();

    for (int i = t; i < 675; i += 64) {
        const int oc = i / 75, ow = i % 75;
        float v = s_b1[oc];
        #pragma unroll
        for (int ic = 0; ic < 3; ic++) {
            #pragma unroll
            for (int k = 0; k < 3; k++)
                v += s_in[ic * 151 + 2 * ow + k] * s_w1[oc * 9 + ic * 3 + k];
        }
        s_c1[i] = lrelu(v);
    }
    __syncthreads();

    if (t < 3) {
        x[n * 40 + t] = pose[n * 3 + t];
    } else if (t < 40) {
        const int ow = t - 3;
        float v = s_b2;
        #pragma unroll
        for (int ic = 0; ic < 9; ic++) {
            #pragma unroll
            for (int k = 0; k < 3; k++)
                v += s_c1[ic * 75 + 2 * ow + k] * s_w2[ic * 3 + k];
        }
        x[n * 40 + t] = lrelu(v);
    }
}

// ---------------------------------------------------------------------------
// Coarse binning: bucket = dst>>6 (64 nodes/bucket), fixed CAP-stride regions.
// Block-local LDS histogram gives local rank; ONE global atomic per
// (block,bucket) reserves a contiguous run; edges written as packed
// src | (dstLocal<<16) in ~5-edge runs (src < 65536 fits 16 bits).
// ---------------------------------------------------------------------------
__global__ void bin_kernel(const int* __restrict__ ei, int* __restrict__ gcur,
                           int* __restrict__ pairs, int E, int NB)
{
    __shared__ int s_hist[1024];
    __shared__ int s_base[1024];
    const int t = threadIdx.x;
    const int e0 = blockIdx.x * EPB;

    for (int i = t; i < NB; i += 256) s_hist[i] = 0;
    __syncthreads();

    int pk[16], mt[16];
    #pragma unroll
    for (int j = 0; j < 16; j++) {
        const int e = e0 + j * 256 + t;
        mt[j] = -1;
        if (e < E) {
            const int s = ei[e];
            const int d = ei[E + e];
            const int b = d >> 6;
            const int r = atomicAdd(&s_hist[b], 1);   // local rank, LDS atomic
            pk[j] = s | ((d & 63) << 16);
            mt[j] = b | (r << 10);                    // b<1024, r<4096
        }
    }
    __syncthreads();

    for (int i = t; i < NB; i += 256) {
        const int c = s_hist[i];
        if (c > 0) s_base[i] = atomicAdd(&gcur[i], c);
    }
    __syncthreads();

    #pragma unroll
    for (int j = 0; j < 16; j++) {
        if (mt[j] >= 0) {
            const int b = mt[j] & 1023;
            const int pos = s_base[b] + (mt[j] >> 10);
            if (pos < CAP) pairs[b * CAP + pos] = pk[j];
        }
    }
}

// ---------------------------------------------------------------------------
// Per-bucket segment sum: one block per bucket. 64x40 fp32 LDS tile; 4 waves
// stream edges (4-way unrolled), lanes 0..39 gather one coalesced 160B x-row
// per edge and LDS-atomicAdd into the dstLocal row. One coalesced store out.
// ---------------------------------------------------------------------------
__global__ void bucket_sum_kernel(const int* __restrict__ gcur,
                                  const int* __restrict__ pairs,
                                  const float* __restrict__ x,
                                  float* __restrict__ agg, int N)
{
    __shared__ float tile[64 * 40];
    const int b = blockIdx.x;
    const int t = threadIdx.x;
    const int cnt = min(gcur[b], CAP);

    for (int i = t; i < 2560; i += 256) tile[i] = 0.f;
    __syncthreads();

    const int wv = t >> 6, lane = t & 63;
    if (lane < 40) {
        const int* __restrict__ pr = pairs + b * CAP;
        const float* __restrict__ xl = x + lane;
        int e = (cnt * wv) >> 2;
        const int eend = (cnt * (wv + 1)) >> 2;
        for (; e + 4 <= eend; e += 4) {
            const int p0 = pr[e], p1 = pr[e + 1], p2 = pr[e + 2], p3 = pr[e + 3];
            const float v0 = xl[(p0 & 0xFFFF) * 40];
            const float v1 = xl[(p1 & 0xFFFF) * 40];
            const float v2 = xl[(p2 & 0xFFFF) * 40];
            const float v3 = xl[(p3 & 0xFFFF) * 40];
            atomicAdd(&tile[(p0 >> 16) * 40 + lane], v0);
            atomicAdd(&tile[(p1 >> 16) * 40 + lane], v1);
            atomicAdd(&tile[(p2 >> 16) * 40 + lane], v2);
            atomicAdd(&tile[(p3 >> 16) * 40 + lane], v3);
        }
        for (; e < eend; e++) {
            const int p = pr[e];
            atomicAdd(&tile[(p >> 16) * 40 + lane], xl[(p & 0xFFFF) * 40]);
        }
    }
    __syncthreads();

    const int base = b * 64 * 40;
    const int lim = N * 40;
    for (int i = t; i < 2560; i += 256)
        if (base + i < lim) agg[base + i] = tile[i];
}

// ---------------------------------------------------------------------------
// GraphConv: h = lrelu([agg|x] @ [w_rel|w_root]^T + b_rel), K=80 GEMM.
// ---------------------------------------------------------------------------
__global__ void graphconv_kernel(const float* __restrict__ agg,
                                 const float* __restrict__ x,
                                 const float* __restrict__ w_rel,
                                 const float* __restrict__ w_root,
                                 const float* __restrict__ b_rel,
                                 float* __restrict__ h, int N)
{
    __shared__ float s_A[80][68];
    __shared__ float s_W[80][68];

    const int t = threadIdx.x;
    const int n0 = blockIdx.x * 64;
    const int m0 = blockIdx.y * 64;

    for (int idx = t; idx < 64 * 40; idx += 256) {
        const int r = idx / 40, c = idx % 40;
        const int n = n0 + r;
        s_A[c][r]      = (n < N) ? agg[n * 40 + c] : 0.f;
        s_A[c + 40][r] = (n < N) ? x[n * 40 + c]   : 0.f;
    }
    for (int idx = t; idx < 64 * 40; idx += 256) {
        const int r = idx / 40, c = idx % 40;
        s_W[c][r]      = w_rel[(m0 + r) * 40 + c];
        s_W[c + 40][r] = w_root[(m0 + r) * 40 + c];
    }
    __syncthreads();

    const int tm = t % 16, tn = t / 16;
    float acc[4][4] = {};
    for (int k = 0; k < 80; k++) {
        const float4 a = *(const float4*)&s_A[k][tn * 4];
        const float4 w = *(const float4*)&s_W[k][tm * 4];
        const float av[4] = {a.x, a.y, a.z, a.w};
        const float wv[4] = {w.x, w.y, w.z, w.w};
        #pragma unroll
        for (int i = 0; i < 4; i++)
            #pragma unroll
            for (int j = 0; j < 4; j++)
                acc[i][j] += av[i] * wv[j];
    }

    #pragma unroll
    for (int i = 0; i < 4; i++) {
        const int n = n0 + tn * 4 + i;
        if (n >= N) continue;
        #pragma unroll
        for (int j = 0; j < 4; j++) {
            const int m = m0 + tm * 4 + j;
            h[n * 256 + m] = lrelu(acc[i][j] + b_rel[m]);
        }
    }
}

// ---------------------------------------------------------------------------
// MLP layer: C = lrelu(A @ W^T + b), A [N,256], W [256,256] (out-major).
// ---------------------------------------------------------------------------
__global__ void mlp_kernel(const float* __restrict__ A,
                           const float* __restrict__ W,
                           const float* __restrict__ b,
                           float* __restrict__ C, int N)
{
    __shared__ float s_A[64][68];
    __shared__ float s_W[64][68];

    const int t = threadIdx.x;
    const int n0 = blockIdx.x * 64;
    const int m0 = blockIdx.y * 64;
    const int tm = t % 16, tn = t / 16;

    float acc[4][4] = {};
    for (int kc = 0; kc < 256; kc += 64) {
        __syncthreads();
        for (int idx = t; idx < 64 * 64; idx += 256) {
            const int r = idx / 64, c = idx % 64;
            const int n = n0 + r;
            s_A[c][r] = (n < N) ? A[n * 256 + kc + c] : 0.f;
            s_W[c][r] = W[(m0 + r) * 256 + kc + c];
        }
        __syncthreads();
        #pragma unroll 4
        for (int k = 0; k < 64; k++) {
            const float4 a = *(const float4*)&s_A[k][tn * 4];
            const float4 w = *(const float4*)&s_W[k][tm * 4];
            const float av[4] = {a.x, a.y, a.z, a.w};
            const float wv[4] = {w.x, w.y, w.z, w.w};
            #pragma unroll
            for (int i = 0; i < 4; i++)
                #pragma unroll
                for (int j = 0; j < 4; j++)
                    acc[i][j] += av[i] * wv[j];
        }
    }

    #pragma unroll
    for (int i = 0; i < 4; i++) {
        const int n = n0 + tn * 4 + i;
        if (n >= N) continue;
        #pragma unroll
        for (int j = 0; j < 4; j++) {
            const int m = m0 + tm * 4 + j;
            C[n * 256 + m] = lrelu(acc[i][j] + b[m]);
        }
    }
}

// ---------------------------------------------------------------------------
// Pred: out[n] = h[n] . w_pred + b_pred.  One wave per node (4 waves/block).
// ---------------------------------------------------------------------------
__global__ void pred_kernel(const float* __restrict__ h,
                            const float* __restrict__ w,
                            const float* __restrict__ b,
                            float* __restrict__ out, int N)
{
    __shared__ float s_w[256];
    const int t = threadIdx.x;
    s_w[t] = w[t];
    __syncthreads();

    const int wave = t / 64, lane = t % 64;
    const int n = blockIdx.x * 4 + wave;
    if (n >= N) return;

    float v = 0.f;
    #pragma unroll
    for (int j = 0; j < 4; j++)
        v += h[n * 256 + lane + j * 64] * s_w[lane + j * 64];

    #pragma unroll
    for (int off = 32; off > 0; off >>= 1)
        v += __shfl_down(v, off);

    if (lane == 0) out[n] = v + b[0];
}

// ---------------------------------------------------------------------------
extern "C" void kernel_launch(void* const* d_in, const int* in_sizes, int n_in,
                              void* d_out, int out_size, void* d_ws, size_t ws_size,
                              hipStream_t stream)
{
    const float* pose   = (const float*)d_in[0];
    const float* views  = (const float*)d_in[1];
    const int*   ei     = (const int*)d_in[2];
    const float* w_e1   = (const float*)d_in[3];
    const float* b_e1   = (const float*)d_in[4];
    const float* w_e2   = (const float*)d_in[5];
    const float* b_e2   = (const float*)d_in[6];
    const float* w_rel  = (const float*)d_in[7];
    const float* b_rel  = (const float*)d_in[8];
    const float* w_root = (const float*)d_in[9];
    const float* w_l1   = (const float*)d_in[10];
    const float* b_l1   = (const float*)d_in[11];
    const float* w_l2   = (const float*)d_in[12];
    const float* b_l2   = (const float*)d_in[13];
    const float* w_l3   = (const float*)d_in[14];
    const float* b_l3   = (const float*)d_in[15];
    const float* w_pred = (const float*)d_in[16];
    const float* b_pred = (const float*)d_in[17];
    float* out = (float*)d_out;

    const int N = in_sizes[0] / 3;       // 50000
    const int E = in_sizes[2] / 2;       // 4950000
    const int NB = (N + 63) >> 6;        // 782 buckets

    // Workspace layout. pairs/gcur alias h0/h1 (dead before graphconv writes).
    float* x   = (float*)d_ws;            // N*40 floats
    float* agg = x + (size_t)N * 40;      // N*40 floats
    float* h0  = agg + (size_t)N * 40;    // N*256 floats
    float* h1  = h0 + (size_t)N * 256;    // N*256 floats
    int* pairs = (int*)h0;                // NB*CAP ints = 25.6MB < 51.2MB
    int* gcur  = (int*)h1;                // NB ints

    encoder_kernel<<<N, 64, 0, stream>>>(pose, views, w_e1, b_e1, w_e2, b_e2, x);

    hipMemsetAsync(gcur, 0, (size_t)NB * sizeof(int), stream);
    bin_kernel<<<(E + EPB - 1) / EPB, 256, 0, stream>>>(ei, gcur, pairs, E, NB);
    bucket_sum_kernel<<<NB, 256, 0, stream>>>(gcur, pairs, x, agg, N);

    dim3 gtile((N + 63) / 64, 4);
    graphconv_kernel<<<gtile, 256, 0, stream>>>(agg, x, w_rel, w_root, b_rel, h0, N);
    mlp_kernel<<<gtile, 256, 0, stream>>>(h0, w_l1, b_l1, h1, N);
    mlp_kernel<<<gtile, 256, 0, stream>>>(h1, w_l2, b_l2, h0, N);
    mlp_kernel<<<gtile, 256, 0, stream>>>(h0, w_l3, b_l3, h1, N);
    pred_kernel<<<(N + 3) / 4, 256, 0, stream>>>(h1, w_pred, b_pred, out, N);
}

// Round 4
// 918.566 us; speedup vs baseline: 2.2955x; 2.2955x over previous
//
#include <hip/hip_runtime.h>

#define NEG_SLOPE 0.1f
__device__ __forceinline__ float lrelu(float v) { return v >= 0.f ? v : NEG_SLOPE * v; }

constexpr int CAP = 8192;   // per-bucket capacity (mean 6330, sd ~80)
constexpr int EPB = 4096;   // edges per bin block (16 per thread, contiguous)

// ---------------------------------------------------------------------------
// Encoder: per node, conv1d(3->9,k3,s2) + lrelu, conv1d(9->1,k3,s2) + lrelu,
// concat with pose -> x[N][40].  One block (64 threads) per node.
// ---------------------------------------------------------------------------
__global__ void encoder_kernel(const float* __restrict__ pose,
                               const float* __restrict__ views,
                               const float* __restrict__ w1, const float* __restrict__ b1,
                               const float* __restrict__ w2, const float* __restrict__ b2,
                               float* __restrict__ x)
{
    __shared__ float s_in[3 * 151];
    __shared__ float s_c1[9 * 75];
    __shared__ float s_w1[81];
    __shared__ float s_b1[9];
    __shared__ float s_w2[27];
    __shared__ float s_b2;

    const int n = blockIdx.x;
    const int t = threadIdx.x;

    for (int i = t; i < 453; i += 64) s_in[i] = views[n * 453 + i];
    for (int i = t; i < 81; i += 64)  s_w1[i] = w1[i];
    if (t < 9)  s_b1[t] = b1[t];
    if (t < 27) s_w2[t] = w2[t];
    if (t == 0) s_b2 = b2[0];
    __syncthreads();

    for (int i = t; i < 675; i += 64) {
        const int oc = i / 75, ow = i % 75;
        float v = s_b1[oc];
        #pragma unroll
        for (int ic = 0; ic < 3; ic++) {
            #pragma unroll
            for (int k = 0; k < 3; k++)
                v += s_in[ic * 151 + 2 * ow + k] * s_w1[oc * 9 + ic * 3 + k];
        }
        s_c1[i] = lrelu(v);
    }
    __syncthreads();

    if (t < 3) {
        x[n * 40 + t] = pose[n * 3 + t];
    } else if (t < 40) {
        const int ow = t - 3;
        float v = s_b2;
        #pragma unroll
        for (int ic = 0; ic < 9; ic++) {
            #pragma unroll
            for (int k = 0; k < 3; k++)
                v += s_c1[ic * 75 + 2 * ow + k] * s_w2[ic * 3 + k];
        }
        x[n * 40 + t] = lrelu(v);
    }
}

// ---------------------------------------------------------------------------
// Coarse binning: bucket = dst>>6. Block LDS-histograms 4096 contiguous edges
// (int4-vectorized loads, 16/thread), reserves per-(block,bucket) runs with
// ONE global atomic, writes packed src|dstLocal<<16.
// ---------------------------------------------------------------------------
__global__ void bin_kernel(const int* __restrict__ ei, int* __restrict__ gcur,
                           int* __restrict__ pairs, int E, int NB)
{
    __shared__ int s_hist[1024];
    __shared__ int s_base[1024];
    const int t = threadIdx.x;
    const int e0 = blockIdx.x * EPB + t * 16;

    for (int i = t; i < NB; i += 256) s_hist[i] = 0;
    __syncthreads();

    int pk[16], mt[16];
    auto proc = [&](int j, int sv, int dv) {
        const int b = dv >> 6;
        const int r = atomicAdd(&s_hist[b], 1);   // local rank (LDS atomic)
        pk[j] = sv | ((dv & 63) << 16);
        mt[j] = b | (r << 10);                    // b<1024, r<4096
    };

    if (e0 + 16 <= E) {
        #pragma unroll
        for (int q = 0; q < 4; q++) {
            const int4 sv = *(const int4*)(ei + e0 + 4 * q);
            const int4 dv = *(const int4*)(ei + E + e0 + 4 * q);
            proc(4 * q + 0, sv.x, dv.x);
            proc(4 * q + 1, sv.y, dv.y);
            proc(4 * q + 2, sv.z, dv.z);
            proc(4 * q + 3, sv.w, dv.w);
        }
    } else {
        #pragma unroll
        for (int j = 0; j < 16; j++) {
            mt[j] = -1;
            const int e = e0 + j;
            if (e < E) proc(j, ei[e], ei[E + e]);
        }
    }
    __syncthreads();

    for (int i = t; i < NB; i += 256) {
        const int c = s_hist[i];
        if (c > 0) s_base[i] = atomicAdd(&gcur[i], c);
    }
    __syncthreads();

    #pragma unroll
    for (int j = 0; j < 16; j++) {
        if (mt[j] >= 0) {
            const int b = mt[j] & 1023;
            const int pos = s_base[b] + (mt[j] >> 10);
            if (pos < CAP) pairs[b * CAP + pos] = pk[j];
        }
    }
}

// ---------------------------------------------------------------------------
// Per-bucket exact counting sort (no global atomics). One block per bucket:
// LDS hist over 64 local nodes -> wave-shuffle exclusive scan (runs 8-aligned,
// pads filled with src=0 sentinels) -> scatter src ids into per-node runs.
// Emits node_start/node_cnt for the gather.
// ---------------------------------------------------------------------------
__global__ void bucket_sort_kernel(const int* __restrict__ gcur,
                                   const int* __restrict__ pairs,
                                   int* __restrict__ sorted,
                                   int* __restrict__ node_start,
                                   int* __restrict__ node_cnt)
{
    __shared__ int s_cnt[64], s_off[64], s_cur[64];
    const int b = blockIdx.x;
    const int t = threadIdx.x;
    const int cnt = min(gcur[b], CAP);
    const int* __restrict__ pr = pairs + b * CAP;
    int* __restrict__ so = sorted + (size_t)b * CAP;

    if (t < 64) s_cnt[t] = 0;
    __syncthreads();
    for (int i = t; i < cnt; i += 256)
        atomicAdd(&s_cnt[pr[i] >> 16], 1);
    __syncthreads();

    if (t < 64) {   // wave 0: exclusive scan of 8-aligned counts
        const int c = s_cnt[t];
        const int p = (c + 7) & ~7;
        int sc = p;
        #pragma unroll
        for (int d = 1; d < 64; d <<= 1) {
            const int u = __shfl_up(sc, d);
            if (t >= d) sc += u;
        }
        const int excl = sc - p;
        s_off[t] = excl;
        s_cur[t] = excl;
        node_start[b * 64 + t] = b * CAP + excl;
        node_cnt[b * 64 + t] = c;
    }
    __syncthreads();

    if (t < 64) {   // pad fill: sentinel src=0 (masked out by gather)
        const int e0 = s_off[t] + s_cnt[t];
        const int e1 = s_off[t] + ((s_cnt[t] + 7) & ~7);
        for (int i = e0; i < e1 && i < CAP; i++) so[i] = 0;
    }
    for (int i = t; i < cnt; i += 256) {
        const int p = pr[i];
        const int pos = atomicAdd(&s_cur[p >> 16], 1);
        if (pos < CAP) so[pos] = p & 0xFFFF;
    }
}

// ---------------------------------------------------------------------------
// Atomic-free segment sum: one wave per node (50k waves). Lanes 0..39 own one
// feature; 8 outstanding coalesced 160B x-row gathers per iter; src indices
// come 8-at-a-time via two aligned int4 broadcast loads.
// ---------------------------------------------------------------------------
__global__ void gather_sum_kernel(const int* __restrict__ sorted,
                                  const int* __restrict__ node_start,
                                  const int* __restrict__ node_cnt,
                                  const float* __restrict__ x,
                                  float* __restrict__ agg, int N)
{
    const int n = blockIdx.x * 4 + (threadIdx.x >> 6);
    const int lane = threadIdx.x & 63;
    if (n >= N || lane >= 40) return;

    const int start = node_start[n];
    const int cnt = node_cnt[n];
    const int* __restrict__ srt = sorted + start;
    const float* __restrict__ xl = x + lane;

    float acc = 0.f;
    const int full = cnt & ~7;
    int e = 0;
    for (; e < full; e += 8) {
        const int4 i0 = *(const int4*)(srt + e);
        const int4 i1 = *(const int4*)(srt + e + 4);
        const float v0 = xl[i0.x * 40], v1 = xl[i0.y * 40];
        const float v2 = xl[i0.z * 40], v3 = xl[i0.w * 40];
        const float v4 = xl[i1.x * 40], v5 = xl[i1.y * 40];
        const float v6 = xl[i1.z * 40], v7 = xl[i1.w * 40];
        acc += ((v0 + v1) + (v2 + v3)) + ((v4 + v5) + (v6 + v7));
    }
    if (e < cnt) {   // one masked tail iter; pads are valid sentinel src=0
        const int4 i0 = *(const int4*)(srt + e);
        const int4 i1 = *(const int4*)(srt + e + 4);
        const float v0 = xl[i0.x * 40], v1 = xl[i0.y * 40];
        const float v2 = xl[i0.z * 40], v3 = xl[i0.w * 40];
        const float v4 = xl[i1.x * 40], v5 = xl[i1.y * 40];
        const float v6 = xl[i1.z * 40], v7 = xl[i1.w * 40];
        acc += (e + 0 < cnt ? v0 : 0.f) + (e + 1 < cnt ? v1 : 0.f)
             + (e + 2 < cnt ? v2 : 0.f) + (e + 3 < cnt ? v3 : 0.f)
             + (e + 4 < cnt ? v4 : 0.f) + (e + 5 < cnt ? v5 : 0.f)
             + (e + 6 < cnt ? v6 : 0.f) + (e + 7 < cnt ? v7 : 0.f);
    }
    agg[n * 40 + lane] = acc;
}

// ---------------------------------------------------------------------------
// GraphConv: h = lrelu([agg|x] @ [w_rel|w_root]^T + b_rel), K=80 GEMM.
// ---------------------------------------------------------------------------
__global__ void graphconv_kernel(const float* __restrict__ agg,
                                 const float* __restrict__ x,
                                 const float* __restrict__ w_rel,
                                 const float* __restrict__ w_root,
                                 const float* __restrict__ b_rel,
                                 float* __restrict__ h, int N)
{
    __shared__ float s_A[80][68];
    __shared__ float s_W[80][68];

    const int t = threadIdx.x;
    const int n0 = blockIdx.x * 64;
    const int m0 = blockIdx.y * 64;

    for (int idx = t; idx < 64 * 40; idx += 256) {
        const int r = idx / 40, c = idx % 40;
        const int n = n0 + r;
        s_A[c][r]      = (n < N) ? agg[n * 40 + c] : 0.f;
        s_A[c + 40][r] = (n < N) ? x[n * 40 + c]   : 0.f;
    }
    for (int idx = t; idx < 64 * 40; idx += 256) {
        const int r = idx / 40, c = idx % 40;
        s_W[c][r]      = w_rel[(m0 + r) * 40 + c];
        s_W[c + 40][r] = w_root[(m0 + r) * 40 + c];
    }
    __syncthreads();

    const int tm = t % 16, tn = t / 16;
    float acc[4][4] = {};
    for (int k = 0; k < 80; k++) {
        const float4 a = *(const float4*)&s_A[k][tn * 4];
        const float4 w = *(const float4*)&s_W[k][tm * 4];
        const float av[4] = {a.x, a.y, a.z, a.w};
        const float wv[4] = {w.x, w.y, w.z, w.w};
        #pragma unroll
        for (int i = 0; i < 4; i++)
            #pragma unroll
            for (int j = 0; j < 4; j++)
                acc[i][j] += av[i] * wv[j];
    }

    #pragma unroll
    for (int i = 0; i < 4; i++) {
        const int n = n0 + tn * 4 + i;
        if (n >= N) continue;
        #pragma unroll
        for (int j = 0; j < 4; j++) {
            const int m = m0 + tm * 4 + j;
            h[n * 256 + m] = lrelu(acc[i][j] + b_rel[m]);
        }
    }
}

// ---------------------------------------------------------------------------
// MLP layer: C = lrelu(A @ W^T + b), A [N,256], W [256,256] (out-major).
// ---------------------------------------------------------------------------
__global__ void mlp_kernel(const float* __restrict__ A,
                           const float* __restrict__ W,
                           const float* __restrict__ b,
                           float* __restrict__ C, int N)
{
    __shared__ float s_A[64][68];
    __shared__ float s_W[64][68];

    const int t = threadIdx.x;
    const int n0 = blockIdx.x * 64;
    const int m0 = blockIdx.y * 64;
    const int tm = t % 16, tn = t / 16;

    float acc[4][4] = {};
    for (int kc = 0; kc < 256; kc += 64) {
        __syncthreads();
        for (int idx = t; idx < 64 * 64; idx += 256) {
            const int r = idx / 64, c = idx % 64;
            const int n = n0 + r;
            s_A[c][r] = (n < N) ? A[n * 256 + kc + c] : 0.f;
            s_W[c][r] = W[(m0 + r) * 256 + kc + c];
        }
        __syncthreads();
        #pragma unroll 4
        for (int k = 0; k < 64; k++) {
            const float4 a = *(const float4*)&s_A[k][tn * 4];
            const float4 w = *(const float4*)&s_W[k][tm * 4];
            const float av[4] = {a.x, a.y, a.z, a.w};
            const float wv[4] = {w.x, w.y, w.z, w.w};
            #pragma unroll
            for (int i = 0; i < 4; i++)
                #pragma unroll
                for (int j = 0; j < 4; j++)
                    acc[i][j] += av[i] * wv[j];
        }
    }

    #pragma unroll
    for (int i = 0; i < 4; i++) {
        const int n = n0 + tn * 4 + i;
        if (n >= N) continue;
        #pragma unroll
        for (int j = 0; j < 4; j++) {
            const int m = m0 + tm * 4 + j;
            C[n * 256 + m] = lrelu(acc[i][j] + b[m]);
        }
    }
}

// ---------------------------------------------------------------------------
// Pred: out[n] = h[n] . w_pred + b_pred.  One wave per node (4 waves/block).
// ---------------------------------------------------------------------------
__global__ void pred_kernel(const float* __restrict__ h,
                            const float* __restrict__ w,
                            const float* __restrict__ b,
                            float* __restrict__ out, int N)
{
    __shared__ float s_w[256];
    const int t = threadIdx.x;
    s_w[t] = w[t];
    __syncthreads();

    const int wave = t / 64, lane = t % 64;
    const int n = blockIdx.x * 4 + wave;
    if (n >= N) return;

    float v = 0.f;
    #pragma unroll
    for (int j = 0; j < 4; j++)
        v += h[n * 256 + lane + j * 64] * s_w[lane + j * 64];

    #pragma unroll
    for (int off = 32; off > 0; off >>= 1)
        v += __shfl_down(v, off);

    if (lane == 0) out[n] = v + b[0];
}

// ---------------------------------------------------------------------------
extern "C" void kernel_launch(void* const* d_in, const int* in_sizes, int n_in,
                              void* d_out, int out_size, void* d_ws, size_t ws_size,
                              hipStream_t stream)
{
    const float* pose   = (const float*)d_in[0];
    const float* views  = (const float*)d_in[1];
    const int*   ei     = (const int*)d_in[2];
    const float* w_e1   = (const float*)d_in[3];
    const float* b_e1   = (const float*)d_in[4];
    const float* w_e2   = (const float*)d_in[5];
    const float* b_e2   = (const float*)d_in[6];
    const float* w_rel  = (const float*)d_in[7];
    const float* b_rel  = (const float*)d_in[8];
    const float* w_root = (const float*)d_in[9];
    const float* w_l1   = (const float*)d_in[10];
    const float* b_l1   = (const float*)d_in[11];
    const float* w_l2   = (const float*)d_in[12];
    const float* b_l2   = (const float*)d_in[13];
    const float* w_l3   = (const float*)d_in[14];
    const float* b_l3   = (const float*)d_in[15];
    const float* w_pred = (const float*)d_in[16];
    const float* b_pred = (const float*)d_in[17];
    float* out = (float*)d_out;

    const int N = in_sizes[0] / 3;       // 50000
    const int E = in_sizes[2] / 2;       // 4950000
    const int NB = (N + 63) >> 6;        // 782 buckets

    // Workspace. Graph-int scratch lives inside the h0+h1 region (102.4 MB)
    // and is fully consumed before graphconv/mlp write h0/h1.
    float* x   = (float*)d_ws;            // N*40
    float* agg = x + (size_t)N * 40;      // N*40
    float* h0  = agg + (size_t)N * 40;    // N*256
    float* h1  = h0 + (size_t)N * 256;    // N*256
    int* pairs      = (int*)h0;                       // NB*CAP (25.6 MB)
    int* sorted     = pairs + (size_t)NB * CAP;       // NB*CAP (25.6 MB)
    int* gcur       = sorted + (size_t)NB * CAP;      // NB
    int* node_start = gcur + 1024;                    // NB*64
    int* node_cnt   = node_start + NB * 64;           // NB*64   (~51.7 MB total)

    encoder_kernel<<<N, 64, 0, stream>>>(pose, views, w_e1, b_e1, w_e2, b_e2, x);

    hipMemsetAsync(gcur, 0, (size_t)NB * sizeof(int), stream);
    bin_kernel<<<(E + EPB - 1) / EPB, 256, 0, stream>>>(ei, gcur, pairs, E, NB);
    bucket_sort_kernel<<<NB, 256, 0, stream>>>(gcur, pairs, sorted, node_start, node_cnt);
    gather_sum_kernel<<<NB * 16, 256, 0, stream>>>(sorted, node_start, node_cnt, x, agg, N);

    dim3 gtile((N + 63) / 64, 4);
    graphconv_kernel<<<gtile, 256, 0, stream>>>(agg, x, w_rel, w_root, b_rel, h0, N);
    mlp_kernel<<<gtile, 256, 0, stream>>>(h0, w_l1, b_l1, h1, N);
    mlp_kernel<<<gtile, 256, 0, stream>>>(h1, w_l2, b_l2, h0, N);
    mlp_kernel<<<gtile, 256, 0, stream>>>(h0, w_l3, b_l3, h1, N);
    pred_kernel<<<(N + 3) / 4, 256, 0, stream>>>(h1, w_pred, b_pred, out, N);
}

// Round 5
// 524.310 us; speedup vs baseline: 4.0215x; 1.7520x over previous
//
#include <hip/hip_runtime.h>

#define NEG_SLOPE 0.1f
__device__ __forceinline__ float lrelu(float v) { return v >= 0.f ? v : NEG_SLOPE * v; }

constexpr int CAP = 8192;   // per-bucket capacity (mean 6330, sd ~80)
constexpr int EPB = 4096;   // edges per bin block (16 per thread, contiguous)

typedef __attribute__((ext_vector_type(8))) short short8;   // 8 bf16 (4 VGPRs)
typedef __attribute__((ext_vector_type(4))) float f32x4;    // MFMA accum

__device__ __forceinline__ unsigned short f2bf(float f) {   // RNE
    union { float f; unsigned u; } v; v.f = f;
    const unsigned r = v.u + 0x7FFF + ((v.u >> 16) & 1);
    return (unsigned short)(r >> 16);
}
__device__ __forceinline__ float bf2f(unsigned short h) {
    union { unsigned u; float f; } v; v.u = ((unsigned)h) << 16;
    return v.f;
}

// ---------------------------------------------------------------------------
// Weight prep: fp32 -> bf16 (per call; no cross-call state allowed).
// ---------------------------------------------------------------------------
__global__ void cvt_bf16_kernel(const float* __restrict__ src, unsigned short* __restrict__ dst, int n)
{
    const int i = blockIdx.x * blockDim.x + threadIdx.x;
    if (i < n) dst[i] = f2bf(src[i]);
}

// Wg[256][160] = [w_rel | w_root | w_rel | w_root] bf16 (hi/lo A-split shares W).
__global__ void build_wg_kernel(const float* __restrict__ w_rel, const float* __restrict__ w_root,
                                unsigned short* __restrict__ Wg)
{
    const int i = blockIdx.x * blockDim.x + threadIdx.x;
    if (i >= 256 * 160) return;
    const int m = i / 160, c = i % 160;
    const int cc = c & 63 ? c % 80 : c % 80;  // (kept simple below)
    float v;
    const int k = c % 80;
    v = (k < 40) ? w_rel[m * 40 + k] : w_root[m * 40 + (k - 40)];
    Wg[i] = f2bf(v);
}

// ---------------------------------------------------------------------------
// Encoder: per node, conv1d(3->9,k3,s2)+lrelu, conv1d(9->1,k3,s2)+lrelu,
// concat pose -> x[N][40] fp32.  One block (64 threads) per node.
// ---------------------------------------------------------------------------
__global__ void encoder_kernel(const float* __restrict__ pose,
                               const float* __restrict__ views,
                               const float* __restrict__ w1, const float* __restrict__ b1,
                               const float* __restrict__ w2, const float* __restrict__ b2,
                               float* __restrict__ x)
{
    __shared__ float s_in[3 * 151];
    __shared__ float s_c1[9 * 75];
    __shared__ float s_w1[81];
    __shared__ float s_b1[9];
    __shared__ float s_w2[27];
    __shared__ float s_b2;

    const int n = blockIdx.x;
    const int t = threadIdx.x;

    for (int i = t; i < 453; i += 64) s_in[i] = views[n * 453 + i];
    for (int i = t; i < 81; i += 64)  s_w1[i] = w1[i];
    if (t < 9)  s_b1[t] = b1[t];
    if (t < 27) s_w2[t] = w2[t];
    if (t == 0) s_b2 = b2[0];
    __syncthreads();

    for (int i = t; i < 675; i += 64) {
        const int oc = i / 75, ow = i % 75;
        float v = s_b1[oc];
        #pragma unroll
        for (int ic = 0; ic < 3; ic++) {
            #pragma unroll
            for (int k = 0; k < 3; k++)
                v += s_in[ic * 151 + 2 * ow + k] * s_w1[oc * 9 + ic * 3 + k];
        }
        s_c1[i] = lrelu(v);
    }
    __syncthreads();

    if (t < 3) {
        x[n * 40 + t] = pose[n * 3 + t];
    } else if (t < 40) {
        const int ow = t - 3;
        float v = s_b2;
        #pragma unroll
        for (int ic = 0; ic < 9; ic++) {
            #pragma unroll
            for (int k = 0; k < 3; k++)
                v += s_c1[ic * 75 + 2 * ow + k] * s_w2[ic * 3 + k];
        }
        x[n * 40 + t] = lrelu(v);
    }
}

// ---------------------------------------------------------------------------
// Coarse binning: bucket = dst>>6, packed src|dstLocal<<16, one global atomic
// per (block,bucket).
// ---------------------------------------------------------------------------
__global__ void bin_kernel(const int* __restrict__ ei, int* __restrict__ gcur,
                           int* __restrict__ pairs, int E, int NB)
{
    __shared__ int s_hist[1024];
    __shared__ int s_base[1024];
    const int t = threadIdx.x;
    const int e0 = blockIdx.x * EPB + t * 16;

    for (int i = t; i < NB; i += 256) s_hist[i] = 0;
    __syncthreads();

    int pk[16], mt[16];
    auto proc = [&](int j, int sv, int dv) {
        const int b = dv >> 6;
        const int r = atomicAdd(&s_hist[b], 1);
        pk[j] = sv | ((dv & 63) << 16);
        mt[j] = b | (r << 10);
    };

    if (e0 + 16 <= E) {
        #pragma unroll
        for (int q = 0; q < 4; q++) {
            const int4 sv = *(const int4*)(ei + e0 + 4 * q);
            const int4 dv = *(const int4*)(ei + E + e0 + 4 * q);
            proc(4 * q + 0, sv.x, dv.x);
            proc(4 * q + 1, sv.y, dv.y);
            proc(4 * q + 2, sv.z, dv.z);
            proc(4 * q + 3, sv.w, dv.w);
        }
    } else {
        #pragma unroll
        for (int j = 0; j < 16; j++) {
            mt[j] = -1;
            const int e = e0 + j;
            if (e < E) proc(j, ei[e], ei[E + e]);
        }
    }
    __syncthreads();

    for (int i = t; i < NB; i += 256) {
        const int c = s_hist[i];
        if (c > 0) s_base[i] = atomicAdd(&gcur[i], c);
    }
    __syncthreads();

    #pragma unroll
    for (int j = 0; j < 16; j++) {
        if (mt[j] >= 0) {
            const int b = mt[j] & 1023;
            const int pos = s_base[b] + (mt[j] >> 10);
            if (pos < CAP) pairs[b * CAP + pos] = pk[j];
        }
    }
}

// ---------------------------------------------------------------------------
// Per-bucket exact counting sort (LDS only), 8-aligned runs with src=0 pads.
// ---------------------------------------------------------------------------
__global__ void bucket_sort_kernel(const int* __restrict__ gcur,
                                   const int* __restrict__ pairs,
                                   int* __restrict__ sorted,
                                   int* __restrict__ node_start,
                                   int* __restrict__ node_cnt)
{
    __shared__ int s_cnt[64], s_off[64], s_cur[64];
    const int b = blockIdx.x;
    const int t = threadIdx.x;
    const int cnt = min(gcur[b], CAP);
    const int* __restrict__ pr = pairs + b * CAP;
    int* __restrict__ so = sorted + (size_t)b * CAP;

    if (t < 64) s_cnt[t] = 0;
    __syncthreads();
    for (int i = t; i < cnt; i += 256)
        atomicAdd(&s_cnt[pr[i] >> 16], 1);
    __syncthreads();

    if (t < 64) {
        const int c = s_cnt[t];
        const int p = (c + 7) & ~7;
        int sc = p;
        #pragma unroll
        for (int d = 1; d < 64; d <<= 1) {
            const int u = __shfl_up(sc, d);
            if (t >= d) sc += u;
        }
        const int excl = sc - p;
        s_off[t] = excl;
        s_cur[t] = excl;
        node_start[b * 64 + t] = b * CAP + excl;
        node_cnt[b * 64 + t] = c;
    }
    __syncthreads();

    if (t < 64) {
        const int e0 = s_off[t] + s_cnt[t];
        const int e1 = s_off[t] + ((s_cnt[t] + 7) & ~7);
        for (int i = e0; i < e1 && i < CAP; i++) so[i] = 0;
    }
    for (int i = t; i < cnt; i += 256) {
        const int p = pr[i];
        const int pos = atomicAdd(&s_cur[p >> 16], 1);
        if (pos < CAP) so[pos] = p & 0xFFFF;
    }
}

// ---------------------------------------------------------------------------
// Atomic-free segment sum: one wave per node, 8 outstanding 160B row gathers.
// ---------------------------------------------------------------------------
__global__ void gather_sum_kernel(const int* __restrict__ sorted,
                                  const int* __restrict__ node_start,
                                  const int* __restrict__ node_cnt,
                                  const float* __restrict__ x,
                                  float* __restrict__ agg, int N)
{
    const int n = blockIdx.x * 4 + (threadIdx.x >> 6);
    const int lane = threadIdx.x & 63;
    if (n >= N || lane >= 40) return;

    const int start = node_start[n];
    const int cnt = node_cnt[n];
    const int* __restrict__ srt = sorted + start;
    const float* __restrict__ xl = x + lane;

    float acc = 0.f;
    const int full = cnt & ~7;
    int e = 0;
    for (; e < full; e += 8) {
        const int4 i0 = *(const int4*)(srt + e);
        const int4 i1 = *(const int4*)(srt + e + 4);
        const float v0 = xl[i0.x * 40], v1 = xl[i0.y * 40];
        const float v2 = xl[i0.z * 40], v3 = xl[i0.w * 40];
        const float v4 = xl[i1.x * 40], v5 = xl[i1.y * 40];
        const float v6 = xl[i1.z * 40], v7 = xl[i1.w * 40];
        acc += ((v0 + v1) + (v2 + v3)) + ((v4 + v5) + (v6 + v7));
    }
    if (e < cnt) {
        const int4 i0 = *(const int4*)(srt + e);
        const int4 i1 = *(const int4*)(srt + e + 4);
        const float v0 = xl[i0.x * 40], v1 = xl[i0.y * 40];
        const float v2 = xl[i0.z * 40], v3 = xl[i0.w * 40];
        const float v4 = xl[i1.x * 40], v5 = xl[i1.y * 40];
        const float v6 = xl[i1.z * 40], v7 = xl[i1.w * 40];
        acc += (e + 0 < cnt ? v0 : 0.f) + (e + 1 < cnt ? v1 : 0.f)
             + (e + 2 < cnt ? v2 : 0.f) + (e + 3 < cnt ? v3 : 0.f)
             + (e + 4 < cnt ? v4 : 0.f) + (e + 5 < cnt ? v5 : 0.f)
             + (e + 6 < cnt ? v6 : 0.f) + (e + 7 < cnt ? v7 : 0.f);
    }
    agg[n * 40 + lane] = acc;
}

// ---------------------------------------------------------------------------
// GraphConv via MFMA, K=160: A = [agg_hi|x_hi|agg_lo|x_lo] bf16 (hi/lo split
// for near-fp32 A-side), W = [w_rel|w_root|w_rel|w_root] bf16.
// Block: 256 thr = 4 waves; 64 rows x 256 cols; wave = 64 cols, 4x4 MFMA acc.
// ---------------------------------------------------------------------------
__global__ void graphconv_mfma_kernel(const float* __restrict__ agg,
                                      const float* __restrict__ x,
                                      const unsigned short* __restrict__ Wg,
                                      const float* __restrict__ b,
                                      unsigned short* __restrict__ C, int N)
{
    __shared__ __align__(16) unsigned short aT[64 * 168];  // 168 = 160 + 8 pad
    const int t = threadIdx.x;
    const int n0 = blockIdx.x * 64;
    const int wave = t >> 6, lane = t & 63, q = lane >> 4, l16 = lane & 15;

    for (int u = t; u < 640; u += 256) {
        const int row = u / 10, c = (u % 10) * 4;
        const int srow = min(n0 + row, N - 1);
        const float4 fa = *(const float4*)(agg + (size_t)srow * 40 + c);
        const float4 fx = *(const float4*)(x + (size_t)srow * 40 + c);
        const float av[4] = {fa.x, fa.y, fa.z, fa.w};
        const float xv[4] = {fx.x, fx.y, fx.z, fx.w};
        ushort4 ha, la, hx, lx;
        ha.x = f2bf(av[0]); la.x = f2bf(av[0] - bf2f(ha.x));
        ha.y = f2bf(av[1]); la.y = f2bf(av[1] - bf2f(ha.y));
        ha.z = f2bf(av[2]); la.z = f2bf(av[2] - bf2f(ha.z));
        ha.w = f2bf(av[3]); la.w = f2bf(av[3] - bf2f(ha.w));
        hx.x = f2bf(xv[0]); lx.x = f2bf(xv[0] - bf2f(hx.x));
        hx.y = f2bf(xv[1]); lx.y = f2bf(xv[1] - bf2f(hx.y));
        hx.z = f2bf(xv[2]); lx.z = f2bf(xv[2] - bf2f(hx.z));
        hx.w = f2bf(xv[3]); lx.w = f2bf(xv[3] - bf2f(hx.w));
        unsigned short* rp = aT + row * 168;
        *(ushort4*)(rp + c)       = ha;
        *(ushort4*)(rp + 40 + c)  = hx;
        *(ushort4*)(rp + 80 + c)  = la;
        *(ushort4*)(rp + 120 + c) = lx;
    }
    __syncthreads();

    f32x4 acc[4][4] = {};
    for (int k0 = 0; k0 < 160; k0 += 32) {
        short8 af[4], wf[4];
        #pragma unroll
        for (int nt = 0; nt < 4; nt++)
            af[nt] = *(const short8*)(aT + (nt * 16 + l16) * 168 + k0 + q * 8);
        #pragma unroll
        for (int mt = 0; mt < 4; mt++)
            wf[mt] = *(const short8*)(Wg + (wave * 64 + mt * 16 + l16) * 160 + k0 + q * 8);
        #pragma unroll
        for (int nt = 0; nt < 4; nt++)
            #pragma unroll
            for (int mt = 0; mt < 4; mt++)
                acc[nt][mt] = __builtin_amdgcn_mfma_f32_16x16x32_bf16(af[nt], wf[mt], acc[nt][mt], 0, 0, 0);
    }

    float bias[4];
    #pragma unroll
    for (int mt = 0; mt < 4; mt++) bias[mt] = b[wave * 64 + mt * 16 + l16];

    #pragma unroll
    for (int nt = 0; nt < 4; nt++)
        #pragma unroll
        for (int r = 0; r < 4; r++) {
            const int row = n0 + nt * 16 + q * 4 + r;   // C/D: row=quad*4+reg
            if (row >= N) continue;
            #pragma unroll
            for (int mt = 0; mt < 4; mt++) {
                const int col = wave * 64 + mt * 16 + l16;  // C/D: col=lane&15
                C[(size_t)row * 256 + col] = f2bf(lrelu(acc[nt][mt][r] + bias[mt]));
            }
        }
}

// ---------------------------------------------------------------------------
// MLP layer via MFMA: C = lrelu(A @ W^T + b), A [N,256] bf16, W [256,256] bf16.
// Same 64-row x 256-col block structure, K=256 (8 k-steps).
// ---------------------------------------------------------------------------
__global__ void mlp_mfma_kernel(const unsigned short* __restrict__ A,
                                const unsigned short* __restrict__ W,
                                const float* __restrict__ b,
                                unsigned short* __restrict__ C, int N)
{
    __shared__ __align__(16) unsigned short aT[64 * 264];  // 264 = 256 + 8 pad
    const int t = threadIdx.x;
    const int n0 = blockIdx.x * 64;
    const int wave = t >> 6, lane = t & 63, q = lane >> 4, l16 = lane & 15;

    #pragma unroll
    for (int i = 0; i < 8; i++) {
        const int u = t + 256 * i;
        const int row = u >> 5, c16 = u & 31;
        const int srow = min(n0 + row, N - 1);
        *(uint4*)(aT + row * 264 + c16 * 8) = *(const uint4*)(A + (size_t)srow * 256 + c16 * 8);
    }
    __syncthreads();

    f32x4 acc[4][4] = {};
    const unsigned short* wbase = W + (wave * 64 + l16) * 256 + q * 8;
    for (int k0 = 0; k0 < 256; k0 += 32) {
        short8 af[4], wf[4];
        #pragma unroll
        for (int nt = 0; nt < 4; nt++)
            af[nt] = *(const short8*)(aT + (nt * 16 + l16) * 264 + k0 + q * 8);
        #pragma unroll
        for (int mt = 0; mt < 4; mt++)
            wf[mt] = *(const short8*)(wbase + mt * 16 * 256 + k0);
        #pragma unroll
        for (int nt = 0; nt < 4; nt++)
            #pragma unroll
            for (int mt = 0; mt < 4; mt++)
                acc[nt][mt] = __builtin_amdgcn_mfma_f32_16x16x32_bf16(af[nt], wf[mt], acc[nt][mt], 0, 0, 0);
    }

    float bias[4];
    #pragma unroll
    for (int mt = 0; mt < 4; mt++) bias[mt] = b[wave * 64 + mt * 16 + l16];

    #pragma unroll
    for (int nt = 0; nt < 4; nt++)
        #pragma unroll
        for (int r = 0; r < 4; r++) {
            const int row = n0 + nt * 16 + q * 4 + r;
            if (row >= N) continue;
            #pragma unroll
            for (int mt = 0; mt < 4; mt++) {
                const int col = wave * 64 + mt * 16 + l16;
                C[(size_t)row * 256 + col] = f2bf(lrelu(acc[nt][mt][r] + bias[mt]));
            }
        }
}

// ---------------------------------------------------------------------------
// Pred: out[n] = h[n] . w_pred + b_pred.  One wave per node; h is bf16.
// ---------------------------------------------------------------------------
__global__ void pred_kernel(const unsigned short* __restrict__ h,
                            const float* __restrict__ w,
                            const float* __restrict__ b,
                            float* __restrict__ out, int N)
{
    __shared__ float s_w[256];
    const int t = threadIdx.x;
    s_w[t] = w[t];
    __syncthreads();

    const int wave = t / 64, lane = t % 64;
    const int n = blockIdx.x * 4 + wave;
    if (n >= N) return;

    float v = 0.f;
    #pragma unroll
    for (int j = 0; j < 4; j++)
        v += bf2f(h[(size_t)n * 256 + lane + j * 64]) * s_w[lane + j * 64];

    #pragma unroll
    for (int off = 32; off > 0; off >>= 1)
        v += __shfl_down(v, off);

    if (lane == 0) out[n] = v + b[0];
}

// ---------------------------------------------------------------------------
extern "C" void kernel_launch(void* const* d_in, const int* in_sizes, int n_in,
                              void* d_out, int out_size, void* d_ws, size_t ws_size,
                              hipStream_t stream)
{
    const float* pose   = (const float*)d_in[0];
    const float* views  = (const float*)d_in[1];
    const int*   ei     = (const int*)d_in[2];
    const float* w_e1   = (const float*)d_in[3];
    const float* b_e1   = (const float*)d_in[4];
    const float* w_e2   = (const float*)d_in[5];
    const float* b_e2   = (const float*)d_in[6];
    const float* w_rel  = (const float*)d_in[7];
    const float* b_rel  = (const float*)d_in[8];
    const float* w_root = (const float*)d_in[9];
    const float* w_l1   = (const float*)d_in[10];
    const float* b_l1   = (const float*)d_in[11];
    const float* w_l2   = (const float*)d_in[12];
    const float* b_l2   = (const float*)d_in[13];
    const float* w_l3   = (const float*)d_in[14];
    const float* b_l3   = (const float*)d_in[15];
    const float* w_pred = (const float*)d_in[16];
    const float* b_pred = (const float*)d_in[17];
    float* out = (float*)d_out;

    const int N = in_sizes[0] / 3;       // 50000
    const int E = in_sizes[2] / 2;       // 4950000
    const int NB = (N + 63) >> 6;        // 782 buckets
    const int NBLK = (N + 63) / 64;      // row blocks for GEMMs

    // Workspace layout. hb0/hb1 alias pairs/sorted: graph ints are fully dead
    // (last read = gather_sum) before graphconv/mlp write hb0/hb1.
    float* x   = (float*)d_ws;                       // N*40 fp32
    float* agg = x + (size_t)N * 40;                 // N*40 fp32
    int* pairs  = (int*)(agg + (size_t)N * 40);      // NB*CAP ints (25.62 MB)
    int* sorted = pairs + (size_t)NB * CAP;          // NB*CAP ints (25.62 MB)
    unsigned short* hb0 = (unsigned short*)pairs;    // N*256 bf16 (25.6 MB) alias
    unsigned short* hb1 = (unsigned short*)sorted;   // N*256 bf16 (25.6 MB) alias
    int* gcur       = sorted + (size_t)NB * CAP;     // 1024
    int* node_start = gcur + 1024;                   // NB*64
    int* node_cnt   = node_start + NB * 64;          // NB*64
    unsigned short* Wb1 = (unsigned short*)(node_cnt + NB * 64);  // 256*256
    unsigned short* Wb2 = Wb1 + 256 * 256;
    unsigned short* Wb3 = Wb2 + 256 * 256;
    unsigned short* Wg  = Wb3 + 256 * 256;           // 256*160

    // Weight prep (bf16)
    cvt_bf16_kernel<<<256, 256, 0, stream>>>(w_l1, Wb1, 256 * 256);
    cvt_bf16_kernel<<<256, 256, 0, stream>>>(w_l2, Wb2, 256 * 256);
    cvt_bf16_kernel<<<256, 256, 0, stream>>>(w_l3, Wb3, 256 * 256);
    build_wg_kernel<<<160, 256, 0, stream>>>(w_rel, w_root, Wg);

    encoder_kernel<<<N, 64, 0, stream>>>(pose, views, w_e1, b_e1, w_e2, b_e2, x);

    hipMemsetAsync(gcur, 0, (size_t)NB * sizeof(int), stream);
    bin_kernel<<<(E + EPB - 1) / EPB, 256, 0, stream>>>(ei, gcur, pairs, E, NB);
    bucket_sort_kernel<<<NB, 256, 0, stream>>>(gcur, pairs, sorted, node_start, node_cnt);
    gather_sum_kernel<<<NB * 16, 256, 0, stream>>>(sorted, node_start, node_cnt, x, agg, N);

    graphconv_mfma_kernel<<<NBLK, 256, 0, stream>>>(agg, x, Wg, b_rel, hb0, N);
    mlp_mfma_kernel<<<NBLK, 256, 0, stream>>>(hb0, Wb1, b_l1, hb1, N);
    mlp_mfma_kernel<<<NBLK, 256, 0, stream>>>(hb1, Wb2, b_l2, hb0, N);
    mlp_mfma_kernel<<<NBLK, 256, 0, stream>>>(hb0, Wb3, b_l3, hb1, N);
    pred_kernel<<<(N + 3) / 4, 256, 0, stream>>>(hb1, w_pred, b_pred, out, N);
}

// Round 6
// 507.707 us; speedup vs baseline: 4.1531x; 1.0327x over previous
//
#include <hip/hip_runtime.h>
#include <hip/hip_fp16.h>

#define NEG_SLOPE 0.1f
__device__ __forceinline__ float lrelu(float v) { return v >= 0.f ? v : NEG_SLOPE * v; }

constexpr int CAP = 8192;   // per-bucket capacity (mean 6330, sd ~80)
constexpr int EPB = 4096;   // edges per bin block (16 per thread, contiguous)

typedef __attribute__((ext_vector_type(8))) short short8;   // 8 bf16 (4 VGPRs)
typedef __attribute__((ext_vector_type(4))) float f32x4;    // MFMA accum

__device__ __forceinline__ unsigned short f2bf(float f) {   // RNE
    union { float f; unsigned u; } v; v.f = f;
    const unsigned r = v.u + 0x7FFF + ((v.u >> 16) & 1);
    return (unsigned short)(r >> 16);
}
__device__ __forceinline__ float bf2f(unsigned short h) {
    union { unsigned u; float f; } v; v.u = ((unsigned)h) << 16;
    return v.f;
}

// ---------------------------------------------------------------------------
// Weight prep: fp32 -> bf16 (per call; no cross-call state allowed).
// ---------------------------------------------------------------------------
__global__ void cvt_bf16_kernel(const float* __restrict__ src, unsigned short* __restrict__ dst, int n)
{
    const int i = blockIdx.x * blockDim.x + threadIdx.x;
    if (i < n) dst[i] = f2bf(src[i]);
}

// Wg[256][160] = [w_rel | w_root | w_rel | w_root] bf16 (hi/lo A-split shares W).
__global__ void build_wg_kernel(const float* __restrict__ w_rel, const float* __restrict__ w_root,
                                unsigned short* __restrict__ Wg)
{
    const int i = blockIdx.x * blockDim.x + threadIdx.x;
    if (i >= 256 * 160) return;
    const int m = i / 160, c = i % 160;
    const int k = c % 80;
    const float v = (k < 40) ? w_rel[m * 40 + k] : w_root[m * 40 + (k - 40)];
    Wg[i] = f2bf(v);
}

// ---------------------------------------------------------------------------
// Encoder: per node, conv1d(3->9,k3,s2)+lrelu, conv1d(9->1,k3,s2)+lrelu,
// concat pose -> x[N][40] fp32 + xh[N][40] fp16 (gather copy, 4MB = L2-sized).
// ---------------------------------------------------------------------------
__global__ void encoder_kernel(const float* __restrict__ pose,
                               const float* __restrict__ views,
                               const float* __restrict__ w1, const float* __restrict__ b1,
                               const float* __restrict__ w2, const float* __restrict__ b2,
                               float* __restrict__ x, __half* __restrict__ xh)
{
    __shared__ float s_in[3 * 151];
    __shared__ float s_c1[9 * 75];
    __shared__ float s_w1[81];
    __shared__ float s_b1[9];
    __shared__ float s_w2[27];
    __shared__ float s_b2;

    const int n = blockIdx.x;
    const int t = threadIdx.x;

    for (int i = t; i < 453; i += 64) s_in[i] = views[n * 453 + i];
    for (int i = t; i < 81; i += 64)  s_w1[i] = w1[i];
    if (t < 9)  s_b1[t] = b1[t];
    if (t < 27) s_w2[t] = w2[t];
    if (t == 0) s_b2 = b2[0];
    __syncthreads();

    for (int i = t; i < 675; i += 64) {
        const int oc = i / 75, ow = i % 75;
        float v = s_b1[oc];
        #pragma unroll
        for (int ic = 0; ic < 3; ic++) {
            #pragma unroll
            for (int k = 0; k < 3; k++)
                v += s_in[ic * 151 + 2 * ow + k] * s_w1[oc * 9 + ic * 3 + k];
        }
        s_c1[i] = lrelu(v);
    }
    __syncthreads();

    if (t < 3) {
        const float v = pose[n * 3 + t];
        x[n * 40 + t] = v;
        xh[n * 40 + t] = __float2half(v);
    } else if (t < 40) {
        const int ow = t - 3;
        float v = s_b2;
        #pragma unroll
        for (int ic = 0; ic < 9; ic++) {
            #pragma unroll
            for (int k = 0; k < 3; k++)
                v += s_c1[ic * 75 + 2 * ow + k] * s_w2[ic * 3 + k];
        }
        v = lrelu(v);
        x[n * 40 + t] = v;
        xh[n * 40 + t] = __float2half(v);
    }
}

// ---------------------------------------------------------------------------
// Coarse binning: bucket = dst>>6, packed src|dstLocal<<16, one global atomic
// per (block,bucket).
// ---------------------------------------------------------------------------
__global__ void bin_kernel(const int* __restrict__ ei, int* __restrict__ gcur,
                           int* __restrict__ pairs, int E, int NB)
{
    __shared__ int s_hist[1024];
    __shared__ int s_base[1024];
    const int t = threadIdx.x;
    const int e0 = blockIdx.x * EPB + t * 16;

    for (int i = t; i < NB; i += 256) s_hist[i] = 0;
    __syncthreads();

    int pk[16], mt[16];
    auto proc = [&](int j, int sv, int dv) {
        const int b = dv >> 6;
        const int r = atomicAdd(&s_hist[b], 1);
        pk[j] = sv | ((dv & 63) << 16);
        mt[j] = b | (r << 10);
    };

    if (e0 + 16 <= E) {
        #pragma unroll
        for (int q = 0; q < 4; q++) {
            const int4 sv = *(const int4*)(ei + e0 + 4 * q);
            const int4 dv = *(const int4*)(ei + E + e0 + 4 * q);
            proc(4 * q + 0, sv.x, dv.x);
            proc(4 * q + 1, sv.y, dv.y);
            proc(4 * q + 2, sv.z, dv.z);
            proc(4 * q + 3, sv.w, dv.w);
        }
    } else {
        #pragma unroll
        for (int j = 0; j < 16; j++) {
            mt[j] = -1;
            const int e = e0 + j;
            if (e < E) proc(j, ei[e], ei[E + e]);
        }
    }
    __syncthreads();

    for (int i = t; i < NB; i += 256) {
        const int c = s_hist[i];
        if (c > 0) s_base[i] = atomicAdd(&gcur[i], c);
    }
    __syncthreads();

    #pragma unroll
    for (int j = 0; j < 16; j++) {
        if (mt[j] >= 0) {
            const int b = mt[j] & 1023;
            const int pos = s_base[b] + (mt[j] >> 10);
            if (pos < CAP) pairs[b * CAP + pos] = pk[j];
        }
    }
}

// ---------------------------------------------------------------------------
// Per-bucket exact counting sort (LDS only), 8-aligned runs with src=0 pads.
// ---------------------------------------------------------------------------
__global__ void bucket_sort_kernel(const int* __restrict__ gcur,
                                   const int* __restrict__ pairs,
                                   int* __restrict__ sorted,
                                   int* __restrict__ node_start,
                                   int* __restrict__ node_cnt)
{
    __shared__ int s_cnt[64], s_off[64], s_cur[64];
    const int b = blockIdx.x;
    const int t = threadIdx.x;
    const int cnt = min(gcur[b], CAP);
    const int* __restrict__ pr = pairs + b * CAP;
    int* __restrict__ so = sorted + (size_t)b * CAP;

    if (t < 64) s_cnt[t] = 0;
    __syncthreads();
    for (int i = t; i < cnt; i += 256)
        atomicAdd(&s_cnt[pr[i] >> 16], 1);
    __syncthreads();

    if (t < 64) {
        const int c = s_cnt[t];
        const int p = (c + 7) & ~7;
        int sc = p;
        #pragma unroll
        for (int d = 1; d < 64; d <<= 1) {
            const int u = __shfl_up(sc, d);
            if (t >= d) sc += u;
        }
        const int excl = sc - p;
        s_off[t] = excl;
        s_cur[t] = excl;
        node_start[b * 64 + t] = b * CAP + excl;
        node_cnt[b * 64 + t] = c;
    }
    __syncthreads();

    if (t < 64) {
        const int e0 = s_off[t] + s_cnt[t];
        const int e1 = s_off[t] + ((s_cnt[t] + 7) & ~7);
        for (int i = e0; i < e1 && i < CAP; i++) so[i] = 0;
    }
    for (int i = t; i < cnt; i += 256) {
        const int p = pr[i];
        const int pos = atomicAdd(&s_cur[p >> 16], 1);
        if (pos < CAP) so[pos] = p & 0xFFFF;
    }
}

// ---------------------------------------------------------------------------
// Atomic-free segment sum: one wave per node, 8 outstanding 80B fp16 row
// gathers per iter. Working set (xh) = 4MB -> per-XCD-L2 resident.
// ---------------------------------------------------------------------------
__global__ void gather_sum_kernel(const int* __restrict__ sorted,
                                  const int* __restrict__ node_start,
                                  const int* __restrict__ node_cnt,
                                  const __half* __restrict__ xh,
                                  float* __restrict__ agg, int N)
{
    const int n = blockIdx.x * 4 + (threadIdx.x >> 6);
    const int lane = threadIdx.x & 63;
    if (n >= N || lane >= 40) return;

    const int start = node_start[n];
    const int cnt = node_cnt[n];
    const int* __restrict__ srt = sorted + start;
    const __half* __restrict__ xl = xh + lane;

    float acc = 0.f;
    const int full = cnt & ~7;
    int e = 0;
    for (; e < full; e += 8) {
        const int4 i0 = *(const int4*)(srt + e);
        const int4 i1 = *(const int4*)(srt + e + 4);
        const float v0 = __half2float(xl[i0.x * 40]), v1 = __half2float(xl[i0.y * 40]);
        const float v2 = __half2float(xl[i0.z * 40]), v3 = __half2float(xl[i0.w * 40]);
        const float v4 = __half2float(xl[i1.x * 40]), v5 = __half2float(xl[i1.y * 40]);
        const float v6 = __half2float(xl[i1.z * 40]), v7 = __half2float(xl[i1.w * 40]);
        acc += ((v0 + v1) + (v2 + v3)) + ((v4 + v5) + (v6 + v7));
    }
    if (e < cnt) {   // masked tail; pads are sentinel src=0 (valid address)
        const int4 i0 = *(const int4*)(srt + e);
        const int4 i1 = *(const int4*)(srt + e + 4);
        const float v0 = __half2float(xl[i0.x * 40]), v1 = __half2float(xl[i0.y * 40]);
        const float v2 = __half2float(xl[i0.z * 40]), v3 = __half2float(xl[i0.w * 40]);
        const float v4 = __half2float(xl[i1.x * 40]), v5 = __half2float(xl[i1.y * 40]);
        const float v6 = __half2float(xl[i1.z * 40]), v7 = __half2float(xl[i1.w * 40]);
        acc += (e + 0 < cnt ? v0 : 0.f) + (e + 1 < cnt ? v1 : 0.f)
             + (e + 2 < cnt ? v2 : 0.f) + (e + 3 < cnt ? v3 : 0.f)
             + (e + 4 < cnt ? v4 : 0.f) + (e + 5 < cnt ? v5 : 0.f)
             + (e + 6 < cnt ? v6 : 0.f) + (e + 7 < cnt ? v7 : 0.f);
    }
    agg[n * 40 + lane] = acc;
}

// ---------------------------------------------------------------------------
// GraphConv via MFMA, K=160: A = [agg_hi|x_hi|agg_lo|x_lo] bf16 (hi/lo split
// for near-fp32 A-side), W = [w_rel|w_root|w_rel|w_root] bf16.
// ---------------------------------------------------------------------------
__global__ void graphconv_mfma_kernel(const float* __restrict__ agg,
                                      const float* __restrict__ x,
                                      const unsigned short* __restrict__ Wg,
                                      const float* __restrict__ b,
                                      unsigned short* __restrict__ C, int N)
{
    __shared__ __align__(16) unsigned short aT[64 * 168];  // 168 = 160 + 8 pad
    const int t = threadIdx.x;
    const int n0 = blockIdx.x * 64;
    const int wave = t >> 6, lane = t & 63, q = lane >> 4, l16 = lane & 15;

    for (int u = t; u < 640; u += 256) {
        const int row = u / 10, c = (u % 10) * 4;
        const int srow = min(n0 + row, N - 1);
        const float4 fa = *(const float4*)(agg + (size_t)srow * 40 + c);
        const float4 fx = *(const float4*)(x + (size_t)srow * 40 + c);
        const float av[4] = {fa.x, fa.y, fa.z, fa.w};
        const float xv[4] = {fx.x, fx.y, fx.z, fx.w};
        ushort4 ha, la, hx, lx;
        ha.x = f2bf(av[0]); la.x = f2bf(av[0] - bf2f(ha.x));
        ha.y = f2bf(av[1]); la.y = f2bf(av[1] - bf2f(ha.y));
        ha.z = f2bf(av[2]); la.z = f2bf(av[2] - bf2f(ha.z));
        ha.w = f2bf(av[3]); la.w = f2bf(av[3] - bf2f(ha.w));
        hx.x = f2bf(xv[0]); lx.x = f2bf(xv[0] - bf2f(hx.x));
        hx.y = f2bf(xv[1]); lx.y = f2bf(xv[1] - bf2f(hx.y));
        hx.z = f2bf(xv[2]); lx.z = f2bf(xv[2] - bf2f(hx.z));
        hx.w = f2bf(xv[3]); lx.w = f2bf(xv[3] - bf2f(hx.w));
        unsigned short* rp = aT + row * 168;
        *(ushort4*)(rp + c)       = ha;
        *(ushort4*)(rp + 40 + c)  = hx;
        *(ushort4*)(rp + 80 + c)  = la;
        *(ushort4*)(rp + 120 + c) = lx;
    }
    __syncthreads();

    f32x4 acc[4][4] = {};
    for (int k0 = 0; k0 < 160; k0 += 32) {
        short8 af[4], wf[4];
        #pragma unroll
        for (int nt = 0; nt < 4; nt++)
            af[nt] = *(const short8*)(aT + (nt * 16 + l16) * 168 + k0 + q * 8);
        #pragma unroll
        for (int mt = 0; mt < 4; mt++)
            wf[mt] = *(const short8*)(Wg + (wave * 64 + mt * 16 + l16) * 160 + k0 + q * 8);
        #pragma unroll
        for (int nt = 0; nt < 4; nt++)
            #pragma unroll
            for (int mt = 0; mt < 4; mt++)
                acc[nt][mt] = __builtin_amdgcn_mfma_f32_16x16x32_bf16(af[nt], wf[mt], acc[nt][mt], 0, 0, 0);
    }

    float bias[4];
    #pragma unroll
    for (int mt = 0; mt < 4; mt++) bias[mt] = b[wave * 64 + mt * 16 + l16];

    #pragma unroll
    for (int nt = 0; nt < 4; nt++)
        #pragma unroll
        for (int r = 0; r < 4; r++) {
            const int row = n0 + nt * 16 + q * 4 + r;   // C/D: row=quad*4+reg
            if (row >= N) continue;
            #pragma unroll
            for (int mt = 0; mt < 4; mt++) {
                const int col = wave * 64 + mt * 16 + l16;  // C/D: col=lane&15
                C[(size_t)row * 256 + col] = f2bf(lrelu(acc[nt][mt][r] + bias[mt]));
            }
        }
}

// ---------------------------------------------------------------------------
// MLP layer via MFMA: C = lrelu(A @ W^T + b), A [N,256] bf16, W [256,256] bf16.
// ---------------------------------------------------------------------------
__global__ void mlp_mfma_kernel(const unsigned short* __restrict__ A,
                                const unsigned short* __restrict__ W,
                                const float* __restrict__ b,
                                unsigned short* __restrict__ C, int N)
{
    __shared__ __align__(16) unsigned short aT[64 * 264];  // 264 = 256 + 8 pad
    const int t = threadIdx.x;
    const int n0 = blockIdx.x * 64;
    const int wave = t >> 6, lane = t & 63, q = lane >> 4, l16 = lane & 15;

    #pragma unroll
    for (int i = 0; i < 8; i++) {
        const int u = t + 256 * i;
        const int row = u >> 5, c16 = u & 31;
        const int srow = min(n0 + row, N - 1);
        *(uint4*)(aT + row * 264 + c16 * 8) = *(const uint4*)(A + (size_t)srow * 256 + c16 * 8);
    }
    __syncthreads();

    f32x4 acc[4][4] = {};
    const unsigned short* wbase = W + (wave * 64 + l16) * 256 + q * 8;
    for (int k0 = 0; k0 < 256; k0 += 32) {
        short8 af[4], wf[4];
        #pragma unroll
        for (int nt = 0; nt < 4; nt++)
            af[nt] = *(const short8*)(aT + (nt * 16 + l16) * 264 + k0 + q * 8);
        #pragma unroll
        for (int mt = 0; mt < 4; mt++)
            wf[mt] = *(const short8*)(wbase + mt * 16 * 256 + k0);
        #pragma unroll
        for (int nt = 0; nt < 4; nt++)
            #pragma unroll
            for (int mt = 0; mt < 4; mt++)
                acc[nt][mt] = __builtin_amdgcn_mfma_f32_16x16x32_bf16(af[nt], wf[mt], acc[nt][mt], 0, 0, 0);
    }

    float bias[4];
    #pragma unroll
    for (int mt = 0; mt < 4; mt++) bias[mt] = b[wave * 64 + mt * 16 + l16];

    #pragma unroll
    for (int nt = 0; nt < 4; nt++)
        #pragma unroll
        for (int r = 0; r < 4; r++) {
            const int row = n0 + nt * 16 + q * 4 + r;
            if (row >= N) continue;
            #pragma unroll
            for (int mt = 0; mt < 4; mt++) {
                const int col = wave * 64 + mt * 16 + l16;
                C[(size_t)row * 256 + col] = f2bf(lrelu(acc[nt][mt][r] + bias[mt]));
            }
        }
}

// ---------------------------------------------------------------------------
// Pred: out[n] = h[n] . w_pred + b_pred.  One wave per node; h is bf16.
// ---------------------------------------------------------------------------
__global__ void pred_kernel(const unsigned short* __restrict__ h,
                            const float* __restrict__ w,
                            const float* __restrict__ b,
                            float* __restrict__ out, int N)
{
    __shared__ float s_w[256];
    const int t = threadIdx.x;
    s_w[t] = w[t];
    __syncthreads();

    const int wave = t / 64, lane = t % 64;
    const int n = blockIdx.x * 4 + wave;
    if (n >= N) return;

    float v = 0.f;
    #pragma unroll
    for (int j = 0; j < 4; j++)
        v += bf2f(h[(size_t)n * 256 + lane + j * 64]) * s_w[lane + j * 64];

    #pragma unroll
    for (int off = 32; off > 0; off >>= 1)
        v += __shfl_down(v, off);

    if (lane == 0) out[n] = v + b[0];
}

// ---------------------------------------------------------------------------
extern "C" void kernel_launch(void* const* d_in, const int* in_sizes, int n_in,
                              void* d_out, int out_size, void* d_ws, size_t ws_size,
                              hipStream_t stream)
{
    const float* pose   = (const float*)d_in[0];
    const float* views  = (const float*)d_in[1];
    const int*   ei     = (const int*)d_in[2];
    const float* w_e1   = (const float*)d_in[3];
    const float* b_e1   = (const float*)d_in[4];
    const float* w_e2   = (const float*)d_in[5];
    const float* b_e2   = (const float*)d_in[6];
    const float* w_rel  = (const float*)d_in[7];
    const float* b_rel  = (const float*)d_in[8];
    const float* w_root = (const float*)d_in[9];
    const float* w_l1   = (const float*)d_in[10];
    const float* b_l1   = (const float*)d_in[11];
    const float* w_l2   = (const float*)d_in[12];
    const float* b_l2   = (const float*)d_in[13];
    const float* w_l3   = (const float*)d_in[14];
    const float* b_l3   = (const float*)d_in[15];
    const float* w_pred = (const float*)d_in[16];
    const float* b_pred = (const float*)d_in[17];
    float* out = (float*)d_out;

    const int N = in_sizes[0] / 3;       // 50000
    const int E = in_sizes[2] / 2;       // 4950000
    const int NB = (N + 63) >> 6;        // 782 buckets
    const int NBLK = (N + 63) / 64;      // row blocks for GEMMs

    // Workspace layout. hb0/hb1 alias pairs/sorted: graph ints are fully dead
    // (last read = gather_sum) before graphconv/mlp write hb0/hb1.
    float* x   = (float*)d_ws;                       // N*40 fp32
    float* agg = x + (size_t)N * 40;                 // N*40 fp32
    int* pairs  = (int*)(agg + (size_t)N * 40);      // NB*CAP ints (25.62 MB)
    int* sorted = pairs + (size_t)NB * CAP;          // NB*CAP ints (25.62 MB)
    unsigned short* hb0 = (unsigned short*)pairs;    // N*256 bf16 alias
    unsigned short* hb1 = (unsigned short*)sorted;   // N*256 bf16 alias
    int* gcur       = sorted + (size_t)NB * CAP;     // 1024
    int* node_start = gcur + 1024;                   // NB*64
    int* node_cnt   = node_start + NB * 64;          // NB*64
    unsigned short* Wb1 = (unsigned short*)(node_cnt + NB * 64);  // 256*256
    unsigned short* Wb2 = Wb1 + 256 * 256;
    unsigned short* Wb3 = Wb2 + 256 * 256;
    unsigned short* Wg  = Wb3 + 256 * 256;           // 256*160
    __half* xh = (__half*)(Wg + 256 * 160);          // N*40 fp16 (4 MB)

    // Weight prep (bf16)
    cvt_bf16_kernel<<<256, 256, 0, stream>>>(w_l1, Wb1, 256 * 256);
    cvt_bf16_kernel<<<256, 256, 0, stream>>>(w_l2, Wb2, 256 * 256);
    cvt_bf16_kernel<<<256, 256, 0, stream>>>(w_l3, Wb3, 256 * 256);
    build_wg_kernel<<<160, 256, 0, stream>>>(w_rel, w_root, Wg);

    encoder_kernel<<<N, 64, 0, stream>>>(pose, views, w_e1, b_e1, w_e2, b_e2, x, xh);

    hipMemsetAsync(gcur, 0, (size_t)NB * sizeof(int), stream);
    bin_kernel<<<(E + EPB - 1) / EPB, 256, 0, stream>>>(ei, gcur, pairs, E, NB);
    bucket_sort_kernel<<<NB, 256, 0, stream>>>(gcur, pairs, sorted, node_start, node_cnt);
    gather_sum_kernel<<<NB * 16, 256, 0, stream>>>(sorted, node_start, node_cnt, xh, agg, N);

    graphconv_mfma_kernel<<<NBLK, 256, 0, stream>>>(agg, x, Wg, b_rel, hb0, N);
    mlp_mfma_kernel<<<NBLK, 256, 0, stream>>>(hb0, Wb1, b_l1, hb1, N);
    mlp_mfma_kernel<<<NBLK, 256, 0, stream>>>(hb1, Wb2, b_l2, hb0, N);
    mlp_mfma_kernel<<<NBLK, 256, 0, stream>>>(hb0, Wb3, b_l3, hb1, N);
    pred_kernel<<<(N + 3) / 4, 256, 0, stream>>>(hb1, w_pred, b_pred, out, N);
}

// Round 7
// 479.128 us; speedup vs baseline: 4.4008x; 1.0596x over previous
//
#include <hip/hip_runtime.h>
#include <hip/hip_fp16.h>

#define NEG_SLOPE 0.1f
__device__ __forceinline__ float lrelu(float v) { return v >= 0.f ? v : NEG_SLOPE * v; }

constexpr int CAP = 8192;   // per-bucket capacity (mean 6330, sd ~80)
constexpr int EPB = 4096;   // edges per bin block (16 per thread, contiguous)

typedef __attribute__((ext_vector_type(8))) short short8;   // 8 bf16 (4 VGPRs)
typedef __attribute__((ext_vector_type(4))) float f32x4;    // MFMA accum

__device__ __forceinline__ unsigned short f2bf(float f) {   // RNE
    union { float f; unsigned u; } v; v.f = f;
    const unsigned r = v.u + 0x7FFF + ((v.u >> 16) & 1);
    return (unsigned short)(r >> 16);
}
__device__ __forceinline__ float bf2f(unsigned short h) {
    union { unsigned u; float f; } v; v.u = ((unsigned)h) << 16;
    return v.f;
}

// ---------------------------------------------------------------------------
// Weight prep: fp32 -> bf16 (per call; no cross-call state allowed).
// ---------------------------------------------------------------------------
__global__ void cvt_bf16_kernel(const float* __restrict__ src, unsigned short* __restrict__ dst, int n)
{
    const int i = blockIdx.x * blockDim.x + threadIdx.x;
    if (i < n) dst[i] = f2bf(src[i]);
}

// Wg[256][160] = [w_rel | w_root | w_rel | w_root] bf16 (hi/lo A-split shares W).
__global__ void build_wg_kernel(const float* __restrict__ w_rel, const float* __restrict__ w_root,
                                unsigned short* __restrict__ Wg)
{
    const int i = blockIdx.x * blockDim.x + threadIdx.x;
    if (i >= 256 * 160) return;
    const int m = i / 160, c = i % 160;
    const int k = c % 80;
    const float v = (k < 40) ? w_rel[m * 40 + k] : w_root[m * 40 + (k - 40)];
    Wg[i] = f2bf(v);
}

// ---------------------------------------------------------------------------
// Encoder v2: one WAVE per node, 4 nodes per 256-thread block.
// conv1 (3->9,k3,s2): lane = output position, 3-tap window read DIRECT from
// global (dense, L1/L2-served overlap), all 9 oc kept in registers -> zero
// LDS for the input stage. c1 stored to LDS even/odd-deinterleaved so
// conv2's stride-2 taps become stride-1 conflict-free reads.
// ---------------------------------------------------------------------------
__global__ __launch_bounds__(256) void encoder_kernel(
        const float* __restrict__ pose,
        const float* __restrict__ views,
        const float* __restrict__ w1, const float* __restrict__ b1,
        const float* __restrict__ w2, const float* __restrict__ b2,
        float* __restrict__ x, __half* __restrict__ xh, int N)
{
    __shared__ float s_w1[81];
    __shared__ float s_b1[9];
    __shared__ float s_w2[27];
    __shared__ float s_b2[1];
    __shared__ float s_c1[4][9][80];   // [wave][oc][(p&1)*40 + (p>>1)]

    const int t = threadIdx.x;
    if (t < 81) s_w1[t] = w1[t];
    if (t >= 96 && t < 105) s_b1[t - 96] = b1[t - 96];
    if (t >= 128 && t < 155) s_w2[t - 128] = w2[t - 128];
    if (t == 240) s_b2[0] = b2[0];
    __syncthreads();

    const int w = t >> 6, lane = t & 63;
    const int n = min(blockIdx.x * 4 + w, N - 1);   // clamp: dup writes benign
    const float* __restrict__ vin = views + (size_t)n * 453;

    // conv1: positions 0..74 over two passes (lane, 64+lane)
    #pragma unroll
    for (int pass = 0; pass < 2; pass++) {
        const int p = pass * 64 + lane;
        if (p < 75) {
            float e[3], o[3], e1[3];
            #pragma unroll
            for (int ic = 0; ic < 3; ic++) {
                const float* ci = vin + ic * 151 + 2 * p;
                e[ic] = ci[0]; o[ic] = ci[1]; e1[ic] = ci[2];
            }
            #pragma unroll
            for (int oc = 0; oc < 9; oc++) {
                float v = s_b1[oc];
                #pragma unroll
                for (int ic = 0; ic < 3; ic++)
                    v += s_w1[oc * 9 + ic * 3 + 0] * e[ic]
                       + s_w1[oc * 9 + ic * 3 + 1] * o[ic]
                       + s_w1[oc * 9 + ic * 3 + 2] * e1[ic];
                s_c1[w][oc][(p & 1) * 40 + (p >> 1)] = lrelu(v);
            }
        }
    }
    __syncthreads();   // safety; producers/consumers are same-wave anyway

    // conv2 (9->1,k3,s2): 37 outputs; lanes 0..2 pass pose through.
    float outv = 0.f;
    if (lane < 3) {
        outv = pose[(size_t)n * 3 + lane];
    } else if (lane < 40) {
        const int ow = lane - 3;
        float v = s_b2[0];
        #pragma unroll
        for (int ic = 0; ic < 9; ic++)
            v += s_w2[ic * 3 + 0] * s_c1[w][ic][ow]
               + s_w2[ic * 3 + 1] * s_c1[w][ic][40 + ow]
               + s_w2[ic * 3 + 2] * s_c1[w][ic][ow + 1];
        outv = lrelu(v);
    }
    if (lane < 40) {
        x[(size_t)n * 40 + lane] = outv;
        xh[(size_t)n * 40 + lane] = __float2half(outv);
    }
}

// ---------------------------------------------------------------------------
// Coarse binning: bucket = dst>>6, packed src|dstLocal<<16, one global atomic
// per (block,bucket).
// ---------------------------------------------------------------------------
__global__ void bin_kernel(const int* __restrict__ ei, int* __restrict__ gcur,
                           int* __restrict__ pairs, int E, int NB)
{
    __shared__ int s_hist[1024];
    __shared__ int s_base[1024];
    const int t = threadIdx.x;
    const int e0 = blockIdx.x * EPB + t * 16;

    for (int i = t; i < NB; i += 256) s_hist[i] = 0;
    __syncthreads();

    int pk[16], mt[16];
    auto proc = [&](int j, int sv, int dv) {
        const int b = dv >> 6;
        const int r = atomicAdd(&s_hist[b], 1);
        pk[j] = sv | ((dv & 63) << 16);
        mt[j] = b | (r << 10);
    };

    if (e0 + 16 <= E) {
        #pragma unroll
        for (int q = 0; q < 4; q++) {
            const int4 sv = *(const int4*)(ei + e0 + 4 * q);
            const int4 dv = *(const int4*)(ei + E + e0 + 4 * q);
            proc(4 * q + 0, sv.x, dv.x);
            proc(4 * q + 1, sv.y, dv.y);
            proc(4 * q + 2, sv.z, dv.z);
            proc(4 * q + 3, sv.w, dv.w);
        }
    } else {
        #pragma unroll
        for (int j = 0; j < 16; j++) {
            mt[j] = -1;
            const int e = e0 + j;
            if (e < E) proc(j, ei[e], ei[E + e]);
        }
    }
    __syncthreads();

    for (int i = t; i < NB; i += 256) {
        const int c = s_hist[i];
        if (c > 0) s_base[i] = atomicAdd(&gcur[i], c);
    }
    __syncthreads();

    #pragma unroll
    for (int j = 0; j < 16; j++) {
        if (mt[j] >= 0) {
            const int b = mt[j] & 1023;
            const int pos = s_base[b] + (mt[j] >> 10);
            if (pos < CAP) pairs[b * CAP + pos] = pk[j];
        }
    }
}

// ---------------------------------------------------------------------------
// Per-bucket exact counting sort (LDS only), 8-aligned runs with src=0 pads.
// ---------------------------------------------------------------------------
__global__ void bucket_sort_kernel(const int* __restrict__ gcur,
                                   const int* __restrict__ pairs,
                                   int* __restrict__ sorted,
                                   int* __restrict__ node_start,
                                   int* __restrict__ node_cnt)
{
    __shared__ int s_cnt[64], s_off[64], s_cur[64];
    const int b = blockIdx.x;
    const int t = threadIdx.x;
    const int cnt = min(gcur[b], CAP);
    const int* __restrict__ pr = pairs + b * CAP;
    int* __restrict__ so = sorted + (size_t)b * CAP;

    if (t < 64) s_cnt[t] = 0;
    __syncthreads();
    for (int i = t; i < cnt; i += 256)
        atomicAdd(&s_cnt[pr[i] >> 16], 1);
    __syncthreads();

    if (t < 64) {
        const int c = s_cnt[t];
        const int p = (c + 7) & ~7;
        int sc = p;
        #pragma unroll
        for (int d = 1; d < 64; d <<= 1) {
            const int u = __shfl_up(sc, d);
            if (t >= d) sc += u;
        }
        const int excl = sc - p;
        s_off[t] = excl;
        s_cur[t] = excl;
        node_start[b * 64 + t] = b * CAP + excl;
        node_cnt[b * 64 + t] = c;
    }
    __syncthreads();

    if (t < 64) {
        const int e0 = s_off[t] + s_cnt[t];
        const int e1 = s_off[t] + ((s_cnt[t] + 7) & ~7);
        for (int i = e0; i < e1 && i < CAP; i++) so[i] = 0;
    }
    for (int i = t; i < cnt; i += 256) {
        const int p = pr[i];
        const int pos = atomicAdd(&s_cur[p >> 16], 1);
        if (pos < CAP) so[pos] = p & 0xFFFF;
    }
}

// ---------------------------------------------------------------------------
// Atomic-free segment sum: one wave per node, 8 outstanding 80B fp16 row
// gathers per iter. Working set (xh) = 4MB -> per-XCD-L2 resident.
// ---------------------------------------------------------------------------
__global__ void gather_sum_kernel(const int* __restrict__ sorted,
                                  const int* __restrict__ node_start,
                                  const int* __restrict__ node_cnt,
                                  const __half* __restrict__ xh,
                                  float* __restrict__ agg, int N)
{
    const int n = blockIdx.x * 4 + (threadIdx.x >> 6);
    const int lane = threadIdx.x & 63;
    if (n >= N || lane >= 40) return;

    const int start = node_start[n];
    const int cnt = node_cnt[n];
    const int* __restrict__ srt = sorted + start;
    const __half* __restrict__ xl = xh + lane;

    float acc = 0.f;
    const int full = cnt & ~7;
    int e = 0;
    for (; e < full; e += 8) {
        const int4 i0 = *(const int4*)(srt + e);
        const int4 i1 = *(const int4*)(srt + e + 4);
        const float v0 = __half2float(xl[i0.x * 40]), v1 = __half2float(xl[i0.y * 40]);
        const float v2 = __half2float(xl[i0.z * 40]), v3 = __half2float(xl[i0.w * 40]);
        const float v4 = __half2float(xl[i1.x * 40]), v5 = __half2float(xl[i1.y * 40]);
        const float v6 = __half2float(xl[i1.z * 40]), v7 = __half2float(xl[i1.w * 40]);
        acc += ((v0 + v1) + (v2 + v3)) + ((v4 + v5) + (v6 + v7));
    }
    if (e < cnt) {   // masked tail; pads are sentinel src=0 (valid address)
        const int4 i0 = *(const int4*)(srt + e);
        const int4 i1 = *(const int4*)(srt + e + 4);
        const float v0 = __half2float(xl[i0.x * 40]), v1 = __half2float(xl[i0.y * 40]);
        const float v2 = __half2float(xl[i0.z * 40]), v3 = __half2float(xl[i0.w * 40]);
        const float v4 = __half2float(xl[i1.x * 40]), v5 = __half2float(xl[i1.y * 40]);
        const float v6 = __half2float(xl[i1.z * 40]), v7 = __half2float(xl[i1.w * 40]);
        acc += (e + 0 < cnt ? v0 : 0.f) + (e + 1 < cnt ? v1 : 0.f)
             + (e + 2 < cnt ? v2 : 0.f) + (e + 3 < cnt ? v3 : 0.f)
             + (e + 4 < cnt ? v4 : 0.f) + (e + 5 < cnt ? v5 : 0.f)
             + (e + 6 < cnt ? v6 : 0.f) + (e + 7 < cnt ? v7 : 0.f);
    }
    agg[n * 40 + lane] = acc;
}

// ---------------------------------------------------------------------------
// GraphConv via MFMA, K=160: A = [agg_hi|x_hi|agg_lo|x_lo] bf16 (hi/lo split
// for near-fp32 A-side), W = [w_rel|w_root|w_rel|w_root] bf16.
// ---------------------------------------------------------------------------
__global__ void graphconv_mfma_kernel(const float* __restrict__ agg,
                                      const float* __restrict__ x,
                                      const unsigned short* __restrict__ Wg,
                                      const float* __restrict__ b,
                                      unsigned short* __restrict__ C, int N)
{
    __shared__ __align__(16) unsigned short aT[64 * 168];  // 168 = 160 + 8 pad
    const int t = threadIdx.x;
    const int n0 = blockIdx.x * 64;
    const int wave = t >> 6, lane = t & 63, q = lane >> 4, l16 = lane & 15;

    for (int u = t; u < 640; u += 256) {
        const int row = u / 10, c = (u % 10) * 4;
        const int srow = min(n0 + row, N - 1);
        const float4 fa = *(const float4*)(agg + (size_t)srow * 40 + c);
        const float4 fx = *(const float4*)(x + (size_t)srow * 40 + c);
        const float av[4] = {fa.x, fa.y, fa.z, fa.w};
        const float xv[4] = {fx.x, fx.y, fx.z, fx.w};
        ushort4 ha, la, hx, lx;
        ha.x = f2bf(av[0]); la.x = f2bf(av[0] - bf2f(ha.x));
        ha.y = f2bf(av[1]); la.y = f2bf(av[1] - bf2f(ha.y));
        ha.z = f2bf(av[2]); la.z = f2bf(av[2] - bf2f(ha.z));
        ha.w = f2bf(av[3]); la.w = f2bf(av[3] - bf2f(ha.w));
        hx.x = f2bf(xv[0]); lx.x = f2bf(xv[0] - bf2f(hx.x));
        hx.y = f2bf(xv[1]); lx.y = f2bf(xv[1] - bf2f(hx.y));
        hx.z = f2bf(xv[2]); lx.z = f2bf(xv[2] - bf2f(hx.z));
        hx.w = f2bf(xv[3]); lx.w = f2bf(xv[3] - bf2f(hx.w));
        unsigned short* rp = aT + row * 168;
        *(ushort4*)(rp + c)       = ha;
        *(ushort4*)(rp + 40 + c)  = hx;
        *(ushort4*)(rp + 80 + c)  = la;
        *(ushort4*)(rp + 120 + c) = lx;
    }
    __syncthreads();

    f32x4 acc[4][4] = {};
    for (int k0 = 0; k0 < 160; k0 += 32) {
        short8 af[4], wf[4];
        #pragma unroll
        for (int nt = 0; nt < 4; nt++)
            af[nt] = *(const short8*)(aT + (nt * 16 + l16) * 168 + k0 + q * 8);
        #pragma unroll
        for (int mt = 0; mt < 4; mt++)
            wf[mt] = *(const short8*)(Wg + (wave * 64 + mt * 16 + l16) * 160 + k0 + q * 8);
        #pragma unroll
        for (int nt = 0; nt < 4; nt++)
            #pragma unroll
            for (int mt = 0; mt < 4; mt++)
                acc[nt][mt] = __builtin_amdgcn_mfma_f32_16x16x32_bf16(af[nt], wf[mt], acc[nt][mt], 0, 0, 0);
    }

    float bias[4];
    #pragma unroll
    for (int mt = 0; mt < 4; mt++) bias[mt] = b[wave * 64 + mt * 16 + l16];

    #pragma unroll
    for (int nt = 0; nt < 4; nt++)
        #pragma unroll
        for (int r = 0; r < 4; r++) {
            const int row = n0 + nt * 16 + q * 4 + r;   // C/D: row=quad*4+reg
            if (row >= N) continue;
            #pragma unroll
            for (int mt = 0; mt < 4; mt++) {
                const int col = wave * 64 + mt * 16 + l16;  // C/D: col=lane&15
                C[(size_t)row * 256 + col] = f2bf(lrelu(acc[nt][mt][r] + bias[mt]));
            }
        }
}

// ---------------------------------------------------------------------------
// MLP layer via MFMA: C = lrelu(A @ W^T + b), A [N,256] bf16, W [256,256] bf16.
// ---------------------------------------------------------------------------
__global__ void mlp_mfma_kernel(const unsigned short* __restrict__ A,
                                const unsigned short* __restrict__ W,
                                const float* __restrict__ b,
                                unsigned short* __restrict__ C, int N)
{
    __shared__ __align__(16) unsigned short aT[64 * 264];  // 264 = 256 + 8 pad
    const int t = threadIdx.x;
    const int n0 = blockIdx.x * 64;
    const int wave = t >> 6, lane = t & 63, q = lane >> 4, l16 = lane & 15;

    #pragma unroll
    for (int i = 0; i < 8; i++) {
        const int u = t + 256 * i;
        const int row = u >> 5, c16 = u & 31;
        const int srow = min(n0 + row, N - 1);
        *(uint4*)(aT + row * 264 + c16 * 8) = *(const uint4*)(A + (size_t)srow * 256 + c16 * 8);
    }
    __syncthreads();

    f32x4 acc[4][4] = {};
    const unsigned short* wbase = W + (wave * 64 + l16) * 256 + q * 8;
    for (int k0 = 0; k0 < 256; k0 += 32) {
        short8 af[4], wf[4];
        #pragma unroll
        for (int nt = 0; nt < 4; nt++)
            af[nt] = *(const short8*)(aT + (nt * 16 + l16) * 264 + k0 + q * 8);
        #pragma unroll
        for (int mt = 0; mt < 4; mt++)
            wf[mt] = *(const short8*)(wbase + mt * 16 * 256 + k0);
        #pragma unroll
        for (int nt = 0; nt < 4; nt++)
            #pragma unroll
            for (int mt = 0; mt < 4; mt++)
                acc[nt][mt] = __builtin_amdgcn_mfma_f32_16x16x32_bf16(af[nt], wf[mt], acc[nt][mt], 0, 0, 0);
    }

    float bias[4];
    #pragma unroll
    for (int mt = 0; mt < 4; mt++) bias[mt] = b[wave * 64 + mt * 16 + l16];

    #pragma unroll
    for (int nt = 0; nt < 4; nt++)
        #pragma unroll
        for (int r = 0; r < 4; r++) {
            const int row = n0 + nt * 16 + q * 4 + r;
            if (row >= N) continue;
            #pragma unroll
            for (int mt = 0; mt < 4; mt++) {
                const int col = wave * 64 + mt * 16 + l16;
                C[(size_t)row * 256 + col] = f2bf(lrelu(acc[nt][mt][r] + bias[mt]));
            }
        }
}

// ---------------------------------------------------------------------------
// Pred: out[n] = h[n] . w_pred + b_pred.  One wave per node; h is bf16.
// ---------------------------------------------------------------------------
__global__ void pred_kernel(const unsigned short* __restrict__ h,
                            const float* __restrict__ w,
                            const float* __restrict__ b,
                            float* __restrict__ out, int N)
{
    __shared__ float s_w[256];
    const int t = threadIdx.x;
    s_w[t] = w[t];
    __syncthreads();

    const int wave = t / 64, lane = t % 64;
    const int n = blockIdx.x * 4 + wave;
    if (n >= N) return;

    float v = 0.f;
    #pragma unroll
    for (int j = 0; j < 4; j++)
        v += bf2f(h[(size_t)n * 256 + lane + j * 64]) * s_w[lane + j * 64];

    #pragma unroll
    for (int off = 32; off > 0; off >>= 1)
        v += __shfl_down(v, off);

    if (lane == 0) out[n] = v + b[0];
}

// ---------------------------------------------------------------------------
extern "C" void kernel_launch(void* const* d_in, const int* in_sizes, int n_in,
                              void* d_out, int out_size, void* d_ws, size_t ws_size,
                              hipStream_t stream)
{
    const float* pose   = (const float*)d_in[0];
    const float* views  = (const float*)d_in[1];
    const int*   ei     = (const int*)d_in[2];
    const float* w_e1   = (const float*)d_in[3];
    const float* b_e1   = (const float*)d_in[4];
    const float* w_e2   = (const float*)d_in[5];
    const float* b_e2   = (const float*)d_in[6];
    const float* w_rel  = (const float*)d_in[7];
    const float* b_rel  = (const float*)d_in[8];
    const float* w_root = (const float*)d_in[9];
    const float* w_l1   = (const float*)d_in[10];
    const float* b_l1   = (const float*)d_in[11];
    const float* w_l2   = (const float*)d_in[12];
    const float* b_l2   = (const float*)d_in[13];
    const float* w_l3   = (const float*)d_in[14];
    const float* b_l3   = (const float*)d_in[15];
    const float* w_pred = (const float*)d_in[16];
    const float* b_pred = (const float*)d_in[17];
    float* out = (float*)d_out;

    const int N = in_sizes[0] / 3;       // 50000
    const int E = in_sizes[2] / 2;       // 4950000
    const int NB = (N + 63) >> 6;        // 782 buckets
    const int NBLK = (N + 63) / 64;      // row blocks for GEMMs

    // Workspace layout. hb0/hb1 alias pairs/sorted: graph ints are fully dead
    // (last read = gather_sum) before graphconv/mlp write hb0/hb1.
    float* x   = (float*)d_ws;                       // N*40 fp32
    float* agg = x + (size_t)N * 40;                 // N*40 fp32
    int* pairs  = (int*)(agg + (size_t)N * 40);      // NB*CAP ints (25.62 MB)
    int* sorted = pairs + (size_t)NB * CAP;          // NB*CAP ints (25.62 MB)
    unsigned short* hb0 = (unsigned short*)pairs;    // N*256 bf16 alias
    unsigned short* hb1 = (unsigned short*)sorted;   // N*256 bf16 alias
    int* gcur       = sorted + (size_t)NB * CAP;     // 1024
    int* node_start = gcur + 1024;                   // NB*64
    int* node_cnt   = node_start + NB * 64;          // NB*64
    unsigned short* Wb1 = (unsigned short*)(node_cnt + NB * 64);  // 256*256
    unsigned short* Wb2 = Wb1 + 256 * 256;
    unsigned short* Wb3 = Wb2 + 256 * 256;
    unsigned short* Wg  = Wb3 + 256 * 256;           // 256*160
    __half* xh = (__half*)(Wg + 256 * 160);          // N*40 fp16 (4 MB)

    // Weight prep (bf16)
    cvt_bf16_kernel<<<256, 256, 0, stream>>>(w_l1, Wb1, 256 * 256);
    cvt_bf16_kernel<<<256, 256, 0, stream>>>(w_l2, Wb2, 256 * 256);
    cvt_bf16_kernel<<<256, 256, 0, stream>>>(w_l3, Wb3, 256 * 256);
    build_wg_kernel<<<160, 256, 0, stream>>>(w_rel, w_root, Wg);

    encoder_kernel<<<(N + 3) / 4, 256, 0, stream>>>(pose, views, w_e1, b_e1, w_e2, b_e2, x, xh, N);

    hipMemsetAsync(gcur, 0, (size_t)NB * sizeof(int), stream);
    bin_kernel<<<(E + EPB - 1) / EPB, 256, 0, stream>>>(ei, gcur, pairs, E, NB);
    bucket_sort_kernel<<<NB, 256, 0, stream>>>(gcur, pairs, sorted, node_start, node_cnt);
    gather_sum_kernel<<<NB * 16, 256, 0, stream>>>(sorted, node_start, node_cnt, xh, agg, N);

    graphconv_mfma_kernel<<<NBLK, 256, 0, stream>>>(agg, x, Wg, b_rel, hb0, N);
    mlp_mfma_kernel<<<NBLK, 256, 0, stream>>>(hb0, Wb1, b_l1, hb1, N);
    mlp_mfma_kernel<<<NBLK, 256, 0, stream>>>(hb1, Wb2, b_l2, hb0, N);
    mlp_mfma_kernel<<<NBLK, 256, 0, stream>>>(hb0, Wb3, b_l3, hb1, N);
    pred_kernel<<<(N + 3) / 4, 256, 0, stream>>>(hb1, w_pred, b_pred, out, N);
}

// Round 8
// 455.881 us; speedup vs baseline: 4.6252x; 1.0510x over previous
//
#include <hip/hip_runtime.h>
#include <hip/hip_fp16.h>

#define NEG_SLOPE 0.1f
__device__ __forceinline__ float lrelu(float v) { return v >= 0.f ? v : NEG_SLOPE * v; }

constexpr int CAP = 8192;   // per-bucket capacity (mean 6330 + 12-align pads < 7200)
constexpr int EPB = 4096;   // edges per bin block (16 per thread, contiguous)

typedef __attribute__((ext_vector_type(8))) short short8;   // 8 bf16 (4 VGPRs)
typedef __attribute__((ext_vector_type(4))) float f32x4;    // MFMA accum

__device__ __forceinline__ unsigned short f2bf(float f) {   // RNE
    union { float f; unsigned u; } v; v.f = f;
    const unsigned r = v.u + 0x7FFF + ((v.u >> 16) & 1);
    return (unsigned short)(r >> 16);
}
__device__ __forceinline__ float bf2f(unsigned short h) {
    union { unsigned u; float f; } v; v.u = ((unsigned)h) << 16;
    return v.f;
}

// ---------------------------------------------------------------------------
// Weight prep: fp32 -> bf16 (per call; no cross-call state allowed).
// ---------------------------------------------------------------------------
__global__ void cvt_bf16_kernel(const float* __restrict__ src, unsigned short* __restrict__ dst, int n)
{
    const int i = blockIdx.x * blockDim.x + threadIdx.x;
    if (i < n) dst[i] = f2bf(src[i]);
}

// Wg[256][160] = [w_rel | w_root | w_rel | w_root] bf16 (hi/lo A-split shares W).
__global__ void build_wg_kernel(const float* __restrict__ w_rel, const float* __restrict__ w_root,
                                unsigned short* __restrict__ Wg)
{
    const int i = blockIdx.x * blockDim.x + threadIdx.x;
    if (i >= 256 * 160) return;
    const int m = i / 160, c = i % 160;
    const int k = c % 80;
    const float v = (k < 40) ? w_rel[m * 40 + k] : w_root[m * 40 + (k - 40)];
    Wg[i] = f2bf(v);
}

// ---------------------------------------------------------------------------
// Encoder: one WAVE per node, 4 nodes per 256-thread block. conv1 windows
// direct from global (registers), c1 even/odd-deinterleaved in LDS so conv2's
// stride-2 taps are conflict-free.
// ---------------------------------------------------------------------------
__global__ __launch_bounds__(256) void encoder_kernel(
        const float* __restrict__ pose,
        const float* __restrict__ views,
        const float* __restrict__ w1, const float* __restrict__ b1,
        const float* __restrict__ w2, const float* __restrict__ b2,
        float* __restrict__ x, __half* __restrict__ xh, int N)
{
    __shared__ float s_w1[81];
    __shared__ float s_b1[9];
    __shared__ float s_w2[27];
    __shared__ float s_b2[1];
    __shared__ float s_c1[4][9][80];   // [wave][oc][(p&1)*40 + (p>>1)]

    const int t = threadIdx.x;
    if (t < 81) s_w1[t] = w1[t];
    if (t >= 96 && t < 105) s_b1[t - 96] = b1[t - 96];
    if (t >= 128 && t < 155) s_w2[t - 128] = w2[t - 128];
    if (t == 240) s_b2[0] = b2[0];
    __syncthreads();

    const int w = t >> 6, lane = t & 63;
    const int n = min(blockIdx.x * 4 + w, N - 1);   // clamp: dup writes benign
    const float* __restrict__ vin = views + (size_t)n * 453;

    #pragma unroll
    for (int pass = 0; pass < 2; pass++) {
        const int p = pass * 64 + lane;
        if (p < 75) {
            float e[3], o[3], e1[3];
            #pragma unroll
            for (int ic = 0; ic < 3; ic++) {
                const float* ci = vin + ic * 151 + 2 * p;
                e[ic] = ci[0]; o[ic] = ci[1]; e1[ic] = ci[2];
            }
            #pragma unroll
            for (int oc = 0; oc < 9; oc++) {
                float v = s_b1[oc];
                #pragma unroll
                for (int ic = 0; ic < 3; ic++)
                    v += s_w1[oc * 9 + ic * 3 + 0] * e[ic]
                       + s_w1[oc * 9 + ic * 3 + 1] * o[ic]
                       + s_w1[oc * 9 + ic * 3 + 2] * e1[ic];
                s_c1[w][oc][(p & 1) * 40 + (p >> 1)] = lrelu(v);
            }
        }
    }
    __syncthreads();

    float outv = 0.f;
    if (lane < 3) {
        outv = pose[(size_t)n * 3 + lane];
    } else if (lane < 40) {
        const int ow = lane - 3;
        float v = s_b2[0];
        #pragma unroll
        for (int ic = 0; ic < 9; ic++)
            v += s_w2[ic * 3 + 0] * s_c1[w][ic][ow]
               + s_w2[ic * 3 + 1] * s_c1[w][ic][40 + ow]
               + s_w2[ic * 3 + 2] * s_c1[w][ic][ow + 1];
        outv = lrelu(v);
    }
    if (lane < 40) {
        x[(size_t)n * 40 + lane] = outv;
        xh[(size_t)n * 40 + lane] = __float2half(outv);
    }
}

// ---------------------------------------------------------------------------
// Coarse binning: bucket = dst>>6, packed src|dstLocal<<16, one global atomic
// per (block,bucket).
// ---------------------------------------------------------------------------
__global__ void bin_kernel(const int* __restrict__ ei, int* __restrict__ gcur,
                           int* __restrict__ pairs, int E, int NB)
{
    __shared__ int s_hist[1024];
    __shared__ int s_base[1024];
    const int t = threadIdx.x;
    const int e0 = blockIdx.x * EPB + t * 16;

    for (int i = t; i < NB; i += 256) s_hist[i] = 0;
    __syncthreads();

    int pk[16], mt[16];
    auto proc = [&](int j, int sv, int dv) {
        const int b = dv >> 6;
        const int r = atomicAdd(&s_hist[b], 1);
        pk[j] = sv | ((dv & 63) << 16);
        mt[j] = b | (r << 10);
    };

    if (e0 + 16 <= E) {
        #pragma unroll
        for (int q = 0; q < 4; q++) {
            const int4 sv = *(const int4*)(ei + e0 + 4 * q);
            const int4 dv = *(const int4*)(ei + E + e0 + 4 * q);
            proc(4 * q + 0, sv.x, dv.x);
            proc(4 * q + 1, sv.y, dv.y);
            proc(4 * q + 2, sv.z, dv.z);
            proc(4 * q + 3, sv.w, dv.w);
        }
    } else {
        #pragma unroll
        for (int j = 0; j < 16; j++) {
            mt[j] = -1;
            const int e = e0 + j;
            if (e < E) proc(j, ei[e], ei[E + e]);
        }
    }
    __syncthreads();

    for (int i = t; i < NB; i += 256) {
        const int c = s_hist[i];
        if (c > 0) s_base[i] = atomicAdd(&gcur[i], c);
    }
    __syncthreads();

    #pragma unroll
    for (int j = 0; j < 16; j++) {
        if (mt[j] >= 0) {
            const int b = mt[j] & 1023;
            const int pos = s_base[b] + (mt[j] >> 10);
            if (pos < CAP) pairs[b * CAP + pos] = pk[j];
        }
    }
}

// ---------------------------------------------------------------------------
// Per-bucket exact counting sort (LDS only). Runs 12-aligned, pads filled with
// sentinel src=N -> gather adds the explicit zero row, no tail masking needed.
// ---------------------------------------------------------------------------
__global__ void bucket_sort_kernel(const int* __restrict__ gcur,
                                   const int* __restrict__ pairs,
                                   int* __restrict__ sorted,
                                   int* __restrict__ node_start,
                                   int* __restrict__ node_cnt, int N)
{
    __shared__ int s_cnt[64], s_off[64], s_cur[64];
    const int b = blockIdx.x;
    const int t = threadIdx.x;
    const int cnt = min(gcur[b], CAP);
    const int* __restrict__ pr = pairs + b * CAP;
    int* __restrict__ so = sorted + (size_t)b * CAP;

    if (t < 64) s_cnt[t] = 0;
    __syncthreads();
    for (int i = t; i < cnt; i += 256)
        atomicAdd(&s_cnt[pr[i] >> 16], 1);
    __syncthreads();

    if (t < 64) {   // exclusive scan of 12-aligned counts
        const int c = s_cnt[t];
        const int p = ((c + 11) / 12) * 12;
        int sc = p;
        #pragma unroll
        for (int d = 1; d < 64; d <<= 1) {
            const int u = __shfl_up(sc, d);
            if (t >= d) sc += u;
        }
        const int excl = sc - p;
        s_off[t] = excl;
        s_cur[t] = excl;
        node_start[b * 64 + t] = b * CAP + excl;
        node_cnt[b * 64 + t] = c;
    }
    __syncthreads();

    if (t < 64) {   // pad fill: sentinel src=N (zero row in xh)
        const int e0 = s_off[t] + s_cnt[t];
        const int e1 = s_off[t] + ((s_cnt[t] + 11) / 12) * 12;
        for (int i = e0; i < e1 && i < CAP; i++) so[i] = N;
    }
    for (int i = t; i < cnt; i += 256) {
        const int p = pr[i];
        const int pos = atomicAdd(&s_cur[p >> 16], 1);
        if (pos < CAP) so[pos] = p & 0xFFFF;
    }
}

// ---------------------------------------------------------------------------
// Segment sum v3: one wave per node, 3 edges per iteration. Lane l<60:
// edge-slot l/20, feature-pair l%20 as packed __half2 (4B/lane). 12 edges per
// unrolled iter = 4 idx dwords + 4 half2 loads. Pads hit the zero row (src=N)
// so there is no tail masking. Cross-slot shuffle reduce at the end.
// ---------------------------------------------------------------------------
__global__ void gather_sum_kernel(const int* __restrict__ sorted,
                                  const int* __restrict__ node_start,
                                  const int* __restrict__ node_cnt,
                                  const __half* __restrict__ xh,
                                  float* __restrict__ agg, int N)
{
    const int n = blockIdx.x * 4 + (threadIdx.x >> 6);
    const int lane = threadIdx.x & 63;
    if (n >= N) return;

    const int start = node_start[n];
    const int cntp = ((node_cnt[n] + 11) / 12) * 12;
    const int slot = min(lane / 20, 2);          // lanes 60..63 duplicate slot 2
    const int fp = lane % 20;
    const int* __restrict__ srt = sorted + start + slot;
    const __half* __restrict__ xb = xh + 2 * fp;

    float accx = 0.f, accy = 0.f;
    for (int e = 0; e < cntp; e += 12) {
        const int i0 = srt[e];
        const int i1 = srt[e + 3];
        const int i2 = srt[e + 6];
        const int i3 = srt[e + 9];
        const __half2 h0 = *(const __half2*)(xb + i0 * 40);
        const __half2 h1 = *(const __half2*)(xb + i1 * 40);
        const __half2 h2 = *(const __half2*)(xb + i2 * 40);
        const __half2 h3 = *(const __half2*)(xb + i3 * 40);
        const float2 f0 = __half22float2(h0);
        const float2 f1 = __half22float2(h1);
        const float2 f2 = __half22float2(h2);
        const float2 f3 = __half22float2(h3);
        accx += (f0.x + f1.x) + (f2.x + f3.x);
        accy += (f0.y + f1.y) + (f2.y + f3.y);
    }

    // cross-slot reduce: lane f (<20) += lanes f+20, f+40
    const float ax1 = __shfl(accx, fp + 20);
    const float ay1 = __shfl(accy, fp + 20);
    const float ax2 = __shfl(accx, fp + 40);
    const float ay2 = __shfl(accy, fp + 40);
    if (lane < 20) {
        float2 o;
        o.x = accx + ax1 + ax2;
        o.y = accy + ay1 + ay2;
        *(float2*)(agg + (size_t)n * 40 + 2 * fp) = o;
    }
}

// ---------------------------------------------------------------------------
// GraphConv via MFMA, K=160: A = [agg_hi|x_hi|agg_lo|x_lo] bf16 (hi/lo split
// for near-fp32 A-side), W = [w_rel|w_root|w_rel|w_root] bf16.
// ---------------------------------------------------------------------------
__global__ void graphconv_mfma_kernel(const float* __restrict__ agg,
                                      const float* __restrict__ x,
                                      const unsigned short* __restrict__ Wg,
                                      const float* __restrict__ b,
                                      unsigned short* __restrict__ C, int N)
{
    __shared__ __align__(16) unsigned short aT[64 * 168];  // 168 = 160 + 8 pad
    const int t = threadIdx.x;
    const int n0 = blockIdx.x * 64;
    const int wave = t >> 6, lane = t & 63, q = lane >> 4, l16 = lane & 15;

    for (int u = t; u < 640; u += 256) {
        const int row = u / 10, c = (u % 10) * 4;
        const int srow = min(n0 + row, N - 1);
        const float4 fa = *(const float4*)(agg + (size_t)srow * 40 + c);
        const float4 fx = *(const float4*)(x + (size_t)srow * 40 + c);
        const float av[4] = {fa.x, fa.y, fa.z, fa.w};
        const float xv[4] = {fx.x, fx.y, fx.z, fx.w};
        ushort4 ha, la, hx, lx;
        ha.x = f2bf(av[0]); la.x = f2bf(av[0] - bf2f(ha.x));
        ha.y = f2bf(av[1]); la.y = f2bf(av[1] - bf2f(ha.y));
        ha.z = f2bf(av[2]); la.z = f2bf(av[2] - bf2f(ha.z));
        ha.w = f2bf(av[3]); la.w = f2bf(av[3] - bf2f(ha.w));
        hx.x = f2bf(xv[0]); lx.x = f2bf(xv[0] - bf2f(hx.x));
        hx.y = f2bf(xv[1]); lx.y = f2bf(xv[1] - bf2f(hx.y));
        hx.z = f2bf(xv[2]); lx.z = f2bf(xv[2] - bf2f(hx.z));
        hx.w = f2bf(xv[3]); lx.w = f2bf(xv[3] - bf2f(hx.w));
        unsigned short* rp = aT + row * 168;
        *(ushort4*)(rp + c)       = ha;
        *(ushort4*)(rp + 40 + c)  = hx;
        *(ushort4*)(rp + 80 + c)  = la;
        *(ushort4*)(rp + 120 + c) = lx;
    }
    __syncthreads();

    f32x4 acc[4][4] = {};
    for (int k0 = 0; k0 < 160; k0 += 32) {
        short8 af[4], wf[4];
        #pragma unroll
        for (int nt = 0; nt < 4; nt++)
            af[nt] = *(const short8*)(aT + (nt * 16 + l16) * 168 + k0 + q * 8);
        #pragma unroll
        for (int mt = 0; mt < 4; mt++)
            wf[mt] = *(const short8*)(Wg + (wave * 64 + mt * 16 + l16) * 160 + k0 + q * 8);
        #pragma unroll
        for (int nt = 0; nt < 4; nt++)
            #pragma unroll
            for (int mt = 0; mt < 4; mt++)
                acc[nt][mt] = __builtin_amdgcn_mfma_f32_16x16x32_bf16(af[nt], wf[mt], acc[nt][mt], 0, 0, 0);
    }

    float bias[4];
    #pragma unroll
    for (int mt = 0; mt < 4; mt++) bias[mt] = b[wave * 64 + mt * 16 + l16];

    #pragma unroll
    for (int nt = 0; nt < 4; nt++)
        #pragma unroll
        for (int r = 0; r < 4; r++) {
            const int row = n0 + nt * 16 + q * 4 + r;   // C/D: row=quad*4+reg
            if (row >= N) continue;
            #pragma unroll
            for (int mt = 0; mt < 4; mt++) {
                const int col = wave * 64 + mt * 16 + l16;  // C/D: col=lane&15
                C[(size_t)row * 256 + col] = f2bf(lrelu(acc[nt][mt][r] + bias[mt]));
            }
        }
}

// ---------------------------------------------------------------------------
// MLP layer via MFMA: C = lrelu(A @ W^T + b), A [N,256] bf16, W [256,256] bf16.
// ---------------------------------------------------------------------------
__global__ void mlp_mfma_kernel(const unsigned short* __restrict__ A,
                                const unsigned short* __restrict__ W,
                                const float* __restrict__ b,
                                unsigned short* __restrict__ C, int N)
{
    __shared__ __align__(16) unsigned short aT[64 * 264];  // 264 = 256 + 8 pad
    const int t = threadIdx.x;
    const int n0 = blockIdx.x * 64;
    const int wave = t >> 6, lane = t & 63, q = lane >> 4, l16 = lane & 15;

    #pragma unroll
    for (int i = 0; i < 8; i++) {
        const int u = t + 256 * i;
        const int row = u >> 5, c16 = u & 31;
        const int srow = min(n0 + row, N - 1);
        *(uint4*)(aT + row * 264 + c16 * 8) = *(const uint4*)(A + (size_t)srow * 256 + c16 * 8);
    }
    __syncthreads();

    f32x4 acc[4][4] = {};
    const unsigned short* wbase = W + (wave * 64 + l16) * 256 + q * 8;
    for (int k0 = 0; k0 < 256; k0 += 32) {
        short8 af[4], wf[4];
        #pragma unroll
        for (int nt = 0; nt < 4; nt++)
            af[nt] = *(const short8*)(aT + (nt * 16 + l16) * 264 + k0 + q * 8);
        #pragma unroll
        for (int mt = 0; mt < 4; mt++)
            wf[mt] = *(const short8*)(wbase + mt * 16 * 256 + k0);
        #pragma unroll
        for (int nt = 0; nt < 4; nt++)
            #pragma unroll
            for (int mt = 0; mt < 4; mt++)
                acc[nt][mt] = __builtin_amdgcn_mfma_f32_16x16x32_bf16(af[nt], wf[mt], acc[nt][mt], 0, 0, 0);
    }

    float bias[4];
    #pragma unroll
    for (int mt = 0; mt < 4; mt++) bias[mt] = b[wave * 64 + mt * 16 + l16];

    #pragma unroll
    for (int nt = 0; nt < 4; nt++)
        #pragma unroll
        for (int r = 0; r < 4; r++) {
            const int row = n0 + nt * 16 + q * 4 + r;
            if (row >= N) continue;
            #pragma unroll
            for (int mt = 0; mt < 4; mt++) {
                const int col = wave * 64 + mt * 16 + l16;
                C[(size_t)row * 256 + col] = f2bf(lrelu(acc[nt][mt][r] + bias[mt]));
            }
        }
}

// ---------------------------------------------------------------------------
// Pred: out[n] = h[n] . w_pred + b_pred.  One wave per node; h is bf16.
// ---------------------------------------------------------------------------
__global__ void pred_kernel(const unsigned short* __restrict__ h,
                            const float* __restrict__ w,
                            const float* __restrict__ b,
                            float* __restrict__ out, int N)
{
    __shared__ float s_w[256];
    const int t = threadIdx.x;
    s_w[t] = w[t];
    __syncthreads();

    const int wave = t / 64, lane = t % 64;
    const int n = blockIdx.x * 4 + wave;
    if (n >= N) return;

    float v = 0.f;
    #pragma unroll
    for (int j = 0; j < 4; j++)
        v += bf2f(h[(size_t)n * 256 + lane + j * 64]) * s_w[lane + j * 64];

    #pragma unroll
    for (int off = 32; off > 0; off >>= 1)
        v += __shfl_down(v, off);

    if (lane == 0) out[n] = v + b[0];
}

// ---------------------------------------------------------------------------
extern "C" void kernel_launch(void* const* d_in, const int* in_sizes, int n_in,
                              void* d_out, int out_size, void* d_ws, size_t ws_size,
                              hipStream_t stream)
{
    const float* pose   = (const float*)d_in[0];
    const float* views  = (const float*)d_in[1];
    const int*   ei     = (const int*)d_in[2];
    const float* w_e1   = (const float*)d_in[3];
    const float* b_e1   = (const float*)d_in[4];
    const float* w_e2   = (const float*)d_in[5];
    const float* b_e2   = (const float*)d_in[6];
    const float* w_rel  = (const float*)d_in[7];
    const float* b_rel  = (const float*)d_in[8];
    const float* w_root = (const float*)d_in[9];
    const float* w_l1   = (const float*)d_in[10];
    const float* b_l1   = (const float*)d_in[11];
    const float* w_l2   = (const float*)d_in[12];
    const float* b_l2   = (const float*)d_in[13];
    const float* w_l3   = (const float*)d_in[14];
    const float* b_l3   = (const float*)d_in[15];
    const float* w_pred = (const float*)d_in[16];
    const float* b_pred = (const float*)d_in[17];
    float* out = (float*)d_out;

    const int N = in_sizes[0] / 3;       // 50000
    const int E = in_sizes[2] / 2;       // 4950000
    const int NB = (N + 63) >> 6;        // 782 buckets
    const int NBLK = (N + 63) / 64;      // row blocks for GEMMs

    // Workspace layout. hb0/hb1 alias pairs/sorted: graph ints are fully dead
    // (last read = gather_sum) before graphconv/mlp write hb0/hb1.
    float* x   = (float*)d_ws;                       // N*40 fp32
    float* agg = x + (size_t)N * 40;                 // N*40 fp32
    int* pairs  = (int*)(agg + (size_t)N * 40);      // NB*CAP ints (25.62 MB)
    int* sorted = pairs + (size_t)NB * CAP;          // NB*CAP ints (25.62 MB)
    unsigned short* hb0 = (unsigned short*)pairs;    // N*256 bf16 alias
    unsigned short* hb1 = (unsigned short*)sorted;   // N*256 bf16 alias
    int* gcur       = sorted + (size_t)NB * CAP;     // 1024
    int* node_start = gcur + 1024;                   // NB*64
    int* node_cnt   = node_start + NB * 64;          // NB*64
    unsigned short* Wb1 = (unsigned short*)(node_cnt + NB * 64);  // 256*256
    unsigned short* Wb2 = Wb1 + 256 * 256;
    unsigned short* Wb3 = Wb2 + 256 * 256;
    unsigned short* Wg  = Wb3 + 256 * 256;           // 256*160
    __half* xh = (__half*)(Wg + 256 * 160);          // (N+1)*40 fp16; row N = zeros

    // Weight prep (bf16)
    cvt_bf16_kernel<<<256, 256, 0, stream>>>(w_l1, Wb1, 256 * 256);
    cvt_bf16_kernel<<<256, 256, 0, stream>>>(w_l2, Wb2, 256 * 256);
    cvt_bf16_kernel<<<256, 256, 0, stream>>>(w_l3, Wb3, 256 * 256);
    build_wg_kernel<<<160, 256, 0, stream>>>(w_rel, w_root, Wg);

    encoder_kernel<<<(N + 3) / 4, 256, 0, stream>>>(pose, views, w_e1, b_e1, w_e2, b_e2, x, xh, N);
    hipMemsetAsync(xh + (size_t)N * 40, 0, 40 * sizeof(__half), stream);  // sentinel row

    hipMemsetAsync(gcur, 0, (size_t)NB * sizeof(int), stream);
    bin_kernel<<<(E + EPB - 1) / EPB, 256, 0, stream>>>(ei, gcur, pairs, E, NB);
    bucket_sort_kernel<<<NB, 256, 0, stream>>>(gcur, pairs, sorted, node_start, node_cnt, N);
    gather_sum_kernel<<<NB * 16, 256, 0, stream>>>(sorted, node_start, node_cnt, xh, agg, N);

    graphconv_mfma_kernel<<<NBLK, 256, 0, stream>>>(agg, x, Wg, b_rel, hb0, N);
    mlp_mfma_kernel<<<NBLK, 256, 0, stream>>>(hb0, Wb1, b_l1, hb1, N);
    mlp_mfma_kernel<<<NBLK, 256, 0, stream>>>(hb1, Wb2, b_l2, hb0, N);
    mlp_mfma_kernel<<<NBLK, 256, 0, stream>>>(hb0, Wb3, b_l3, hb1, N);
    pred_kernel<<<(N + 3) / 4, 256, 0, stream>>>(hb1, w_pred, b_pred, out, N);
}

// Round 9
// 438.547 us; speedup vs baseline: 4.8080x; 1.0395x over previous
//
#include <hip/hip_runtime.h>
#include <hip/hip_fp16.h>

#define NEG_SLOPE 0.1f
__device__ __forceinline__ float lrelu(float v) { return v >= 0.f ? v : NEG_SLOPE * v; }

constexpr int CAP = 8192;   // per-bucket capacity (mean 6330 + 12-align pads < 7200)
constexpr int EPB = 8192;   // edges per bin block (16 per thread, 512 threads)

typedef __attribute__((ext_vector_type(8))) short short8;   // 8 bf16 (4 VGPRs)
typedef __attribute__((ext_vector_type(4))) float f32x4;    // MFMA accum

__device__ __forceinline__ unsigned short f2bf(float f) {   // RNE
    union { float f; unsigned u; } v; v.f = f;
    const unsigned r = v.u + 0x7FFF + ((v.u >> 16) & 1);
    return (unsigned short)(r >> 16);
}
__device__ __forceinline__ float bf2f(unsigned short h) {
    union { unsigned u; float f; } v; v.u = ((unsigned)h) << 16;
    return v.f;
}

// ---------------------------------------------------------------------------
// Weight prep: fp32 -> bf16 (per call; no cross-call state allowed).
// ---------------------------------------------------------------------------
__global__ void cvt_bf16_kernel(const float* __restrict__ src, unsigned short* __restrict__ dst, int n)
{
    const int i = blockIdx.x * blockDim.x + threadIdx.x;
    if (i < n) dst[i] = f2bf(src[i]);
}

// Wg[256][160] = [w_rel | w_root | w_rel | w_root] bf16 (hi/lo A-split shares W).
__global__ void build_wg_kernel(const float* __restrict__ w_rel, const float* __restrict__ w_root,
                                unsigned short* __restrict__ Wg)
{
    const int i = blockIdx.x * blockDim.x + threadIdx.x;
    if (i >= 256 * 160) return;
    const int m = i / 160, c = i % 160;
    const int k = c % 80;
    const float v = (k < 40) ? w_rel[m * 40 + k] : w_root[m * 40 + (k - 40)];
    Wg[i] = f2bf(v);
}

// ---------------------------------------------------------------------------
// Encoder: one WAVE per node, 4 nodes per 256-thread block. conv1 windows
// direct from global (registers), c1 even/odd-deinterleaved in LDS so conv2's
// stride-2 taps are conflict-free.
// ---------------------------------------------------------------------------
__global__ __launch_bounds__(256) void encoder_kernel(
        const float* __restrict__ pose,
        const float* __restrict__ views,
        const float* __restrict__ w1, const float* __restrict__ b1,
        const float* __restrict__ w2, const float* __restrict__ b2,
        float* __restrict__ x, __half* __restrict__ xh, int N)
{
    __shared__ float s_w1[81];
    __shared__ float s_b1[9];
    __shared__ float s_w2[27];
    __shared__ float s_b2[1];
    __shared__ float s_c1[4][9][80];   // [wave][oc][(p&1)*40 + (p>>1)]

    const int t = threadIdx.x;
    if (t < 81) s_w1[t] = w1[t];
    if (t >= 96 && t < 105) s_b1[t - 96] = b1[t - 96];
    if (t >= 128 && t < 155) s_w2[t - 128] = w2[t - 128];
    if (t == 240) s_b2[0] = b2[0];
    __syncthreads();

    const int w = t >> 6, lane = t & 63;
    const int n = min(blockIdx.x * 4 + w, N - 1);   // clamp: dup writes benign
    const float* __restrict__ vin = views + (size_t)n * 453;

    #pragma unroll
    for (int pass = 0; pass < 2; pass++) {
        const int p = pass * 64 + lane;
        if (p < 75) {
            float e[3], o[3], e1[3];
            #pragma unroll
            for (int ic = 0; ic < 3; ic++) {
                const float* ci = vin + ic * 151 + 2 * p;
                e[ic] = ci[0]; o[ic] = ci[1]; e1[ic] = ci[2];
            }
            #pragma unroll
            for (int oc = 0; oc < 9; oc++) {
                float v = s_b1[oc];
                #pragma unroll
                for (int ic = 0; ic < 3; ic++)
                    v += s_w1[oc * 9 + ic * 3 + 0] * e[ic]
                       + s_w1[oc * 9 + ic * 3 + 1] * o[ic]
                       + s_w1[oc * 9 + ic * 3 + 2] * e1[ic];
                s_c1[w][oc][(p & 1) * 40 + (p >> 1)] = lrelu(v);
            }
        }
    }
    __syncthreads();

    float outv = 0.f;
    if (lane < 3) {
        outv = pose[(size_t)n * 3 + lane];
    } else if (lane < 40) {
        const int ow = lane - 3;
        float v = s_b2[0];
        #pragma unroll
        for (int ic = 0; ic < 9; ic++)
            v += s_w2[ic * 3 + 0] * s_c1[w][ic][ow]
               + s_w2[ic * 3 + 1] * s_c1[w][ic][40 + ow]
               + s_w2[ic * 3 + 2] * s_c1[w][ic][ow + 1];
        outv = lrelu(v);
    }
    if (lane < 40) {
        x[(size_t)n * 40 + lane] = outv;
        xh[(size_t)n * 40 + lane] = __float2half(outv);
    }
}

// ---------------------------------------------------------------------------
// Coarse binning v2 (512 thr, 8192 edges/block): rank via LDS histogram,
// STAGE packed edges in LDS ordered by bucket (block-local scan), then write
// out linearly -> piecewise-contiguous global stores (~10-edge runs) instead
// of random 4B scatter. One global atomic per (block,bucket).
// ---------------------------------------------------------------------------
__global__ __launch_bounds__(512) void bin_kernel(
        const int* __restrict__ ei, int* __restrict__ gcur,
        int* __restrict__ pairs, int E, int NB)
{
    __shared__ int s_hist[1024];
    __shared__ int s_loff[1024];
    __shared__ int s_base[1024];
    __shared__ int s_wave8[8];
    __shared__ int s_pk[EPB];                 // 32 KB
    __shared__ unsigned short s_bkt[EPB];     // 16 KB
    const int t = threadIdx.x;
    const int lane = t & 63, wid = t >> 6;    // 8 waves
    const int e0 = blockIdx.x * EPB + t * 16;
    const int tot = min(E - blockIdx.x * EPB, EPB);

    for (int i = t; i < 1024; i += 512) s_hist[i] = 0;
    __syncthreads();

    int pk[16], mt[16];
    auto proc = [&](int j, int sv, int dv) {
        const int b = dv >> 6;
        const int r = atomicAdd(&s_hist[b], 1);   // local rank (LDS atomic)
        pk[j] = sv | ((dv & 63) << 16);
        mt[j] = b | (r << 10);                    // b<1024, r<8192 -> 23 bits
    };

    if (e0 + 16 <= E) {
        #pragma unroll
        for (int q = 0; q < 4; q++) {
            const int4 sv = *(const int4*)(ei + e0 + 4 * q);
            const int4 dv = *(const int4*)(ei + E + e0 + 4 * q);
            proc(4 * q + 0, sv.x, dv.x);
            proc(4 * q + 1, sv.y, dv.y);
            proc(4 * q + 2, sv.z, dv.z);
            proc(4 * q + 3, sv.w, dv.w);
        }
    } else {
        #pragma unroll
        for (int j = 0; j < 16; j++) {
            mt[j] = -1;
            const int e = e0 + j;
            if (e < E) proc(j, ei[e], ei[E + e]);
        }
    }
    __syncthreads();

    // exclusive scan of s_hist[0..1023] -> s_loff (two 512-chunks with carry)
    int carry = 0;
    #pragma unroll
    for (int base = 0; base < 1024; base += 512) {
        const int i = base + t;
        const int v = s_hist[i];
        int sc = v;
        #pragma unroll
        for (int d = 1; d < 64; d <<= 1) {
            const int u = __shfl_up(sc, d);
            if (lane >= d) sc += u;
        }
        if (lane == 63) s_wave8[wid] = sc;
        __syncthreads();
        if (wid == 0) {
            int wv = (lane < 8) ? s_wave8[lane] : 0;
            #pragma unroll
            for (int d = 1; d < 8; d <<= 1) {
                const int u = __shfl_up(wv, d);
                if (lane >= d) wv += u;
            }
            if (lane < 8) s_wave8[lane] = wv;
        }
        __syncthreads();
        const int waveoff = (wid > 0) ? s_wave8[wid - 1] : 0;
        s_loff[i] = carry + waveoff + sc - v;
        const int chunk_tot = s_wave8[7];
        __syncthreads();
        carry += chunk_tot;
    }

    // reserve global runs
    for (int i = t; i < NB; i += 512) {
        const int c = s_hist[i];
        if (c > 0) s_base[i] = atomicAdd(&gcur[i], c);
    }
    __syncthreads();

    // stage into LDS, bucket-ordered
    #pragma unroll
    for (int j = 0; j < 16; j++) {
        if (mt[j] >= 0) {
            const int b = mt[j] & 1023;
            const int pos = s_loff[b] + (mt[j] >> 10);
            s_pk[pos] = pk[j];
            s_bkt[pos] = (unsigned short)b;
        }
    }
    __syncthreads();

    // linear write-out: piecewise-contiguous global runs
    for (int i = t; i < tot; i += 512) {
        const int b = s_bkt[i];
        const int p = s_base[b] + (i - s_loff[b]);
        if (p < CAP) pairs[b * CAP + p] = s_pk[i];
    }
}

// ---------------------------------------------------------------------------
// Per-bucket exact counting sort (LDS only). Runs 12-aligned, pads filled with
// sentinel src=N -> gather adds the explicit zero row, no tail masking needed.
// ---------------------------------------------------------------------------
__global__ void bucket_sort_kernel(const int* __restrict__ gcur,
                                   const int* __restrict__ pairs,
                                   int* __restrict__ sorted,
                                   int* __restrict__ node_start,
                                   int* __restrict__ node_cnt, int N)
{
    __shared__ int s_cnt[64], s_off[64], s_cur[64];
    const int b = blockIdx.x;
    const int t = threadIdx.x;
    const int cnt = min(gcur[b], CAP);
    const int* __restrict__ pr = pairs + b * CAP;
    int* __restrict__ so = sorted + (size_t)b * CAP;

    if (t < 64) s_cnt[t] = 0;
    __syncthreads();
    for (int i = t; i < cnt; i += 256)
        atomicAdd(&s_cnt[pr[i] >> 16], 1);
    __syncthreads();

    if (t < 64) {   // exclusive scan of 12-aligned counts
        const int c = s_cnt[t];
        const int p = ((c + 11) / 12) * 12;
        int sc = p;
        #pragma unroll
        for (int d = 1; d < 64; d <<= 1) {
            const int u = __shfl_up(sc, d);
            if (t >= d) sc += u;
        }
        const int excl = sc - p;
        s_off[t] = excl;
        s_cur[t] = excl;
        node_start[b * 64 + t] = b * CAP + excl;
        node_cnt[b * 64 + t] = c;
    }
    __syncthreads();

    if (t < 64) {   // pad fill: sentinel src=N (zero row in xh)
        const int e0 = s_off[t] + s_cnt[t];
        const int e1 = s_off[t] + ((s_cnt[t] + 11) / 12) * 12;
        for (int i = e0; i < e1 && i < CAP; i++) so[i] = N;
    }
    for (int i = t; i < cnt; i += 256) {
        const int p = pr[i];
        const int pos = atomicAdd(&s_cur[p >> 16], 1);
        if (pos < CAP) so[pos] = p & 0xFFFF;
    }
}

// ---------------------------------------------------------------------------
// Segment sum: one wave per node, 3 edges per iteration, packed __half2 lanes.
// Pads hit the zero row (src=N) so there is no tail masking.
// ---------------------------------------------------------------------------
__global__ void gather_sum_kernel(const int* __restrict__ sorted,
                                  const int* __restrict__ node_start,
                                  const int* __restrict__ node_cnt,
                                  const __half* __restrict__ xh,
                                  float* __restrict__ agg, int N)
{
    const int n = blockIdx.x * 4 + (threadIdx.x >> 6);
    const int lane = threadIdx.x & 63;
    if (n >= N) return;

    const int start = node_start[n];
    const int cntp = ((node_cnt[n] + 11) / 12) * 12;
    const int slot = min(lane / 20, 2);          // lanes 60..63 duplicate slot 2
    const int fp = lane % 20;
    const int* __restrict__ srt = sorted + start + slot;
    const __half* __restrict__ xb = xh + 2 * fp;

    float accx = 0.f, accy = 0.f;
    for (int e = 0; e < cntp; e += 12) {
        const int i0 = srt[e];
        const int i1 = srt[e + 3];
        const int i2 = srt[e + 6];
        const int i3 = srt[e + 9];
        const __half2 h0 = *(const __half2*)(xb + i0 * 40);
        const __half2 h1 = *(const __half2*)(xb + i1 * 40);
        const __half2 h2 = *(const __half2*)(xb + i2 * 40);
        const __half2 h3 = *(const __half2*)(xb + i3 * 40);
        const float2 f0 = __half22float2(h0);
        const float2 f1 = __half22float2(h1);
        const float2 f2 = __half22float2(h2);
        const float2 f3 = __half22float2(h3);
        accx += (f0.x + f1.x) + (f2.x + f3.x);
        accy += (f0.y + f1.y) + (f2.y + f3.y);
    }

    const float ax1 = __shfl(accx, fp + 20);
    const float ay1 = __shfl(accy, fp + 20);
    const float ax2 = __shfl(accx, fp + 40);
    const float ay2 = __shfl(accy, fp + 40);
    if (lane < 20) {
        float2 o;
        o.x = accx + ax1 + ax2;
        o.y = accy + ay1 + ay2;
        *(float2*)(agg + (size_t)n * 40 + 2 * fp) = o;
    }
}

// ---------------------------------------------------------------------------
// GraphConv via MFMA, K=160: A = [agg_hi|x_hi|agg_lo|x_lo] bf16 (hi/lo split
// for near-fp32 A-side), W = [w_rel|w_root|w_rel|w_root] bf16.
// ---------------------------------------------------------------------------
__global__ void graphconv_mfma_kernel(const float* __restrict__ agg,
                                      const float* __restrict__ x,
                                      const unsigned short* __restrict__ Wg,
                                      const float* __restrict__ b,
                                      unsigned short* __restrict__ C, int N)
{
    __shared__ __align__(16) unsigned short aT[64 * 168];  // 168 = 160 + 8 pad
    const int t = threadIdx.x;
    const int n0 = blockIdx.x * 64;
    const int wave = t >> 6, lane = t & 63, q = lane >> 4, l16 = lane & 15;

    for (int u = t; u < 640; u += 256) {
        const int row = u / 10, c = (u % 10) * 4;
        const int srow = min(n0 + row, N - 1);
        const float4 fa = *(const float4*)(agg + (size_t)srow * 40 + c);
        const float4 fx = *(const float4*)(x + (size_t)srow * 40 + c);
        const float av[4] = {fa.x, fa.y, fa.z, fa.w};
        const float xv[4] = {fx.x, fx.y, fx.z, fx.w};
        ushort4 ha, la, hx, lx;
        ha.x = f2bf(av[0]); la.x = f2bf(av[0] - bf2f(ha.x));
        ha.y = f2bf(av[1]); la.y = f2bf(av[1] - bf2f(ha.y));
        ha.z = f2bf(av[2]); la.z = f2bf(av[2] - bf2f(ha.z));
        ha.w = f2bf(av[3]); la.w = f2bf(av[3] - bf2f(ha.w));
        hx.x = f2bf(xv[0]); lx.x = f2bf(xv[0] - bf2f(hx.x));
        hx.y = f2bf(xv[1]); lx.y = f2bf(xv[1] - bf2f(hx.y));
        hx.z = f2bf(xv[2]); lx.z = f2bf(xv[2] - bf2f(hx.z));
        hx.w = f2bf(xv[3]); lx.w = f2bf(xv[3] - bf2f(hx.w));
        unsigned short* rp = aT + row * 168;
        *(ushort4*)(rp + c)       = ha;
        *(ushort4*)(rp + 40 + c)  = hx;
        *(ushort4*)(rp + 80 + c)  = la;
        *(ushort4*)(rp + 120 + c) = lx;
    }
    __syncthreads();

    f32x4 acc[4][4] = {};
    for (int k0 = 0; k0 < 160; k0 += 32) {
        short8 af[4], wf[4];
        #pragma unroll
        for (int nt = 0; nt < 4; nt++)
            af[nt] = *(const short8*)(aT + (nt * 16 + l16) * 168 + k0 + q * 8);
        #pragma unroll
        for (int mt = 0; mt < 4; mt++)
            wf[mt] = *(const short8*)(Wg + (wave * 64 + mt * 16 + l16) * 160 + k0 + q * 8);
        #pragma unroll
        for (int nt = 0; nt < 4; nt++)
            #pragma unroll
            for (int mt = 0; mt < 4; mt++)
                acc[nt][mt] = __builtin_amdgcn_mfma_f32_16x16x32_bf16(af[nt], wf[mt], acc[nt][mt], 0, 0, 0);
    }

    float bias[4];
    #pragma unroll
    for (int mt = 0; mt < 4; mt++) bias[mt] = b[wave * 64 + mt * 16 + l16];

    #pragma unroll
    for (int nt = 0; nt < 4; nt++)
        #pragma unroll
        for (int r = 0; r < 4; r++) {
            const int row = n0 + nt * 16 + q * 4 + r;   // C/D: row=quad*4+reg
            if (row >= N) continue;
            #pragma unroll
            for (int mt = 0; mt < 4; mt++) {
                const int col = wave * 64 + mt * 16 + l16;  // C/D: col=lane&15
                C[(size_t)row * 256 + col] = f2bf(lrelu(acc[nt][mt][r] + bias[mt]));
            }
        }
}

// ---------------------------------------------------------------------------
// MLP layer via MFMA: C = lrelu(A @ W^T + b), A [N,256] bf16, W [256,256] bf16.
// ---------------------------------------------------------------------------
__global__ void mlp_mfma_kernel(const unsigned short* __restrict__ A,
                                const unsigned short* __restrict__ W,
                                const float* __restrict__ b,
                                unsigned short* __restrict__ C, int N)
{
    __shared__ __align__(16) unsigned short aT[64 * 264];  // 264 = 256 + 8 pad
    const int t = threadIdx.x;
    const int n0 = blockIdx.x * 64;
    const int wave = t >> 6, lane = t & 63, q = lane >> 4, l16 = lane & 15;

    #pragma unroll
    for (int i = 0; i < 8; i++) {
        const int u = t + 256 * i;
        const int row = u >> 5, c16 = u & 31;
        const int srow = min(n0 + row, N - 1);
        *(uint4*)(aT + row * 264 + c16 * 8) = *(const uint4*)(A + (size_t)srow * 256 + c16 * 8);
    }
    __syncthreads();

    f32x4 acc[4][4] = {};
    const unsigned short* wbase = W + (wave * 64 + l16) * 256 + q * 8;
    for (int k0 = 0; k0 < 256; k0 += 32) {
        short8 af[4], wf[4];
        #pragma unroll
        for (int nt = 0; nt < 4; nt++)
            af[nt] = *(const short8*)(aT + (nt * 16 + l16) * 264 + k0 + q * 8);
        #pragma unroll
        for (int mt = 0; mt < 4; mt++)
            wf[mt] = *(const short8*)(wbase + mt * 16 * 256 + k0);
        #pragma unroll
        for (int nt = 0; nt < 4; nt++)
            #pragma unroll
            for (int mt = 0; mt < 4; mt++)
                acc[nt][mt] = __builtin_amdgcn_mfma_f32_16x16x32_bf16(af[nt], wf[mt], acc[nt][mt], 0, 0, 0);
    }

    float bias[4];
    #pragma unroll
    for (int mt = 0; mt < 4; mt++) bias[mt] = b[wave * 64 + mt * 16 + l16];

    #pragma unroll
    for (int nt = 0; nt < 4; nt++)
        #pragma unroll
        for (int r = 0; r < 4; r++) {
            const int row = n0 + nt * 16 + q * 4 + r;
            if (row >= N) continue;
            #pragma unroll
            for (int mt = 0; mt < 4; mt++) {
                const int col = wave * 64 + mt * 16 + l16;
                C[(size_t)row * 256 + col] = f2bf(lrelu(acc[nt][mt][r] + bias[mt]));
            }
        }
}

// ---------------------------------------------------------------------------
// Pred: out[n] = h[n] . w_pred + b_pred.  One wave per node; h is bf16.
// ---------------------------------------------------------------------------
__global__ void pred_kernel(const unsigned short* __restrict__ h,
                            const float* __restrict__ w,
                            const float* __restrict__ b,
                            float* __restrict__ out, int N)
{
    __shared__ float s_w[256];
    const int t = threadIdx.x;
    s_w[t] = w[t];
    __syncthreads();

    const int wave = t / 64, lane = t % 64;
    const int n = blockIdx.x * 4 + wave;
    if (n >= N) return;

    float v = 0.f;
    #pragma unroll
    for (int j = 0; j < 4; j++)
        v += bf2f(h[(size_t)n * 256 + lane + j * 64]) * s_w[lane + j * 64];

    #pragma unroll
    for (int off = 32; off > 0; off >>= 1)
        v += __shfl_down(v, off);

    if (lane == 0) out[n] = v + b[0];
}

// ---------------------------------------------------------------------------
extern "C" void kernel_launch(void* const* d_in, const int* in_sizes, int n_in,
                              void* d_out, int out_size, void* d_ws, size_t ws_size,
                              hipStream_t stream)
{
    const float* pose   = (const float*)d_in[0];
    const float* views  = (const float*)d_in[1];
    const int*   ei     = (const int*)d_in[2];
    const float* w_e1   = (const float*)d_in[3];
    const float* b_e1   = (const float*)d_in[4];
    const float* w_e2   = (const float*)d_in[5];
    const float* b_e2   = (const float*)d_in[6];
    const float* w_rel  = (const float*)d_in[7];
    const float* b_rel  = (const float*)d_in[8];
    const float* w_root = (const float*)d_in[9];
    const float* w_l1   = (const float*)d_in[10];
    const float* b_l1   = (const float*)d_in[11];
    const float* w_l2   = (const float*)d_in[12];
    const float* b_l2   = (const float*)d_in[13];
    const float* w_l3   = (const float*)d_in[14];
    const float* b_l3   = (const float*)d_in[15];
    const float* w_pred = (const float*)d_in[16];
    const float* b_pred = (const float*)d_in[17];
    float* out = (float*)d_out;

    const int N = in_sizes[0] / 3;       // 50000
    const int E = in_sizes[2] / 2;       // 4950000
    const int NB = (N + 63) >> 6;        // 782 buckets
    const int NBLK = (N + 63) / 64;      // row blocks for GEMMs

    // Workspace layout. hb0/hb1 alias pairs/sorted: graph ints are fully dead
    // (last read = gather_sum) before graphconv/mlp write hb0/hb1.
    float* x   = (float*)d_ws;                       // N*40 fp32
    float* agg = x + (size_t)N * 40;                 // N*40 fp32
    int* pairs  = (int*)(agg + (size_t)N * 40);      // NB*CAP ints (25.62 MB)
    int* sorted = pairs + (size_t)NB * CAP;          // NB*CAP ints (25.62 MB)
    unsigned short* hb0 = (unsigned short*)pairs;    // N*256 bf16 alias
    unsigned short* hb1 = (unsigned short*)sorted;   // N*256 bf16 alias
    int* gcur       = sorted + (size_t)NB * CAP;     // 1024
    int* node_start = gcur + 1024;                   // NB*64
    int* node_cnt   = node_start + NB * 64;          // NB*64
    unsigned short* Wb1 = (unsigned short*)(node_cnt + NB * 64);  // 256*256
    unsigned short* Wb2 = Wb1 + 256 * 256;
    unsigned short* Wb3 = Wb2 + 256 * 256;
    unsigned short* Wg  = Wb3 + 256 * 256;           // 256*160
    __half* xh = (__half*)(Wg + 256 * 160);          // (N+1)*40 fp16; row N = zeros

    // Weight prep (bf16)
    cvt_bf16_kernel<<<256, 256, 0, stream>>>(w_l1, Wb1, 256 * 256);
    cvt_bf16_kernel<<<256, 256, 0, stream>>>(w_l2, Wb2, 256 * 256);
    cvt_bf16_kernel<<<256, 256, 0, stream>>>(w_l3, Wb3, 256 * 256);
    build_wg_kernel<<<160, 256, 0, stream>>>(w_rel, w_root, Wg);

    encoder_kernel<<<(N + 3) / 4, 256, 0, stream>>>(pose, views, w_e1, b_e1, w_e2, b_e2, x, xh, N);
    hipMemsetAsync(xh + (size_t)N * 40, 0, 40 * sizeof(__half), stream);  // sentinel row

    hipMemsetAsync(gcur, 0, (size_t)NB * sizeof(int), stream);
    bin_kernel<<<(E + EPB - 1) / EPB, 512, 0, stream>>>(ei, gcur, pairs, E, NB);
    bucket_sort_kernel<<<NB, 256, 0, stream>>>(gcur, pairs, sorted, node_start, node_cnt, N);
    gather_sum_kernel<<<NB * 16, 256, 0, stream>>>(sorted, node_start, node_cnt, xh, agg, N);

    graphconv_mfma_kernel<<<NBLK, 256, 0, stream>>>(agg, x, Wg, b_rel, hb0, N);
    mlp_mfma_kernel<<<NBLK, 256, 0, stream>>>(hb0, Wb1, b_l1, hb1, N);
    mlp_mfma_kernel<<<NBLK, 256, 0, stream>>>(hb1, Wb2, b_l2, hb0, N);
    mlp_mfma_kernel<<<NBLK, 256, 0, stream>>>(hb0, Wb3, b_l3, hb1, N);
    pred_kernel<<<(N + 3) / 4, 256, 0, stream>>>(hb1, w_pred, b_pred, out, N);
}

// Round 10
// 405.629 us; speedup vs baseline: 5.1982x; 1.0812x over previous
//
#include <hip/hip_runtime.h>
#include <hip/hip_fp16.h>

#define NEG_SLOPE 0.1f
__device__ __forceinline__ float lrelu(float v) { return fmaxf(v, NEG_SLOPE * v); }

constexpr int CAP = 8192;   // per-bucket capacity (mean 6330 + 12-align pads < 7200)
constexpr int EPB = 8192;   // edges per bin block (16 per thread, 512 threads)

typedef __attribute__((ext_vector_type(8))) short short8;   // 8 bf16 (4 VGPRs)
typedef __attribute__((ext_vector_type(4))) float f32x4;    // MFMA accum

__device__ __forceinline__ unsigned short f2bf(float f) {   // RNE
    union { float f; unsigned u; } v; v.f = f;
    const unsigned r = v.u + 0x7FFF + ((v.u >> 16) & 1);
    return (unsigned short)(r >> 16);
}
__device__ __forceinline__ float bf2f(unsigned short h) {
    union { unsigned u; float f; } v; v.u = ((unsigned)h) << 16;
    return v.f;
}

// ---------------------------------------------------------------------------
// Fused prep: bf16 weight conversions + Wg build + gcur zero + xh sentinel
// row. One launch instead of 4 kernels + 2 memsets.
// ---------------------------------------------------------------------------
__global__ void prep_kernel(const float* __restrict__ w_l1, const float* __restrict__ w_l2,
                            const float* __restrict__ w_l3, const float* __restrict__ w_rel,
                            const float* __restrict__ w_root,
                            unsigned short* __restrict__ Wb1, unsigned short* __restrict__ Wb2,
                            unsigned short* __restrict__ Wb3, unsigned short* __restrict__ Wg,
                            int* __restrict__ gcur, __half* __restrict__ xh, int N)
{
    const int i = blockIdx.x * blockDim.x + threadIdx.x;   // grid = 65536
    if (i < 65536) {
        Wb1[i] = f2bf(w_l1[i]);
        Wb2[i] = f2bf(w_l2[i]);
        Wb3[i] = f2bf(w_l3[i]);
    }
    if (i < 40960) {   // Wg[256][160] = [w_rel|w_root|w_rel|w_root]
        const int m = i / 160, c = i % 160;
        const int k = c % 80;
        const float v = (k < 40) ? w_rel[m * 40 + k] : w_root[m * 40 + (k - 40)];
        Wg[i] = f2bf(v);
    }
    if (i < 1024) gcur[i] = 0;
    if (i < 40) xh[(size_t)N * 40 + i] = __float2half(0.f);   // zero sentinel row
}

// ---------------------------------------------------------------------------
// Encoder v3: 4 nodes per 256-thread block, FLAT task ids.
// conv1: 300 tasks (node,pos) -> pass 2 is tasks 256..299, so waves 1-3 skip
// via execz (8 issued wave-bodies -> 5). conv2+pose: 160 flat tasks ->
// coalesced x/xh stores. c1 even/odd-deinterleaved so conv2 taps stride-1.
// ---------------------------------------------------------------------------
__global__ __launch_bounds__(256) void encoder_kernel(
        const float* __restrict__ pose,
        const float* __restrict__ views,
        const float* __restrict__ w1, const float* __restrict__ b1,
        const float* __restrict__ w2, const float* __restrict__ b2,
        float* __restrict__ x, __half* __restrict__ xh, int N)
{
    __shared__ float s_w1[81];
    __shared__ float s_b1[9];
    __shared__ float s_w2[27];
    __shared__ float s_b2[1];
    __shared__ float s_c1[4][9][80];   // [lnode][oc][(p&1)*40 + (p>>1)]

    const int t = threadIdx.x;
    if (t < 81) s_w1[t] = w1[t];
    if (t >= 96 && t < 105) s_b1[t - 96] = b1[t - 96];
    if (t >= 128 && t < 155) s_w2[t - 128] = w2[t - 128];
    if (t == 240) s_b2[0] = b2[0];
    __syncthreads();

    const int nb = blockIdx.x * 4;

    // conv1: 300 position-tasks over 2 passes (pass 2: only wave 0 active)
    #pragma unroll
    for (int pass = 0; pass < 2; pass++) {
        const int task = pass * 256 + t;
        if (task < 300) {
            const int ln = task / 75;
            const int p  = task % 75;
            const int n  = min(nb + ln, N - 1);
            const float* __restrict__ vin = views + (size_t)n * 453 + 2 * p;
            float e[3], o[3], e1[3];
            #pragma unroll
            for (int ic = 0; ic < 3; ic++) {
                const float* ci = vin + ic * 151;
                e[ic] = ci[0]; o[ic] = ci[1]; e1[ic] = ci[2];
            }
            const int didx = (p & 1) * 40 + (p >> 1);
            #pragma unroll
            for (int oc = 0; oc < 9; oc++) {
                float v = s_b1[oc];
                #pragma unroll
                for (int ic = 0; ic < 3; ic++)
                    v += s_w1[oc * 9 + ic * 3 + 0] * e[ic]
                       + s_w1[oc * 9 + ic * 3 + 1] * o[ic]
                       + s_w1[oc * 9 + ic * 3 + 2] * e1[ic];
                s_c1[ln][oc][didx] = lrelu(v);
            }
        }
    }
    __syncthreads();

    // conv2 + pose passthrough: 160 flat tasks, coalesced stores
    if (t < 160) {
        const int ln = t / 40, f = t % 40;
        const int n  = min(nb + ln, N - 1);
        float outv;
        if (f < 3) {
            outv = pose[(size_t)n * 3 + f];
        } else {
            const int ow = f - 3;
            float v = s_b2[0];
            #pragma unroll
            for (int ic = 0; ic < 9; ic++)
                v += s_w2[ic * 3 + 0] * s_c1[ln][ic][ow]
                   + s_w2[ic * 3 + 1] * s_c1[ln][ic][40 + ow]
                   + s_w2[ic * 3 + 2] * s_c1[ln][ic][ow + 1];
            outv = lrelu(v);
        }
        x[(size_t)n * 40 + f] = outv;
        xh[(size_t)n * 40 + f] = __float2half(outv);
    }
}

// ---------------------------------------------------------------------------
// Coarse binning (512 thr, 8192 edges/block): rank via LDS histogram, stage
// bucket-ordered in LDS, linear write-out -> piecewise-contiguous stores.
// ---------------------------------------------------------------------------
__global__ __launch_bounds__(512) void bin_kernel(
        const int* __restrict__ ei, int* __restrict__ gcur,
        int* __restrict__ pairs, int E, int NB)
{
    __shared__ int s_hist[1024];
    __shared__ int s_loff[1024];
    __shared__ int s_base[1024];
    __shared__ int s_wave8[8];
    __shared__ int s_pk[EPB];                 // 32 KB
    __shared__ unsigned short s_bkt[EPB];     // 16 KB
    const int t = threadIdx.x;
    const int lane = t & 63, wid = t >> 6;    // 8 waves
    const int e0 = blockIdx.x * EPB + t * 16;
    const int tot = min(E - blockIdx.x * EPB, EPB);

    for (int i = t; i < 1024; i += 512) s_hist[i] = 0;
    __syncthreads();

    int pk[16], mt[16];
    auto proc = [&](int j, int sv, int dv) {
        const int b = dv >> 6;
        const int r = atomicAdd(&s_hist[b], 1);   // local rank (LDS atomic)
        pk[j] = sv | ((dv & 63) << 16);
        mt[j] = b | (r << 10);                    // b<1024, r<8192 -> 23 bits
    };

    if (e0 + 16 <= E) {
        #pragma unroll
        for (int q = 0; q < 4; q++) {
            const int4 sv = *(const int4*)(ei + e0 + 4 * q);
            const int4 dv = *(const int4*)(ei + E + e0 + 4 * q);
            proc(4 * q + 0, sv.x, dv.x);
            proc(4 * q + 1, sv.y, dv.y);
            proc(4 * q + 2, sv.z, dv.z);
            proc(4 * q + 3, sv.w, dv.w);
        }
    } else {
        #pragma unroll
        for (int j = 0; j < 16; j++) {
            mt[j] = -1;
            const int e = e0 + j;
            if (e < E) proc(j, ei[e], ei[E + e]);
        }
    }
    __syncthreads();

    // exclusive scan of s_hist[0..1023] -> s_loff
    int carry = 0;
    #pragma unroll
    for (int base = 0; base < 1024; base += 512) {
        const int i = base + t;
        const int v = s_hist[i];
        int sc = v;
        #pragma unroll
        for (int d = 1; d < 64; d <<= 1) {
            const int u = __shfl_up(sc, d);
            if (lane >= d) sc += u;
        }
        if (lane == 63) s_wave8[wid] = sc;
        __syncthreads();
        if (wid == 0) {
            int wv = (lane < 8) ? s_wave8[lane] : 0;
            #pragma unroll
            for (int d = 1; d < 8; d <<= 1) {
                const int u = __shfl_up(wv, d);
                if (lane >= d) wv += u;
            }
            if (lane < 8) s_wave8[lane] = wv;
        }
        __syncthreads();
        const int waveoff = (wid > 0) ? s_wave8[wid - 1] : 0;
        s_loff[i] = carry + waveoff + sc - v;
        const int chunk_tot = s_wave8[7];
        __syncthreads();
        carry += chunk_tot;
    }

    for (int i = t; i < NB; i += 512) {
        const int c = s_hist[i];
        if (c > 0) s_base[i] = atomicAdd(&gcur[i], c);
    }
    __syncthreads();

    #pragma unroll
    for (int j = 0; j < 16; j++) {
        if (mt[j] >= 0) {
            const int b = mt[j] & 1023;
            const int pos = s_loff[b] + (mt[j] >> 10);
            s_pk[pos] = pk[j];
            s_bkt[pos] = (unsigned short)b;
        }
    }
    __syncthreads();

    for (int i = t; i < tot; i += 512) {
        const int b = s_bkt[i];
        const int p = s_base[b] + (i - s_loff[b]);
        if (p < CAP) pairs[b * CAP + p] = s_pk[i];
    }
}

// ---------------------------------------------------------------------------
// Per-bucket exact counting sort (LDS only). Runs 12-aligned, pads filled with
// sentinel src=N -> gather adds the explicit zero row, no tail masking needed.
// ---------------------------------------------------------------------------
__global__ void bucket_sort_kernel(const int* __restrict__ gcur,
                                   const int* __restrict__ pairs,
                                   int* __restrict__ sorted,
                                   int* __restrict__ node_start,
                                   int* __restrict__ node_cnt, int N)
{
    __shared__ int s_cnt[64], s_off[64], s_cur[64];
    const int b = blockIdx.x;
    const int t = threadIdx.x;
    const int cnt = min(gcur[b], CAP);
    const int* __restrict__ pr = pairs + b * CAP;
    int* __restrict__ so = sorted + (size_t)b * CAP;

    if (t < 64) s_cnt[t] = 0;
    __syncthreads();
    for (int i = t; i < cnt; i += 256)
        atomicAdd(&s_cnt[pr[i] >> 16], 1);
    __syncthreads();

    if (t < 64) {   // exclusive scan of 12-aligned counts
        const int c = s_cnt[t];
        const int p = ((c + 11) / 12) * 12;
        int sc = p;
        #pragma unroll
        for (int d = 1; d < 64; d <<= 1) {
            const int u = __shfl_up(sc, d);
            if (t >= d) sc += u;
        }
        const int excl = sc - p;
        s_off[t] = excl;
        s_cur[t] = excl;
        node_start[b * 64 + t] = b * CAP + excl;
        node_cnt[b * 64 + t] = c;
    }
    __syncthreads();

    if (t < 64) {   // pad fill: sentinel src=N (zero row in xh)
        const int e0 = s_off[t] + s_cnt[t];
        const int e1 = s_off[t] + ((s_cnt[t] + 11) / 12) * 12;
        for (int i = e0; i < e1 && i < CAP; i++) so[i] = N;
    }
    for (int i = t; i < cnt; i += 256) {
        const int p = pr[i];
        const int pos = atomicAdd(&s_cur[p >> 16], 1);
        if (pos < CAP) so[pos] = p & 0xFFFF;
    }
}

// ---------------------------------------------------------------------------
// Segment sum: one wave per node, 3 edges per iteration, packed __half2 lanes.
// Pads hit the zero row (src=N) so there is no tail masking.
// ---------------------------------------------------------------------------
__global__ void gather_sum_kernel(const int* __restrict__ sorted,
                                  const int* __restrict__ node_start,
                                  const int* __restrict__ node_cnt,
                                  const __half* __restrict__ xh,
                                  float* __restrict__ agg, int N)
{
    const int n = blockIdx.x * 4 + (threadIdx.x >> 6);
    const int lane = threadIdx.x & 63;
    if (n >= N) return;

    const int start = node_start[n];
    const int cntp = ((node_cnt[n] + 11) / 12) * 12;
    const int slot = min(lane / 20, 2);          // lanes 60..63 duplicate slot 2
    const int fp = lane % 20;
    const int* __restrict__ srt = sorted + start + slot;
    const __half* __restrict__ xb = xh + 2 * fp;

    float accx = 0.f, accy = 0.f;
    for (int e = 0; e < cntp; e += 12) {
        const int i0 = srt[e];
        const int i1 = srt[e + 3];
        const int i2 = srt[e + 6];
        const int i3 = srt[e + 9];
        const __half2 h0 = *(const __half2*)(xb + i0 * 40);
        const __half2 h1 = *(const __half2*)(xb + i1 * 40);
        const __half2 h2 = *(const __half2*)(xb + i2 * 40);
        const __half2 h3 = *(const __half2*)(xb + i3 * 40);
        const float2 f0 = __half22float2(h0);
        const float2 f1 = __half22float2(h1);
        const float2 f2 = __half22float2(h2);
        const float2 f3 = __half22float2(h3);
        accx += (f0.x + f1.x) + (f2.x + f3.x);
        accy += (f0.y + f1.y) + (f2.y + f3.y);
    }

    const float ax1 = __shfl(accx, fp + 20);
    const float ay1 = __shfl(accy, fp + 20);
    const float ax2 = __shfl(accx, fp + 40);
    const float ay2 = __shfl(accy, fp + 40);
    if (lane < 20) {
        float2 o;
        o.x = accx + ax1 + ax2;
        o.y = accy + ay1 + ay2;
        *(float2*)(agg + (size_t)n * 40 + 2 * fp) = o;
    }
}

// ---------------------------------------------------------------------------
// GraphConv via MFMA, K=160: A = [agg_hi|x_hi|agg_lo|x_lo] bf16 (hi/lo split
// for near-fp32 A-side), W = [w_rel|w_root|w_rel|w_root] bf16.
// ---------------------------------------------------------------------------
__global__ void graphconv_mfma_kernel(const float* __restrict__ agg,
                                      const float* __restrict__ x,
                                      const unsigned short* __restrict__ Wg,
                                      const float* __restrict__ b,
                                      unsigned short* __restrict__ C, int N)
{
    __shared__ __align__(16) unsigned short aT[64 * 168];  // 168 = 160 + 8 pad
    const int t = threadIdx.x;
    const int n0 = blockIdx.x * 64;
    const int wave = t >> 6, lane = t & 63, q = lane >> 4, l16 = lane & 15;

    for (int u = t; u < 640; u += 256) {
        const int row = u / 10, c = (u % 10) * 4;
        const int srow = min(n0 + row, N - 1);
        const float4 fa = *(const float4*)(agg + (size_t)srow * 40 + c);
        const float4 fx = *(const float4*)(x + (size_t)srow * 40 + c);
        const float av[4] = {fa.x, fa.y, fa.z, fa.w};
        const float xv[4] = {fx.x, fx.y, fx.z, fx.w};
        ushort4 ha, la, hx, lx;
        ha.x = f2bf(av[0]); la.x = f2bf(av[0] - bf2f(ha.x));
        ha.y = f2bf(av[1]); la.y = f2bf(av[1] - bf2f(ha.y));
        ha.z = f2bf(av[2]); la.z = f2bf(av[2] - bf2f(ha.z));
        ha.w = f2bf(av[3]); la.w = f2bf(av[3] - bf2f(ha.w));
        hx.x = f2bf(xv[0]); lx.x = f2bf(xv[0] - bf2f(hx.x));
        hx.y = f2bf(xv[1]); lx.y = f2bf(xv[1] - bf2f(hx.y));
        hx.z = f2bf(xv[2]); lx.z = f2bf(xv[2] - bf2f(hx.z));
        hx.w = f2bf(xv[3]); lx.w = f2bf(xv[3] - bf2f(hx.w));
        unsigned short* rp = aT + row * 168;
        *(ushort4*)(rp + c)       = ha;
        *(ushort4*)(rp + 40 + c)  = hx;
        *(ushort4*)(rp + 80 + c)  = la;
        *(ushort4*)(rp + 120 + c) = lx;
    }
    __syncthreads();

    f32x4 acc[4][4] = {};
    for (int k0 = 0; k0 < 160; k0 += 32) {
        short8 af[4], wf[4];
        #pragma unroll
        for (int nt = 0; nt < 4; nt++)
            af[nt] = *(const short8*)(aT + (nt * 16 + l16) * 168 + k0 + q * 8);
        #pragma unroll
        for (int mt = 0; mt < 4; mt++)
            wf[mt] = *(const short8*)(Wg + (wave * 64 + mt * 16 + l16) * 160 + k0 + q * 8);
        #pragma unroll
        for (int nt = 0; nt < 4; nt++)
            #pragma unroll
            for (int mt = 0; mt < 4; mt++)
                acc[nt][mt] = __builtin_amdgcn_mfma_f32_16x16x32_bf16(af[nt], wf[mt], acc[nt][mt], 0, 0, 0);
    }

    float bias[4];
    #pragma unroll
    for (int mt = 0; mt < 4; mt++) bias[mt] = b[wave * 64 + mt * 16 + l16];

    #pragma unroll
    for (int nt = 0; nt < 4; nt++)
        #pragma unroll
        for (int r = 0; r < 4; r++) {
            const int row = n0 + nt * 16 + q * 4 + r;   // C/D: row=quad*4+reg
            if (row >= N) continue;
            #pragma unroll
            for (int mt = 0; mt < 4; mt++) {
                const int col = wave * 64 + mt * 16 + l16;  // C/D: col=lane&15
                C[(size_t)row * 256 + col] = f2bf(lrelu(acc[nt][mt][r] + bias[mt]));
            }
        }
}

// ---------------------------------------------------------------------------
// MLP layer via MFMA: C = lrelu(A @ W^T + b), A [N,256] bf16, W [256,256] bf16.
// ---------------------------------------------------------------------------
__global__ void mlp_mfma_kernel(const unsigned short* __restrict__ A,
                                const unsigned short* __restrict__ W,
                                const float* __restrict__ b,
                                unsigned short* __restrict__ C, int N)
{
    __shared__ __align__(16) unsigned short aT[64 * 264];  // 264 = 256 + 8 pad
    const int t = threadIdx.x;
    const int n0 = blockIdx.x * 64;
    const int wave = t >> 6, lane = t & 63, q = lane >> 4, l16 = lane & 15;

    #pragma unroll
    for (int i = 0; i < 8; i++) {
        const int u = t + 256 * i;
        const int row = u >> 5, c16 = u & 31;
        const int srow = min(n0 + row, N - 1);
        *(uint4*)(aT + row * 264 + c16 * 8) = *(const uint4*)(A + (size_t)srow * 256 + c16 * 8);
    }
    __syncthreads();

    f32x4 acc[4][4] = {};
    const unsigned short* wbase = W + (wave * 64 + l16) * 256 + q * 8;
    for (int k0 = 0; k0 < 256; k0 += 32) {
        short8 af[4], wf[4];
        #pragma unroll
        for (int nt = 0; nt < 4; nt++)
            af[nt] = *(const short8*)(aT + (nt * 16 + l16) * 264 + k0 + q * 8);
        #pragma unroll
        for (int mt = 0; mt < 4; mt++)
            wf[mt] = *(const short8*)(wbase + mt * 16 * 256 + k0);
        #pragma unroll
        for (int nt = 0; nt < 4; nt++)
            #pragma unroll
            for (int mt = 0; mt < 4; mt++)
                acc[nt][mt] = __builtin_amdgcn_mfma_f32_16x16x32_bf16(af[nt], wf[mt], acc[nt][mt], 0, 0, 0);
    }

    float bias[4];
    #pragma unroll
    for (int mt = 0; mt < 4; mt++) bias[mt] = b[wave * 64 + mt * 16 + l16];

    #pragma unroll
    for (int nt = 0; nt < 4; nt++)
        #pragma unroll
        for (int r = 0; r < 4; r++) {
            const int row = n0 + nt * 16 + q * 4 + r;
            if (row >= N) continue;
            #pragma unroll
            for (int mt = 0; mt < 4; mt++) {
                const int col = wave * 64 + mt * 16 + l16;
                C[(size_t)row * 256 + col] = f2bf(lrelu(acc[nt][mt][r] + bias[mt]));
            }
        }
}

// ---------------------------------------------------------------------------
// Pred: out[n] = h[n] . w_pred + b_pred.  One wave per node; h is bf16.
// ---------------------------------------------------------------------------
__global__ void pred_kernel(const unsigned short* __restrict__ h,
                            const float* __restrict__ w,
                            const float* __restrict__ b,
                            float* __restrict__ out, int N)
{
    __shared__ float s_w[256];
    const int t = threadIdx.x;
    s_w[t] = w[t];
    __syncthreads();

    const int wave = t / 64, lane = t % 64;
    const int n = blockIdx.x * 4 + wave;
    if (n >= N) return;

    float v = 0.f;
    #pragma unroll
    for (int j = 0; j < 4; j++)
        v += bf2f(h[(size_t)n * 256 + lane + j * 64]) * s_w[lane + j * 64];

    #pragma unroll
    for (int off = 32; off > 0; off >>= 1)
        v += __shfl_down(v, off);

    if (lane == 0) out[n] = v + b[0];
}

// ---------------------------------------------------------------------------
extern "C" void kernel_launch(void* const* d_in, const int* in_sizes, int n_in,
                              void* d_out, int out_size, void* d_ws, size_t ws_size,
                              hipStream_t stream)
{
    const float* pose   = (const float*)d_in[0];
    const float* views  = (const float*)d_in[1];
    const int*   ei     = (const int*)d_in[2];
    const float* w_e1   = (const float*)d_in[3];
    const float* b_e1   = (const float*)d_in[4];
    const float* w_e2   = (const float*)d_in[5];
    const float* b_e2   = (const float*)d_in[6];
    const float* w_rel  = (const float*)d_in[7];
    const float* b_rel  = (const float*)d_in[8];
    const float* w_root = (const float*)d_in[9];
    const float* w_l1   = (const float*)d_in[10];
    const float* b_l1   = (const float*)d_in[11];
    const float* w_l2   = (const float*)d_in[12];
    const float* b_l2   = (const float*)d_in[13];
    const float* w_l3   = (const float*)d_in[14];
    const float* b_l3   = (const float*)d_in[15];
    const float* w_pred = (const float*)d_in[16];
    const float* b_pred = (const float*)d_in[17];
    float* out = (float*)d_out;

    const int N = in_sizes[0] / 3;       // 50000
    const int E = in_sizes[2] / 2;       // 4950000
    const int NB = (N + 63) >> 6;        // 782 buckets
    const int NBLK = (N + 63) / 64;      // row blocks for GEMMs

    // Workspace layout. hb0/hb1 alias pairs/sorted: graph ints are fully dead
    // (last read = gather_sum) before graphconv/mlp write hb0/hb1.
    float* x   = (float*)d_ws;                       // N*40 fp32
    float* agg = x + (size_t)N * 40;                 // N*40 fp32
    int* pairs  = (int*)(agg + (size_t)N * 40);      // NB*CAP ints (25.62 MB)
    int* sorted = pairs + (size_t)NB * CAP;          // NB*CAP ints (25.62 MB)
    unsigned short* hb0 = (unsigned short*)pairs;    // N*256 bf16 alias
    unsigned short* hb1 = (unsigned short*)sorted;   // N*256 bf16 alias
    int* gcur       = sorted + (size_t)NB * CAP;     // 1024
    int* node_start = gcur + 1024;                   // NB*64
    int* node_cnt   = node_start + NB * 64;          // NB*64
    unsigned short* Wb1 = (unsigned short*)(node_cnt + NB * 64);  // 256*256
    unsigned short* Wb2 = Wb1 + 256 * 256;
    unsigned short* Wb3 = Wb2 + 256 * 256;
    unsigned short* Wg  = Wb3 + 256 * 256;           // 256*160
    __half* xh = (__half*)(Wg + 256 * 160);          // (N+1)*40 fp16; row N = zeros

    prep_kernel<<<256, 256, 0, stream>>>(w_l1, w_l2, w_l3, w_rel, w_root,
                                         Wb1, Wb2, Wb3, Wg, gcur, xh, N);

    encoder_kernel<<<(N + 3) / 4, 256, 0, stream>>>(pose, views, w_e1, b_e1, w_e2, b_e2, x, xh, N);

    bin_kernel<<<(E + EPB - 1) / EPB, 512, 0, stream>>>(ei, gcur, pairs, E, NB);
    bucket_sort_kernel<<<NB, 256, 0, stream>>>(gcur, pairs, sorted, node_start, node_cnt, N);
    gather_sum_kernel<<<NB * 16, 256, 0, stream>>>(sorted, node_start, node_cnt, xh, agg, N);

    graphconv_mfma_kernel<<<NBLK, 256, 0, stream>>>(agg, x, Wg, b_rel, hb0, N);
    mlp_mfma_kernel<<<NBLK, 256, 0, stream>>>(hb0, Wb1, b_l1, hb1, N);
    mlp_mfma_kernel<<<NBLK, 256, 0, stream>>>(hb1, Wb2, b_l2, hb0, N);
    mlp_mfma_kernel<<<NBLK, 256, 0, stream>>>(hb0, Wb3, b_l3, hb1, N);
    pred_kernel<<<(N + 3) / 4, 256, 0, stream>>>(hb1, w_pred, b_pred, out, N);
}

// Round 11
// 405.186 us; speedup vs baseline: 5.2039x; 1.0011x over previous
//
#include <hip/hip_runtime.h>
#include <hip/hip_fp16.h>

#define NEG_SLOPE 0.1f
__device__ __forceinline__ float lrelu(float v) { return fmaxf(v, NEG_SLOPE * v); }

constexpr int CAP = 8704;   // per-bucket capacity (mean 6330 + 24-align pads < 8000)
constexpr int EPB = 8192;   // edges per bin block (16 per thread, 512 threads)

typedef __attribute__((ext_vector_type(8))) short short8;   // 8 bf16 (4 VGPRs)
typedef __attribute__((ext_vector_type(4))) float f32x4;    // MFMA accum

__device__ __forceinline__ unsigned short f2bf(float f) {   // RNE
    union { float f; unsigned u; } v; v.f = f;
    const unsigned r = v.u + 0x7FFF + ((v.u >> 16) & 1);
    return (unsigned short)(r >> 16);
}
__device__ __forceinline__ float bf2f(unsigned short h) {
    union { unsigned u; float f; } v; v.u = ((unsigned)h) << 16;
    return v.f;
}

// ---------------------------------------------------------------------------
// Fused prep: bf16 weight conversions + Wg build + gcur zero + xh sentinel.
// ---------------------------------------------------------------------------
__global__ void prep_kernel(const float* __restrict__ w_l1, const float* __restrict__ w_l2,
                            const float* __restrict__ w_l3, const float* __restrict__ w_rel,
                            const float* __restrict__ w_root,
                            unsigned short* __restrict__ Wb1, unsigned short* __restrict__ Wb2,
                            unsigned short* __restrict__ Wb3, unsigned short* __restrict__ Wg,
                            int* __restrict__ gcur, __half* __restrict__ xh, int N)
{
    const int i = blockIdx.x * blockDim.x + threadIdx.x;   // grid = 65536
    if (i < 65536) {
        Wb1[i] = f2bf(w_l1[i]);
        Wb2[i] = f2bf(w_l2[i]);
        Wb3[i] = f2bf(w_l3[i]);
    }
    if (i < 40960) {   // Wg[256][160] = [w_rel|w_root|w_rel|w_root]
        const int m = i / 160, c = i % 160;
        const int k = c % 80;
        const float v = (k < 40) ? w_rel[m * 40 + k] : w_root[m * 40 + (k - 40)];
        Wg[i] = f2bf(v);
    }
    if (i < 1024) gcur[i] = 0;
    if (i < 40) xh[(size_t)N * 40 + i] = __float2half(0.f);   // zero sentinel row
}

// ---------------------------------------------------------------------------
// Encoder: 4 nodes per 256-thread block, flat task ids; c1 even/odd-
// deinterleaved in LDS so conv2's stride-2 taps are stride-1.
// ---------------------------------------------------------------------------
__global__ __launch_bounds__(256) void encoder_kernel(
        const float* __restrict__ pose,
        const float* __restrict__ views,
        const float* __restrict__ w1, const float* __restrict__ b1,
        const float* __restrict__ w2, const float* __restrict__ b2,
        float* __restrict__ x, __half* __restrict__ xh, int N)
{
    __shared__ float s_w1[81];
    __shared__ float s_b1[9];
    __shared__ float s_w2[27];
    __shared__ float s_b2[1];
    __shared__ float s_c1[4][9][80];   // [lnode][oc][(p&1)*40 + (p>>1)]

    const int t = threadIdx.x;
    if (t < 81) s_w1[t] = w1[t];
    if (t >= 96 && t < 105) s_b1[t - 96] = b1[t - 96];
    if (t >= 128 && t < 155) s_w2[t - 128] = w2[t - 128];
    if (t == 240) s_b2[0] = b2[0];
    __syncthreads();

    const int nb = blockIdx.x * 4;

    #pragma unroll
    for (int pass = 0; pass < 2; pass++) {
        const int task = pass * 256 + t;
        if (task < 300) {
            const int ln = task / 75;
            const int p  = task % 75;
            const int n  = min(nb + ln, N - 1);
            const float* __restrict__ vin = views + (size_t)n * 453 + 2 * p;
            float e[3], o[3], e1[3];
            #pragma unroll
            for (int ic = 0; ic < 3; ic++) {
                const float* ci = vin + ic * 151;
                e[ic] = ci[0]; o[ic] = ci[1]; e1[ic] = ci[2];
            }
            const int didx = (p & 1) * 40 + (p >> 1);
            #pragma unroll
            for (int oc = 0; oc < 9; oc++) {
                float v = s_b1[oc];
                #pragma unroll
                for (int ic = 0; ic < 3; ic++)
                    v += s_w1[oc * 9 + ic * 3 + 0] * e[ic]
                       + s_w1[oc * 9 + ic * 3 + 1] * o[ic]
                       + s_w1[oc * 9 + ic * 3 + 2] * e1[ic];
                s_c1[ln][oc][didx] = lrelu(v);
            }
        }
    }
    __syncthreads();

    if (t < 160) {
        const int ln = t / 40, f = t % 40;
        const int n  = min(nb + ln, N - 1);
        float outv;
        if (f < 3) {
            outv = pose[(size_t)n * 3 + f];
        } else {
            const int ow = f - 3;
            float v = s_b2[0];
            #pragma unroll
            for (int ic = 0; ic < 9; ic++)
                v += s_w2[ic * 3 + 0] * s_c1[ln][ic][ow]
                   + s_w2[ic * 3 + 1] * s_c1[ln][ic][40 + ow]
                   + s_w2[ic * 3 + 2] * s_c1[ln][ic][ow + 1];
            outv = lrelu(v);
        }
        x[(size_t)n * 40 + f] = outv;
        xh[(size_t)n * 40 + f] = __float2half(outv);
    }
}

// ---------------------------------------------------------------------------
// Coarse binning (512 thr, 8192 edges/block): rank via LDS histogram, stage
// bucket-ordered in LDS, linear write-out. Packed entry = src*80 | dloc<<22
// (byte-offset precompute for the gather; 4M < 2^22).
// ---------------------------------------------------------------------------
__global__ __launch_bounds__(512) void bin_kernel(
        const int* __restrict__ ei, int* __restrict__ gcur,
        int* __restrict__ pairs, int E, int NB)
{
    __shared__ int s_hist[1024];
    __shared__ int s_loff[1024];
    __shared__ int s_base[1024];
    __shared__ int s_wave8[8];
    __shared__ int s_pk[EPB];                 // 32 KB
    __shared__ unsigned short s_bkt[EPB];     // 16 KB
    const int t = threadIdx.x;
    const int lane = t & 63, wid = t >> 6;    // 8 waves
    const int e0 = blockIdx.x * EPB + t * 16;
    const int tot = min(E - blockIdx.x * EPB, EPB);

    for (int i = t; i < 1024; i += 512) s_hist[i] = 0;
    __syncthreads();

    int pk[16], mt[16];
    auto proc = [&](int j, int sv, int dv) {
        const int b = dv >> 6;
        const int r = atomicAdd(&s_hist[b], 1);   // local rank (LDS atomic)
        pk[j] = sv * 80 | ((dv & 63) << 22);
        mt[j] = b | (r << 10);                    // b<1024, r<8192 -> 23 bits
    };

    if (e0 + 16 <= E) {
        #pragma unroll
        for (int q = 0; q < 4; q++) {
            const int4 sv = *(const int4*)(ei + e0 + 4 * q);
            const int4 dv = *(const int4*)(ei + E + e0 + 4 * q);
            proc(4 * q + 0, sv.x, dv.x);
            proc(4 * q + 1, sv.y, dv.y);
            proc(4 * q + 2, sv.z, dv.z);
            proc(4 * q + 3, sv.w, dv.w);
        }
    } else {
        #pragma unroll
        for (int j = 0; j < 16; j++) {
            mt[j] = -1;
            const int e = e0 + j;
            if (e < E) proc(j, ei[e], ei[E + e]);
        }
    }
    __syncthreads();

    // exclusive scan of s_hist[0..1023] -> s_loff
    int carry = 0;
    #pragma unroll
    for (int base = 0; base < 1024; base += 512) {
        const int i = base + t;
        const int v = s_hist[i];
        int sc = v;
        #pragma unroll
        for (int d = 1; d < 64; d <<= 1) {
            const int u = __shfl_up(sc, d);
            if (lane >= d) sc += u;
        }
        if (lane == 63) s_wave8[wid] = sc;
        __syncthreads();
        if (wid == 0) {
            int wv = (lane < 8) ? s_wave8[lane] : 0;
            #pragma unroll
            for (int d = 1; d < 8; d <<= 1) {
                const int u = __shfl_up(wv, d);
                if (lane >= d) wv += u;
            }
            if (lane < 8) s_wave8[lane] = wv;
        }
        __syncthreads();
        const int waveoff = (wid > 0) ? s_wave8[wid - 1] : 0;
        s_loff[i] = carry + waveoff + sc - v;
        const int chunk_tot = s_wave8[7];
        __syncthreads();
        carry += chunk_tot;
    }

    for (int i = t; i < NB; i += 512) {
        const int c = s_hist[i];
        if (c > 0) s_base[i] = atomicAdd(&gcur[i], c);
    }
    __syncthreads();

    #pragma unroll
    for (int j = 0; j < 16; j++) {
        if (mt[j] >= 0) {
            const int b = mt[j] & 1023;
            const int pos = s_loff[b] + (mt[j] >> 10);
            s_pk[pos] = pk[j];
            s_bkt[pos] = (unsigned short)b;
        }
    }
    __syncthreads();

    for (int i = t; i < tot; i += 512) {
        const int b = s_bkt[i];
        const int p = s_base[b] + (i - s_loff[b]);
        if (p < CAP) pairs[b * CAP + p] = s_pk[i];
    }
}

// ---------------------------------------------------------------------------
// Per-bucket exact counting sort (LDS only). Runs 24-aligned; pads filled with
// sentinel byte-offset N*80 (zero row) -> no tail masking in the gather.
// sorted[] holds byte offsets src*80.
// ---------------------------------------------------------------------------
__global__ void bucket_sort_kernel(const int* __restrict__ gcur,
                                   const int* __restrict__ pairs,
                                   int* __restrict__ sorted,
                                   int* __restrict__ node_start,
                                   int* __restrict__ node_cnt, int N)
{
    __shared__ int s_cnt[64], s_off[64], s_cur[64];
    const int b = blockIdx.x;
    const int t = threadIdx.x;
    const int cnt = min(gcur[b], CAP);
    const int* __restrict__ pr = pairs + b * CAP;
    int* __restrict__ so = sorted + (size_t)b * CAP;

    if (t < 64) s_cnt[t] = 0;
    __syncthreads();
    for (int i = t; i < cnt; i += 256)
        atomicAdd(&s_cnt[pr[i] >> 22], 1);
    __syncthreads();

    if (t < 64) {   // exclusive scan of 24-aligned counts
        const int c = s_cnt[t];
        const int p = ((c + 23) / 24) * 24;
        int sc = p;
        #pragma unroll
        for (int d = 1; d < 64; d <<= 1) {
            const int u = __shfl_up(sc, d);
            if (t >= d) sc += u;
        }
        const int excl = sc - p;
        s_off[t] = excl;
        s_cur[t] = excl;
        node_start[b * 64 + t] = b * CAP + excl;
        node_cnt[b * 64 + t] = c;
    }
    __syncthreads();

    if (t < 64) {   // pad fill: sentinel byte offset N*80 (zero row in xh)
        const int e0 = s_off[t] + s_cnt[t];
        const int e1 = s_off[t] + ((s_cnt[t] + 23) / 24) * 24;
        for (int i = e0; i < e1 && i < CAP; i++) so[i] = N * 80;
    }
    for (int i = t; i < cnt; i += 256) {
        const int p = pr[i];
        const int pos = atomicAdd(&s_cur[p >> 22], 1);
        if (pos < CAP) so[pos] = p & 0x3FFFFF;
    }
}

// ---------------------------------------------------------------------------
// Segment sum v4: one wave per node, 6 edges per iteration. Lane l: edge-slot
// l/10, feature-quad l%10 as one 8B uint2 (4 fp16). 24 edges per unrolled
// iter = 4 scalar idx loads + 4 8B gathers. sorted[] holds byte offsets, so
// addressing is a single 64-bit add. Pads hit the zero row.
// ---------------------------------------------------------------------------
__global__ void gather_sum_kernel(const int* __restrict__ sorted,
                                  const int* __restrict__ node_start,
                                  const int* __restrict__ node_cnt,
                                  const __half* __restrict__ xh,
                                  float* __restrict__ agg, int N)
{
    const int n = blockIdx.x * 4 + (threadIdx.x >> 6);
    const int lane = threadIdx.x & 63;
    if (n >= N) return;

    const int start = node_start[n];
    const int cntp = ((node_cnt[n] + 23) / 24) * 24;
    const int slot = min(lane / 10, 5);          // lanes 60..63 duplicate slot 5
    const int f4 = lane % 10;                    // feature quad (4 halfs)
    const int* __restrict__ srt = sorted + start + slot;
    const char* __restrict__ xb = (const char*)xh + f4 * 8;

    float ax = 0.f, ay = 0.f, az = 0.f, aw = 0.f;
    for (int e = 0; e < cntp; e += 24) {
        const int o0 = srt[e];
        const int o1 = srt[e + 6];
        const int o2 = srt[e + 12];
        const int o3 = srt[e + 18];
        const uint2 u0 = *(const uint2*)(xb + o0);
        const uint2 u1 = *(const uint2*)(xb + o1);
        const uint2 u2 = *(const uint2*)(xb + o2);
        const uint2 u3 = *(const uint2*)(xb + o3);
        union { unsigned u; __half2 h; } c;
        float2 f;
        c.u = u0.x; f = __half22float2(c.h); ax += f.x; ay += f.y;
        c.u = u0.y; f = __half22float2(c.h); az += f.x; aw += f.y;
        c.u = u1.x; f = __half22float2(c.h); ax += f.x; ay += f.y;
        c.u = u1.y; f = __half22float2(c.h); az += f.x; aw += f.y;
        c.u = u2.x; f = __half22float2(c.h); ax += f.x; ay += f.y;
        c.u = u2.y; f = __half22float2(c.h); az += f.x; aw += f.y;
        c.u = u3.x; f = __half22float2(c.h); ax += f.x; ay += f.y;
        c.u = u3.y; f = __half22float2(c.h); az += f.x; aw += f.y;
    }

    // cross-slot reduce: lane f4 (<10) += slots 1..5
    float rx = ax, ry = ay, rz = az, rw = aw;
    #pragma unroll
    for (int s = 10; s <= 50; s += 10) {
        rx += __shfl(ax, f4 + s);
        ry += __shfl(ay, f4 + s);
        rz += __shfl(az, f4 + s);
        rw += __shfl(aw, f4 + s);
    }
    if (lane < 10) {
        float4 o; o.x = rx; o.y = ry; o.z = rz; o.w = rw;
        *(float4*)(agg + (size_t)n * 40 + f4 * 4) = o;
    }
}

// ---------------------------------------------------------------------------
// GraphConv via MFMA, K=160: A = [agg_hi|x_hi|agg_lo|x_lo] bf16 (hi/lo split
// for near-fp32 A-side), W = [w_rel|w_root|w_rel|w_root] bf16.
// ---------------------------------------------------------------------------
__global__ void graphconv_mfma_kernel(const float* __restrict__ agg,
                                      const float* __restrict__ x,
                                      const unsigned short* __restrict__ Wg,
                                      const float* __restrict__ b,
                                      unsigned short* __restrict__ C, int N)
{
    __shared__ __align__(16) unsigned short aT[64 * 168];  // 168 = 160 + 8 pad
    const int t = threadIdx.x;
    const int n0 = blockIdx.x * 64;
    const int wave = t >> 6, lane = t & 63, q = lane >> 4, l16 = lane & 15;

    for (int u = t; u < 640; u += 256) {
        const int row = u / 10, c = (u % 10) * 4;
        const int srow = min(n0 + row, N - 1);
        const float4 fa = *(const float4*)(agg + (size_t)srow * 40 + c);
        const float4 fx = *(const float4*)(x + (size_t)srow * 40 + c);
        const float av[4] = {fa.x, fa.y, fa.z, fa.w};
        const float xv[4] = {fx.x, fx.y, fx.z, fx.w};
        ushort4 ha, la, hx, lx;
        ha.x = f2bf(av[0]); la.x = f2bf(av[0] - bf2f(ha.x));
        ha.y = f2bf(av[1]); la.y = f2bf(av[1] - bf2f(ha.y));
        ha.z = f2bf(av[2]); la.z = f2bf(av[2] - bf2f(ha.z));
        ha.w = f2bf(av[3]); la.w = f2bf(av[3] - bf2f(ha.w));
        hx.x = f2bf(xv[0]); lx.x = f2bf(xv[0] - bf2f(hx.x));
        hx.y = f2bf(xv[1]); lx.y = f2bf(xv[1] - bf2f(hx.y));
        hx.z = f2bf(xv[2]); lx.z = f2bf(xv[2] - bf2f(hx.z));
        hx.w = f2bf(xv[3]); lx.w = f2bf(xv[3] - bf2f(hx.w));
        unsigned short* rp = aT + row * 168;
        *(ushort4*)(rp + c)       = ha;
        *(ushort4*)(rp + 40 + c)  = hx;
        *(ushort4*)(rp + 80 + c)  = la;
        *(ushort4*)(rp + 120 + c) = lx;
    }
    __syncthreads();

    f32x4 acc[4][4] = {};
    for (int k0 = 0; k0 < 160; k0 += 32) {
        short8 af[4], wf[4];
        #pragma unroll
        for (int nt = 0; nt < 4; nt++)
            af[nt] = *(const short8*)(aT + (nt * 16 + l16) * 168 + k0 + q * 8);
        #pragma unroll
        for (int mt = 0; mt < 4; mt++)
            wf[mt] = *(const short8*)(Wg + (wave * 64 + mt * 16 + l16) * 160 + k0 + q * 8);
        #pragma unroll
        for (int nt = 0; nt < 4; nt++)
            #pragma unroll
            for (int mt = 0; mt < 4; mt++)
                acc[nt][mt] = __builtin_amdgcn_mfma_f32_16x16x32_bf16(af[nt], wf[mt], acc[nt][mt], 0, 0, 0);
    }

    float bias[4];
    #pragma unroll
    for (int mt = 0; mt < 4; mt++) bias[mt] = b[wave * 64 + mt * 16 + l16];

    #pragma unroll
    for (int nt = 0; nt < 4; nt++)
        #pragma unroll
        for (int r = 0; r < 4; r++) {
            const int row = n0 + nt * 16 + q * 4 + r;   // C/D: row=quad*4+reg
            if (row >= N) continue;
            #pragma unroll
            for (int mt = 0; mt < 4; mt++) {
                const int col = wave * 64 + mt * 16 + l16;  // C/D: col=lane&15
                C[(size_t)row * 256 + col] = f2bf(lrelu(acc[nt][mt][r] + bias[mt]));
            }
        }
}

// ---------------------------------------------------------------------------
// MLP layer via MFMA: C = lrelu(A @ W^T + b), A [N,256] bf16, W [256,256] bf16.
// ---------------------------------------------------------------------------
__global__ void mlp_mfma_kernel(const unsigned short* __restrict__ A,
                                const unsigned short* __restrict__ W,
                                const float* __restrict__ b,
                                unsigned short* __restrict__ C, int N)
{
    __shared__ __align__(16) unsigned short aT[64 * 264];  // 264 = 256 + 8 pad
    const int t = threadIdx.x;
    const int n0 = blockIdx.x * 64;
    const int wave = t >> 6, lane = t & 63, q = lane >> 4, l16 = lane & 15;

    #pragma unroll
    for (int i = 0; i < 8; i++) {
        const int u = t + 256 * i;
        const int row = u >> 5, c16 = u & 31;
        const int srow = min(n0 + row, N - 1);
        *(uint4*)(aT + row * 264 + c16 * 8) = *(const uint4*)(A + (size_t)srow * 256 + c16 * 8);
    }
    __syncthreads();

    f32x4 acc[4][4] = {};
    const unsigned short* wbase = W + (wave * 64 + l16) * 256 + q * 8;
    for (int k0 = 0; k0 < 256; k0 += 32) {
        short8 af[4], wf[4];
        #pragma unroll
        for (int nt = 0; nt < 4; nt++)
            af[nt] = *(const short8*)(aT + (nt * 16 + l16) * 264 + k0 + q * 8);
        #pragma unroll
        for (int mt = 0; mt < 4; mt++)
            wf[mt] = *(const short8*)(wbase + mt * 16 * 256 + k0);
        #pragma unroll
        for (int nt = 0; nt < 4; nt++)
            #pragma unroll
            for (int mt = 0; mt < 4; mt++)
                acc[nt][mt] = __builtin_amdgcn_mfma_f32_16x16x32_bf16(af[nt], wf[mt], acc[nt][mt], 0, 0, 0);
    }

    float bias[4];
    #pragma unroll
    for (int mt = 0; mt < 4; mt++) bias[mt] = b[wave * 64 + mt * 16 + l16];

    #pragma unroll
    for (int nt = 0; nt < 4; nt++)
        #pragma unroll
        for (int r = 0; r < 4; r++) {
            const int row = n0 + nt * 16 + q * 4 + r;
            if (row >= N) continue;
            #pragma unroll
            for (int mt = 0; mt < 4; mt++) {
                const int col = wave * 64 + mt * 16 + l16;
                C[(size_t)row * 256 + col] = f2bf(lrelu(acc[nt][mt][r] + bias[mt]));
            }
        }
}

// ---------------------------------------------------------------------------
// Pred: out[n] = h[n] . w_pred + b_pred.  One wave per node; h is bf16.
// ---------------------------------------------------------------------------
__global__ void pred_kernel(const unsigned short* __restrict__ h,
                            const float* __restrict__ w,
                            const float* __restrict__ b,
                            float* __restrict__ out, int N)
{
    __shared__ float s_w[256];
    const int t = threadIdx.x;
    s_w[t] = w[t];
    __syncthreads();

    const int wave = t / 64, lane = t % 64;
    const int n = blockIdx.x * 4 + wave;
    if (n >= N) return;

    float v = 0.f;
    #pragma unroll
    for (int j = 0; j < 4; j++)
        v += bf2f(h[(size_t)n * 256 + lane + j * 64]) * s_w[lane + j * 64];

    #pragma unroll
    for (int off = 32; off > 0; off >>= 1)
        v += __shfl_down(v, off);

    if (lane == 0) out[n] = v + b[0];
}

// ---------------------------------------------------------------------------
extern "C" void kernel_launch(void* const* d_in, const int* in_sizes, int n_in,
                              void* d_out, int out_size, void* d_ws, size_t ws_size,
                              hipStream_t stream)
{
    const float* pose   = (const float*)d_in[0];
    const float* views  = (const float*)d_in[1];
    const int*   ei     = (const int*)d_in[2];
    const float* w_e1   = (const float*)d_in[3];
    const float* b_e1   = (const float*)d_in[4];
    const float* w_e2   = (const float*)d_in[5];
    const float* b_e2   = (const float*)d_in[6];
    const float* w_rel  = (const float*)d_in[7];
    const float* b_rel  = (const float*)d_in[8];
    const float* w_root = (const float*)d_in[9];
    const float* w_l1   = (const float*)d_in[10];
    const float* b_l1   = (const float*)d_in[11];
    const float* w_l2   = (const float*)d_in[12];
    const float* b_l2   = (const float*)d_in[13];
    const float* w_l3   = (const float*)d_in[14];
    const float* b_l3   = (const float*)d_in[15];
    const float* w_pred = (const float*)d_in[16];
    const float* b_pred = (const float*)d_in[17];
    float* out = (float*)d_out;

    const int N = in_sizes[0] / 3;       // 50000
    const int E = in_sizes[2] / 2;       // 4950000
    const int NB = (N + 63) >> 6;        // 782 buckets
    const int NBLK = (N + 63) / 64;      // row blocks for GEMMs

    // Workspace layout. hb0/hb1 alias pairs/sorted: graph ints are fully dead
    // (last read = gather_sum) before graphconv/mlp write hb0/hb1.
    float* x   = (float*)d_ws;                       // N*40 fp32
    float* agg = x + (size_t)N * 40;                 // N*40 fp32
    int* pairs  = (int*)(agg + (size_t)N * 40);      // NB*CAP ints (27.2 MB)
    int* sorted = pairs + (size_t)NB * CAP;          // NB*CAP ints (27.2 MB)
    unsigned short* hb0 = (unsigned short*)pairs;    // N*256 bf16 alias
    unsigned short* hb1 = (unsigned short*)sorted;   // N*256 bf16 alias
    int* gcur       = sorted + (size_t)NB * CAP;     // 1024
    int* node_start = gcur + 1024;                   // NB*64
    int* node_cnt   = node_start + NB * 64;          // NB*64
    unsigned short* Wb1 = (unsigned short*)(node_cnt + NB * 64);  // 256*256
    unsigned short* Wb2 = Wb1 + 256 * 256;
    unsigned short* Wb3 = Wb2 + 256 * 256;
    unsigned short* Wg  = Wb3 + 256 * 256;           // 256*160
    __half* xh = (__half*)(Wg + 256 * 160);          // (N+1)*40 fp16; row N = zeros

    prep_kernel<<<256, 256, 0, stream>>>(w_l1, w_l2, w_l3, w_rel, w_root,
                                         Wb1, Wb2, Wb3, Wg, gcur, xh, N);

    encoder_kernel<<<(N + 3) / 4, 256, 0, stream>>>(pose, views, w_e1, b_e1, w_e2, b_e2, x, xh, N);

    bin_kernel<<<(E + EPB - 1) / EPB, 512, 0, stream>>>(ei, gcur, pairs, E, NB);
    bucket_sort_kernel<<<NB, 256, 0, stream>>>(gcur, pairs, sorted, node_start, node_cnt, N);
    gather_sum_kernel<<<NB * 16, 256, 0, stream>>>(sorted, node_start, node_cnt, xh, agg, N);

    graphconv_mfma_kernel<<<NBLK, 256, 0, stream>>>(agg, x, Wg, b_rel, hb0, N);
    mlp_mfma_kernel<<<NBLK, 256, 0, stream>>>(hb0, Wb1, b_l1, hb1, N);
    mlp_mfma_kernel<<<NBLK, 256, 0, stream>>>(hb1, Wb2, b_l2, hb0, N);
    mlp_mfma_kernel<<<NBLK, 256, 0, stream>>>(hb0, Wb3, b_l3, hb1, N);
    pred_kernel<<<(N + 3) / 4, 256, 0, stream>>>(hb1, w_pred, b_pred, out, N);
}

// Round 12
// 391.224 us; speedup vs baseline: 5.3896x; 1.0357x over previous
//
#include <hip/hip_runtime.h>
#include <hip/hip_fp16.h>

#define NEG_SLOPE 0.1f
__device__ __forceinline__ float lrelu(float v) { return fmaxf(v, NEG_SLOPE * v); }

constexpr int CAP = 8704;   // per-bucket capacity (mean 6330 + 24-align pads)
constexpr int EPB = 8192;   // edges per bin block (16 per thread, 512 threads)

typedef __attribute__((ext_vector_type(8))) short short8;   // 8 bf16 (4 VGPRs)
typedef __attribute__((ext_vector_type(4))) float f32x4;    // MFMA accum

__device__ __forceinline__ unsigned short f2bf(float f) {   // RNE
    union { float f; unsigned u; } v; v.f = f;
    const unsigned r = v.u + 0x7FFF + ((v.u >> 16) & 1);
    return (unsigned short)(r >> 16);
}
__device__ __forceinline__ float bf2f(unsigned short h) {
    union { unsigned u; float f; } v; v.u = ((unsigned)h) << 16;
    return v.f;
}

// ---------------------------------------------------------------------------
// Encoder (+fused prep in blocks 0..255): 4 nodes per 256-thread block.
// Emits x as bf16 hi/lo (for graphconv) and fp16 (for the gather). Prep:
// bf16 weight conversions, Wg build, gcur zero, xh sentinel row.
// ---------------------------------------------------------------------------
__global__ __launch_bounds__(256) void encoder_kernel(
        const float* __restrict__ pose,
        const float* __restrict__ views,
        const float* __restrict__ w1, const float* __restrict__ b1,
        const float* __restrict__ w2, const float* __restrict__ b2,
        const float* __restrict__ w_l1, const float* __restrict__ w_l2,
        const float* __restrict__ w_l3, const float* __restrict__ w_rel,
        const float* __restrict__ w_root,
        unsigned short* __restrict__ Wb1, unsigned short* __restrict__ Wb2,
        unsigned short* __restrict__ Wb3, unsigned short* __restrict__ Wg,
        int* __restrict__ gcur,
        unsigned short* __restrict__ xHi, unsigned short* __restrict__ xLo,
        __half* __restrict__ xh, int N)
{
    __shared__ float s_w1[81];
    __shared__ float s_b1[9];
    __shared__ float s_w2[27];
    __shared__ float s_b2[1];
    __shared__ float s_c1[4][9][80];   // [lnode][oc][(p&1)*40 + (p>>1)]

    const int t = threadIdx.x;

    // fused prep (first 256 blocks)
    if (blockIdx.x < 256) {
        const int i = blockIdx.x * 256 + t;
        Wb1[i] = f2bf(w_l1[i]);
        Wb2[i] = f2bf(w_l2[i]);
        Wb3[i] = f2bf(w_l3[i]);
        if (i < 40960) {   // Wg[256][160] = [w_rel|w_root|w_rel|w_root]
            const int m = i / 160, c = i % 160;
            const int k = c % 80;
            const float v = (k < 40) ? w_rel[m * 40 + k] : w_root[m * 40 + (k - 40)];
            Wg[i] = f2bf(v);
        }
        if (i < 1024) gcur[i] = 0;
        if (i < 40) xh[(size_t)N * 40 + i] = __float2half(0.f);
    }

    if (t < 81) s_w1[t] = w1[t];
    if (t >= 96 && t < 105) s_b1[t - 96] = b1[t - 96];
    if (t >= 128 && t < 155) s_w2[t - 128] = w2[t - 128];
    if (t == 240) s_b2[0] = b2[0];
    __syncthreads();

    const int nb = blockIdx.x * 4;

    #pragma unroll
    for (int pass = 0; pass < 2; pass++) {
        const int task = pass * 256 + t;
        if (task < 300) {
            const int ln = task / 75;
            const int p  = task % 75;
            const int n  = min(nb + ln, N - 1);
            const float* __restrict__ vin = views + (size_t)n * 453 + 2 * p;
            float e[3], o[3], e1[3];
            #pragma unroll
            for (int ic = 0; ic < 3; ic++) {
                const float* ci = vin + ic * 151;
                e[ic] = ci[0]; o[ic] = ci[1]; e1[ic] = ci[2];
            }
            const int didx = (p & 1) * 40 + (p >> 1);
            #pragma unroll
            for (int oc = 0; oc < 9; oc++) {
                float v = s_b1[oc];
                #pragma unroll
                for (int ic = 0; ic < 3; ic++)
                    v += s_w1[oc * 9 + ic * 3 + 0] * e[ic]
                       + s_w1[oc * 9 + ic * 3 + 1] * o[ic]
                       + s_w1[oc * 9 + ic * 3 + 2] * e1[ic];
                s_c1[ln][oc][didx] = lrelu(v);
            }
        }
    }
    __syncthreads();

    if (t < 160) {
        const int ln = t / 40, f = t % 40;
        const int n  = min(nb + ln, N - 1);
        float outv;
        if (f < 3) {
            outv = pose[(size_t)n * 3 + f];
        } else {
            const int ow = f - 3;
            float v = s_b2[0];
            #pragma unroll
            for (int ic = 0; ic < 9; ic++)
                v += s_w2[ic * 3 + 0] * s_c1[ln][ic][ow]
                   + s_w2[ic * 3 + 1] * s_c1[ln][ic][40 + ow]
                   + s_w2[ic * 3 + 2] * s_c1[ln][ic][ow + 1];
            outv = lrelu(v);
        }
        const unsigned short hi = f2bf(outv);
        const unsigned short lo = f2bf(outv - bf2f(hi));
        xHi[(size_t)n * 40 + f] = hi;
        xLo[(size_t)n * 40 + f] = lo;
        xh[(size_t)n * 40 + f] = __float2half(outv);
    }
}

// ---------------------------------------------------------------------------
// Coarse binning (512 thr, 8192 edges/block): rank via LDS histogram, stage
// bucket-ordered in LDS, linear write-out. Packed entry = src*80 | dloc<<22.
// ---------------------------------------------------------------------------
__global__ __launch_bounds__(512) void bin_kernel(
        const int* __restrict__ ei, int* __restrict__ gcur,
        int* __restrict__ pairs, int E, int NB)
{
    __shared__ int s_hist[1024];
    __shared__ int s_loff[1024];
    __shared__ int s_base[1024];
    __shared__ int s_wave8[8];
    __shared__ int s_pk[EPB];                 // 32 KB
    __shared__ unsigned short s_bkt[EPB];     // 16 KB
    const int t = threadIdx.x;
    const int lane = t & 63, wid = t >> 6;    // 8 waves
    const int e0 = blockIdx.x * EPB + t * 16;
    const int tot = min(E - blockIdx.x * EPB, EPB);

    for (int i = t; i < 1024; i += 512) s_hist[i] = 0;
    __syncthreads();

    int pk[16], mt[16];
    auto proc = [&](int j, int sv, int dv) {
        const int b = dv >> 6;
        const int r = atomicAdd(&s_hist[b], 1);   // local rank (LDS atomic)
        pk[j] = sv * 80 | ((dv & 63) << 22);
        mt[j] = b | (r << 10);
    };

    if (e0 + 16 <= E) {
        #pragma unroll
        for (int q = 0; q < 4; q++) {
            const int4 sv = *(const int4*)(ei + e0 + 4 * q);
            const int4 dv = *(const int4*)(ei + E + e0 + 4 * q);
            proc(4 * q + 0, sv.x, dv.x);
            proc(4 * q + 1, sv.y, dv.y);
            proc(4 * q + 2, sv.z, dv.z);
            proc(4 * q + 3, sv.w, dv.w);
        }
    } else {
        #pragma unroll
        for (int j = 0; j < 16; j++) {
            mt[j] = -1;
            const int e = e0 + j;
            if (e < E) proc(j, ei[e], ei[E + e]);
        }
    }
    __syncthreads();

    // exclusive scan of s_hist[0..1023] -> s_loff
    int carry = 0;
    #pragma unroll
    for (int base = 0; base < 1024; base += 512) {
        const int i = base + t;
        const int v = s_hist[i];
        int sc = v;
        #pragma unroll
        for (int d = 1; d < 64; d <<= 1) {
            const int u = __shfl_up(sc, d);
            if (lane >= d) sc += u;
        }
        if (lane == 63) s_wave8[wid] = sc;
        __syncthreads();
        if (wid == 0) {
            int wv = (lane < 8) ? s_wave8[lane] : 0;
            #pragma unroll
            for (int d = 1; d < 8; d <<= 1) {
                const int u = __shfl_up(wv, d);
                if (lane >= d) wv += u;
            }
            if (lane < 8) s_wave8[lane] = wv;
        }
        __syncthreads();
        const int waveoff = (wid > 0) ? s_wave8[wid - 1] : 0;
        s_loff[i] = carry + waveoff + sc - v;
        const int chunk_tot = s_wave8[7];
        __syncthreads();
        carry += chunk_tot;
    }

    for (int i = t; i < NB; i += 512) {
        const int c = s_hist[i];
        if (c > 0) s_base[i] = atomicAdd(&gcur[i], c);
    }
    __syncthreads();

    #pragma unroll
    for (int j = 0; j < 16; j++) {
        if (mt[j] >= 0) {
            const int b = mt[j] & 1023;
            const int pos = s_loff[b] + (mt[j] >> 10);
            s_pk[pos] = pk[j];
            s_bkt[pos] = (unsigned short)b;
        }
    }
    __syncthreads();

    for (int i = t; i < tot; i += 512) {
        const int b = s_bkt[i];
        const int p = s_base[b] + (i - s_loff[b]);
        if (p < CAP) pairs[b * CAP + p] = s_pk[i];
    }
}

// ---------------------------------------------------------------------------
// Per-bucket exact counting sort (LDS only). Runs 24-aligned; pads = byte
// offset N*80 (zero row). sorted[] holds byte offsets src*80.
// ---------------------------------------------------------------------------
__global__ void bucket_sort_kernel(const int* __restrict__ gcur,
                                   const int* __restrict__ pairs,
                                   int* __restrict__ sorted,
                                   int* __restrict__ node_start,
                                   int* __restrict__ node_cnt, int N)
{
    __shared__ int s_cnt[64], s_off[64], s_cur[64];
    const int b = blockIdx.x;
    const int t = threadIdx.x;
    const int cnt = min(gcur[b], CAP);
    const int* __restrict__ pr = pairs + b * CAP;
    int* __restrict__ so = sorted + (size_t)b * CAP;

    if (t < 64) s_cnt[t] = 0;
    __syncthreads();
    for (int i = t; i < cnt; i += 256)
        atomicAdd(&s_cnt[pr[i] >> 22], 1);
    __syncthreads();

    if (t < 64) {   // exclusive scan of 24-aligned counts
        const int c = s_cnt[t];
        const int p = ((c + 23) / 24) * 24;
        int sc = p;
        #pragma unroll
        for (int d = 1; d < 64; d <<= 1) {
            const int u = __shfl_up(sc, d);
            if (t >= d) sc += u;
        }
        const int excl = sc - p;
        s_off[t] = excl;
        s_cur[t] = excl;
        node_start[b * 64 + t] = b * CAP + excl;
        node_cnt[b * 64 + t] = c;
    }
    __syncthreads();

    if (t < 64) {   // pad fill: sentinel byte offset N*80 (zero row in xh)
        const int e0 = s_off[t] + s_cnt[t];
        const int e1 = s_off[t] + ((s_cnt[t] + 23) / 24) * 24;
        for (int i = e0; i < e1 && i < CAP; i++) so[i] = N * 80;
    }
    for (int i = t; i < cnt; i += 256) {
        const int p = pr[i];
        const int pos = atomicAdd(&s_cur[p >> 22], 1);
        if (pos < CAP) so[pos] = p & 0x3FFFFF;
    }
}

// ---------------------------------------------------------------------------
// Segment sum: one wave per node, 6 edge-slots x 10 feature-quads, 8B uint2
// fp16 gathers, byte-offset indices. Writes agg as bf16 hi/lo directly.
// ---------------------------------------------------------------------------
__global__ void gather_sum_kernel(const int* __restrict__ sorted,
                                  const int* __restrict__ node_start,
                                  const int* __restrict__ node_cnt,
                                  const __half* __restrict__ xh,
                                  unsigned short* __restrict__ aggHi,
                                  unsigned short* __restrict__ aggLo, int N)
{
    const int n = blockIdx.x * 4 + (threadIdx.x >> 6);
    const int lane = threadIdx.x & 63;
    if (n >= N) return;

    const int start = node_start[n];
    const int cntp = ((node_cnt[n] + 23) / 24) * 24;
    const int slot = min(lane / 10, 5);          // lanes 60..63 duplicate slot 5
    const int f4 = lane % 10;                    // feature quad (4 halfs)
    const int* __restrict__ srt = sorted + start + slot;
    const char* __restrict__ xb = (const char*)xh + f4 * 8;

    float ax = 0.f, ay = 0.f, az = 0.f, aw = 0.f;
    for (int e = 0; e < cntp; e += 24) {
        const int o0 = srt[e];
        const int o1 = srt[e + 6];
        const int o2 = srt[e + 12];
        const int o3 = srt[e + 18];
        const uint2 u0 = *(const uint2*)(xb + o0);
        const uint2 u1 = *(const uint2*)(xb + o1);
        const uint2 u2 = *(const uint2*)(xb + o2);
        const uint2 u3 = *(const uint2*)(xb + o3);
        union { unsigned u; __half2 h; } c;
        float2 f;
        c.u = u0.x; f = __half22float2(c.h); ax += f.x; ay += f.y;
        c.u = u0.y; f = __half22float2(c.h); az += f.x; aw += f.y;
        c.u = u1.x; f = __half22float2(c.h); ax += f.x; ay += f.y;
        c.u = u1.y; f = __half22float2(c.h); az += f.x; aw += f.y;
        c.u = u2.x; f = __half22float2(c.h); ax += f.x; ay += f.y;
        c.u = u2.y; f = __half22float2(c.h); az += f.x; aw += f.y;
        c.u = u3.x; f = __half22float2(c.h); ax += f.x; ay += f.y;
        c.u = u3.y; f = __half22float2(c.h); az += f.x; aw += f.y;
    }

    float rx = ax, ry = ay, rz = az, rw = aw;
    #pragma unroll
    for (int s = 10; s <= 50; s += 10) {
        rx += __shfl(ax, f4 + s);
        ry += __shfl(ay, f4 + s);
        rz += __shfl(az, f4 + s);
        rw += __shfl(aw, f4 + s);
    }
    if (lane < 10) {
        ushort4 hi, lo;
        hi.x = f2bf(rx); lo.x = f2bf(rx - bf2f(hi.x));
        hi.y = f2bf(ry); lo.y = f2bf(ry - bf2f(hi.y));
        hi.z = f2bf(rz); lo.z = f2bf(rz - bf2f(hi.z));
        hi.w = f2bf(rw); lo.w = f2bf(rw - bf2f(hi.w));
        *(ushort4*)(aggHi + (size_t)n * 40 + f4 * 4) = hi;
        *(ushort4*)(aggLo + (size_t)n * 40 + f4 * 4) = lo;
    }
}

// ---------------------------------------------------------------------------
// GraphConv via MFMA, K=160: A = [aggHi|xHi|aggLo|xLo] bf16 (pure copies, no
// conversion), W = [w_rel|w_root|w_rel|w_root] bf16.
// ---------------------------------------------------------------------------
__global__ void graphconv_mfma_kernel(const unsigned short* __restrict__ aggHi,
                                      const unsigned short* __restrict__ aggLo,
                                      const unsigned short* __restrict__ xHi,
                                      const unsigned short* __restrict__ xLo,
                                      const unsigned short* __restrict__ Wg,
                                      const float* __restrict__ b,
                                      unsigned short* __restrict__ C, int N)
{
    __shared__ __align__(16) unsigned short aT[64 * 168];  // 168 = 160 + 8 pad
    const int t = threadIdx.x;
    const int n0 = blockIdx.x * 64;
    const int wave = t >> 6, lane = t & 63, q = lane >> 4, l16 = lane & 15;

    for (int u = t; u < 640; u += 256) {
        const int row = u / 10, c = (u % 10) * 4;
        const int srow = min(n0 + row, N - 1);
        const size_t off = (size_t)srow * 40 + c;
        const ushort4 ha = *(const ushort4*)(aggHi + off);
        const ushort4 hx = *(const ushort4*)(xHi + off);
        const ushort4 la = *(const ushort4*)(aggLo + off);
        const ushort4 lx = *(const ushort4*)(xLo + off);
        unsigned short* rp = aT + row * 168;
        *(ushort4*)(rp + c)       = ha;
        *(ushort4*)(rp + 40 + c)  = hx;
        *(ushort4*)(rp + 80 + c)  = la;
        *(ushort4*)(rp + 120 + c) = lx;
    }
    __syncthreads();

    f32x4 acc[4][4] = {};
    for (int k0 = 0; k0 < 160; k0 += 32) {
        short8 af[4], wf[4];
        #pragma unroll
        for (int nt = 0; nt < 4; nt++)
            af[nt] = *(const short8*)(aT + (nt * 16 + l16) * 168 + k0 + q * 8);
        #pragma unroll
        for (int mt = 0; mt < 4; mt++)
            wf[mt] = *(const short8*)(Wg + (wave * 64 + mt * 16 + l16) * 160 + k0 + q * 8);
        #pragma unroll
        for (int nt = 0; nt < 4; nt++)
            #pragma unroll
            for (int mt = 0; mt < 4; mt++)
                acc[nt][mt] = __builtin_amdgcn_mfma_f32_16x16x32_bf16(af[nt], wf[mt], acc[nt][mt], 0, 0, 0);
    }

    float bias[4];
    #pragma unroll
    for (int mt = 0; mt < 4; mt++) bias[mt] = b[wave * 64 + mt * 16 + l16];

    #pragma unroll
    for (int nt = 0; nt < 4; nt++)
        #pragma unroll
        for (int r = 0; r < 4; r++) {
            const int row = n0 + nt * 16 + q * 4 + r;   // C/D: row=quad*4+reg
            if (row >= N) continue;
            #pragma unroll
            for (int mt = 0; mt < 4; mt++) {
                const int col = wave * 64 + mt * 16 + l16;  // C/D: col=lane&15
                C[(size_t)row * 256 + col] = f2bf(lrelu(acc[nt][mt][r] + bias[mt]));
            }
        }
}

// ---------------------------------------------------------------------------
// MLP layer via MFMA: C = lrelu(A @ W^T + b), A [N,256] bf16, W [256,256] bf16.
// ---------------------------------------------------------------------------
__global__ void mlp_mfma_kernel(const unsigned short* __restrict__ A,
                                const unsigned short* __restrict__ W,
                                const float* __restrict__ b,
                                unsigned short* __restrict__ C, int N)
{
    __shared__ __align__(16) unsigned short aT[64 * 264];  // 264 = 256 + 8 pad
    const int t = threadIdx.x;
    const int n0 = blockIdx.x * 64;
    const int wave = t >> 6, lane = t & 63, q = lane >> 4, l16 = lane & 15;

    #pragma unroll
    for (int i = 0; i < 8; i++) {
        const int u = t + 256 * i;
        const int row = u >> 5, c16 = u & 31;
        const int srow = min(n0 + row, N - 1);
        *(uint4*)(aT + row * 264 + c16 * 8) = *(const uint4*)(A + (size_t)srow * 256 + c16 * 8);
    }
    __syncthreads();

    f32x4 acc[4][4] = {};
    const unsigned short* wbase = W + (wave * 64 + l16) * 256 + q * 8;
    for (int k0 = 0; k0 < 256; k0 += 32) {
        short8 af[4], wf[4];
        #pragma unroll
        for (int nt = 0; nt < 4; nt++)
            af[nt] = *(const short8*)(aT + (nt * 16 + l16) * 264 + k0 + q * 8);
        #pragma unroll
        for (int mt = 0; mt < 4; mt++)
            wf[mt] = *(const short8*)(wbase + mt * 16 * 256 + k0);
        #pragma unroll
        for (int nt = 0; nt < 4; nt++)
            #pragma unroll
            for (int mt = 0; mt < 4; mt++)
                acc[nt][mt] = __builtin_amdgcn_mfma_f32_16x16x32_bf16(af[nt], wf[mt], acc[nt][mt], 0, 0, 0);
    }

    float bias[4];
    #pragma unroll
    for (int mt = 0; mt < 4; mt++) bias[mt] = b[wave * 64 + mt * 16 + l16];

    #pragma unroll
    for (int nt = 0; nt < 4; nt++)
        #pragma unroll
        for (int r = 0; r < 4; r++) {
            const int row = n0 + nt * 16 + q * 4 + r;
            if (row >= N) continue;
            #pragma unroll
            for (int mt = 0; mt < 4; mt++) {
                const int col = wave * 64 + mt * 16 + l16;
                C[(size_t)row * 256 + col] = f2bf(lrelu(acc[nt][mt][r] + bias[mt]));
            }
        }
}

// ---------------------------------------------------------------------------
// Final MLP layer FUSED with pred: out[n] = lrelu(A@W3^T+b3)[n] . w_pred
// + b_pred. h3 never hits memory: epilogue dots the fp32 accumulators with
// w_pred, shfl_xor-reduces the 16-lane col group, LDS-reduces across waves.
// ---------------------------------------------------------------------------
__global__ void mlp_pred_kernel(const unsigned short* __restrict__ A,
                                const unsigned short* __restrict__ W,
                                const float* __restrict__ b,
                                const float* __restrict__ w_pred,
                                const float* __restrict__ b_pred,
                                float* __restrict__ out, int N)
{
    __shared__ __align__(16) unsigned short aT[64 * 264];
    __shared__ float s_part[4][64];
    const int t = threadIdx.x;
    const int n0 = blockIdx.x * 64;
    const int wave = t >> 6, lane = t & 63, q = lane >> 4, l16 = lane & 15;

    #pragma unroll
    for (int i = 0; i < 8; i++) {
        const int u = t + 256 * i;
        const int row = u >> 5, c16 = u & 31;
        const int srow = min(n0 + row, N - 1);
        *(uint4*)(aT + row * 264 + c16 * 8) = *(const uint4*)(A + (size_t)srow * 256 + c16 * 8);
    }
    __syncthreads();

    f32x4 acc[4][4] = {};
    const unsigned short* wbase = W + (wave * 64 + l16) * 256 + q * 8;
    for (int k0 = 0; k0 < 256; k0 += 32) {
        short8 af[4], wf[4];
        #pragma unroll
        for (int nt = 0; nt < 4; nt++)
            af[nt] = *(const short8*)(aT + (nt * 16 + l16) * 264 + k0 + q * 8);
        #pragma unroll
        for (int mt = 0; mt < 4; mt++)
            wf[mt] = *(const short8*)(wbase + mt * 16 * 256 + k0);
        #pragma unroll
        for (int nt = 0; nt < 4; nt++)
            #pragma unroll
            for (int mt = 0; mt < 4; mt++)
                acc[nt][mt] = __builtin_amdgcn_mfma_f32_16x16x32_bf16(af[nt], wf[mt], acc[nt][mt], 0, 0, 0);
    }

    float bias[4], wp[4];
    #pragma unroll
    for (int mt = 0; mt < 4; mt++) {
        const int col = wave * 64 + mt * 16 + l16;
        bias[mt] = b[col];
        wp[mt] = w_pred[col];
    }

    #pragma unroll
    for (int nt = 0; nt < 4; nt++)
        #pragma unroll
        for (int r = 0; r < 4; r++) {
            float p = 0.f;
            #pragma unroll
            for (int mt = 0; mt < 4; mt++)
                p += lrelu(acc[nt][mt][r] + bias[mt]) * wp[mt];
            // reduce over the 16-lane column group (same q, l16 = 0..15)
            p += __shfl_xor(p, 1);
            p += __shfl_xor(p, 2);
            p += __shfl_xor(p, 4);
            p += __shfl_xor(p, 8);
            if (l16 == 0) s_part[wave][nt * 16 + q * 4 + r] = p;
        }
    __syncthreads();

    if (t < 64) {
        const int row = n0 + t;
        if (row < N)
            out[row] = s_part[0][t] + s_part[1][t] + s_part[2][t] + s_part[3][t] + b_pred[0];
    }
}

// ---------------------------------------------------------------------------
extern "C" void kernel_launch(void* const* d_in, const int* in_sizes, int n_in,
                              void* d_out, int out_size, void* d_ws, size_t ws_size,
                              hipStream_t stream)
{
    const float* pose   = (const float*)d_in[0];
    const float* views  = (const float*)d_in[1];
    const int*   ei     = (const int*)d_in[2];
    const float* w_e1   = (const float*)d_in[3];
    const float* b_e1   = (const float*)d_in[4];
    const float* w_e2   = (const float*)d_in[5];
    const float* b_e2   = (const float*)d_in[6];
    const float* w_rel  = (const float*)d_in[7];
    const float* b_rel  = (const float*)d_in[8];
    const float* w_root = (const float*)d_in[9];
    const float* w_l1   = (const float*)d_in[10];
    const float* b_l1   = (const float*)d_in[11];
    const float* w_l2   = (const float*)d_in[12];
    const float* b_l2   = (const float*)d_in[13];
    const float* w_l3   = (const float*)d_in[14];
    const float* b_l3   = (const float*)d_in[15];
    const float* w_pred = (const float*)d_in[16];
    const float* b_pred = (const float*)d_in[17];
    float* out = (float*)d_out;

    const int N = in_sizes[0] / 3;       // 50000
    const int E = in_sizes[2] / 2;       // 4950000
    const int NB = (N + 63) >> 6;        // 782 buckets
    const int NBLK = (N + 63) / 64;      // row blocks for GEMMs

    // Workspace layout. hb0/hb1 alias pairs/sorted: graph ints are fully dead
    // (pairs after bucket_sort, sorted after gather) before hb0/hb1 writes.
    unsigned short* xHi = (unsigned short*)d_ws;     // N*40 bf16 (4 MB)
    unsigned short* xLo = xHi + (size_t)N * 40;      // N*40 bf16
    unsigned short* aggHi = xLo + (size_t)N * 40;    // N*40 bf16
    unsigned short* aggLo = aggHi + (size_t)N * 40;  // N*40 bf16
    __half* xh = (__half*)(aggLo + (size_t)N * 40);  // (N+1)*40 fp16; row N = 0
    int* pairs  = (int*)(xh + (size_t)(N + 1) * 40 + 24);   // NB*CAP ints (27.2 MB)
    int* sorted = pairs + (size_t)NB * CAP;          // NB*CAP ints (27.2 MB)
    unsigned short* hb0 = (unsigned short*)pairs;    // N*256 bf16 alias
    unsigned short* hb1 = (unsigned short*)sorted;   // N*256 bf16 alias
    int* gcur       = sorted + (size_t)NB * CAP;     // 1024
    int* node_start = gcur + 1024;                   // NB*64
    int* node_cnt   = node_start + NB * 64;          // NB*64
    unsigned short* Wb1 = (unsigned short*)(node_cnt + NB * 64);  // 256*256
    unsigned short* Wb2 = Wb1 + 256 * 256;
    unsigned short* Wb3 = Wb2 + 256 * 256;
    unsigned short* Wg  = Wb3 + 256 * 256;           // 256*160

    encoder_kernel<<<(N + 3) / 4, 256, 0, stream>>>(
        pose, views, w_e1, b_e1, w_e2, b_e2,
        w_l1, w_l2, w_l3, w_rel, w_root,
        Wb1, Wb2, Wb3, Wg, gcur, xHi, xLo, xh, N);

    bin_kernel<<<(E + EPB - 1) / EPB, 512, 0, stream>>>(ei, gcur, pairs, E, NB);
    bucket_sort_kernel<<<NB, 256, 0, stream>>>(gcur, pairs, sorted, node_start, node_cnt, N);
    gather_sum_kernel<<<NB * 16, 256, 0, stream>>>(sorted, node_start, node_cnt, xh, aggHi, aggLo, N);

    graphconv_mfma_kernel<<<NBLK, 256, 0, stream>>>(aggHi, aggLo, xHi, xLo, Wg, b_rel, hb0, N);
    mlp_mfma_kernel<<<NBLK, 256, 0, stream>>>(hb0, Wb1, b_l1, hb1, N);
    mlp_mfma_kernel<<<NBLK, 256, 0, stream>>>(hb1, Wb2, b_l2, hb0, N);
    mlp_pred_kernel<<<NBLK, 256, 0, stream>>>(hb0, Wb3, b_l3, w_pred, b_pred, out, N);
}

// Round 13
// 370.413 us; speedup vs baseline: 5.6924x; 1.0562x over previous
//
#include <hip/hip_runtime.h>
#include <hip/hip_fp16.h>

#define NEG_SLOPE 0.1f
__device__ __forceinline__ float lrelu(float v) { return fmaxf(v, NEG_SLOPE * v); }

constexpr int CAP = 8704;   // per-bucket capacity (mean 6330 + 24-align pads)
constexpr int EPB = 8192;   // edges per bin block (16 per thread, 512 threads)

typedef __attribute__((ext_vector_type(8))) short short8;   // 8 bf16 (4 VGPRs)
typedef __attribute__((ext_vector_type(4))) float f32x4;    // MFMA accum

__device__ __forceinline__ unsigned short f2bf(float f) {   // RNE
    union { float f; unsigned u; } v; v.f = f;
    const unsigned r = v.u + 0x7FFF + ((v.u >> 16) & 1);
    return (unsigned short)(r >> 16);
}
__device__ __forceinline__ float bf2f(unsigned short h) {
    union { unsigned u; float f; } v; v.u = ((unsigned)h) << 16;
    return v.f;
}

// ---------------------------------------------------------------------------
// FUSED encoder + bin (+prep): one heterogeneous 512-thread launch.
//   blocks [0, NBIN)        : edge binning (LDS histogram + staged write-out)
//   blocks [NBIN, NBIN+ENC) : encoder for 8 nodes; first 128 also do weight
//                             prep (bf16 conversions, Wg, xh sentinel row).
// encoder and bin are data-independent; gcur is zeroed by a prior memset.
// ---------------------------------------------------------------------------
struct BinSmem {
    int hist[1024], loff[1024], base[1024];
    int wave8[8];
    int pk[EPB];                  // 32 KB
    unsigned short bkt[EPB];      // 16 KB
};
struct EncSmem {
    float w1[81], b1v[9], w2[27], b2v[1];
    float c1[8][9][80];           // [lnode][oc][(p&1)*40 + (p>>1)]
};

__global__ __launch_bounds__(512) void enc_bin_kernel(
        // bin inputs
        const int* __restrict__ ei, int* __restrict__ gcur,
        int* __restrict__ pairs, int E, int NB, int NBIN,
        // encoder inputs
        const float* __restrict__ pose, const float* __restrict__ views,
        const float* __restrict__ w1, const float* __restrict__ b1,
        const float* __restrict__ w2, const float* __restrict__ b2,
        // prep inputs
        const float* __restrict__ w_l1, const float* __restrict__ w_l2,
        const float* __restrict__ w_l3, const float* __restrict__ w_rel,
        const float* __restrict__ w_root,
        unsigned short* __restrict__ Wb1, unsigned short* __restrict__ Wb2,
        unsigned short* __restrict__ Wb3, unsigned short* __restrict__ Wg,
        // encoder outputs
        unsigned short* __restrict__ xHi, unsigned short* __restrict__ xLo,
        __half* __restrict__ xh, int N)
{
    __shared__ __align__(16) char smem_raw[sizeof(BinSmem)];
    const int t = threadIdx.x;

    if (blockIdx.x < (unsigned)NBIN) {
        // ----------------- BIN PATH -----------------
        BinSmem& sm = *reinterpret_cast<BinSmem*>(smem_raw);
        const int lane = t & 63, wid = t >> 6;
        const int e0 = blockIdx.x * EPB + t * 16;
        const int tot = min(E - (int)blockIdx.x * EPB, EPB);

        for (int i = t; i < 1024; i += 512) sm.hist[i] = 0;
        __syncthreads();

        int pk[16], mt[16];
        auto proc = [&](int j, int sv, int dv) {
            const int b = dv >> 6;
            const int r = atomicAdd(&sm.hist[b], 1);
            pk[j] = sv * 80 | ((dv & 63) << 22);
            mt[j] = b | (r << 10);
        };

        if (e0 + 16 <= E) {
            #pragma unroll
            for (int q = 0; q < 4; q++) {
                const int4 sv = *(const int4*)(ei + e0 + 4 * q);
                const int4 dv = *(const int4*)(ei + E + e0 + 4 * q);
                proc(4 * q + 0, sv.x, dv.x);
                proc(4 * q + 1, sv.y, dv.y);
                proc(4 * q + 2, sv.z, dv.z);
                proc(4 * q + 3, sv.w, dv.w);
            }
        } else {
            #pragma unroll
            for (int j = 0; j < 16; j++) {
                mt[j] = -1;
                const int e = e0 + j;
                if (e < E) proc(j, ei[e], ei[E + e]);
            }
        }
        __syncthreads();

        // exclusive scan hist -> loff
        int carry = 0;
        #pragma unroll
        for (int base = 0; base < 1024; base += 512) {
            const int i = base + t;
            const int v = sm.hist[i];
            int sc = v;
            #pragma unroll
            for (int d = 1; d < 64; d <<= 1) {
                const int u = __shfl_up(sc, d);
                if (lane >= d) sc += u;
            }
            if (lane == 63) sm.wave8[wid] = sc;
            __syncthreads();
            if (wid == 0) {
                int wv = (lane < 8) ? sm.wave8[lane] : 0;
                #pragma unroll
                for (int d = 1; d < 8; d <<= 1) {
                    const int u = __shfl_up(wv, d);
                    if (lane >= d) wv += u;
                }
                if (lane < 8) sm.wave8[lane] = wv;
            }
            __syncthreads();
            const int waveoff = (wid > 0) ? sm.wave8[wid - 1] : 0;
            sm.loff[i] = carry + waveoff + sc - v;
            const int chunk_tot = sm.wave8[7];
            __syncthreads();
            carry += chunk_tot;
        }

        for (int i = t; i < NB; i += 512) {
            const int c = sm.hist[i];
            if (c > 0) sm.base[i] = atomicAdd(&gcur[i], c);
        }
        __syncthreads();

        #pragma unroll
        for (int j = 0; j < 16; j++) {
            if (mt[j] >= 0) {
                const int b = mt[j] & 1023;
                const int pos = sm.loff[b] + (mt[j] >> 10);
                sm.pk[pos] = pk[j];
                sm.bkt[pos] = (unsigned short)b;
            }
        }
        __syncthreads();

        for (int i = t; i < tot; i += 512) {
            const int b = sm.bkt[i];
            const int p = sm.base[b] + (i - sm.loff[b]);
            if (p < CAP) pairs[b * CAP + p] = sm.pk[i];
        }
        return;
    }

    // ----------------- ENCODER PATH (8 nodes / block) -----------------
    EncSmem& sm = *reinterpret_cast<EncSmem*>(smem_raw);
    const int eb = blockIdx.x - NBIN;

    // fused prep (first 128 encoder blocks)
    if (eb < 128) {
        const int i = eb * 512 + t;
        Wb1[i] = f2bf(w_l1[i]);
        Wb2[i] = f2bf(w_l2[i]);
        Wb3[i] = f2bf(w_l3[i]);
        if (i < 40960) {   // Wg[256][160] = [w_rel|w_root|w_rel|w_root]
            const int m = i / 160, c = i % 160;
            const int k = c % 80;
            const float v = (k < 40) ? w_rel[m * 40 + k] : w_root[m * 40 + (k - 40)];
            Wg[i] = f2bf(v);
        }
        if (eb == 0 && t < 40) xh[(size_t)N * 40 + t] = __float2half(0.f);
    }

    if (t < 81) sm.w1[t] = w1[t];
    if (t >= 96 && t < 105) sm.b1v[t - 96] = b1[t - 96];
    if (t >= 128 && t < 155) sm.w2[t - 128] = w2[t - 128];
    if (t == 240) sm.b2v[0] = b2[0];
    __syncthreads();

    const int nb = eb * 8;

    // conv1: 8 nodes x 75 positions = 600 tasks over 2 passes
    #pragma unroll
    for (int pass = 0; pass < 2; pass++) {
        const int task = pass * 512 + t;
        if (task < 600) {
            const int ln = task / 75;
            const int p  = task % 75;
            const int n  = min(nb + ln, N - 1);
            const float* __restrict__ vin = views + (size_t)n * 453 + 2 * p;
            float e[3], o[3], e1[3];
            #pragma unroll
            for (int ic = 0; ic < 3; ic++) {
                const float* ci = vin + ic * 151;
                e[ic] = ci[0]; o[ic] = ci[1]; e1[ic] = ci[2];
            }
            const int didx = (p & 1) * 40 + (p >> 1);
            #pragma unroll
            for (int oc = 0; oc < 9; oc++) {
                float v = sm.b1v[oc];
                #pragma unroll
                for (int ic = 0; ic < 3; ic++)
                    v += sm.w1[oc * 9 + ic * 3 + 0] * e[ic]
                       + sm.w1[oc * 9 + ic * 3 + 1] * o[ic]
                       + sm.w1[oc * 9 + ic * 3 + 2] * e1[ic];
                sm.c1[ln][oc][didx] = lrelu(v);
            }
        }
    }
    __syncthreads();

    // conv2 + pose passthrough: 8 x 40 = 320 flat tasks
    if (t < 320) {
        const int ln = t / 40, f = t % 40;
        const int n  = min(nb + ln, N - 1);
        float outv;
        if (f < 3) {
            outv = pose[(size_t)n * 3 + f];
        } else {
            const int ow = f - 3;
            float v = sm.b2v[0];
            #pragma unroll
            for (int ic = 0; ic < 9; ic++)
                v += sm.w2[ic * 3 + 0] * sm.c1[ln][ic][ow]
                   + sm.w2[ic * 3 + 1] * sm.c1[ln][ic][40 + ow]
                   + sm.w2[ic * 3 + 2] * sm.c1[ln][ic][ow + 1];
            outv = lrelu(v);
        }
        const unsigned short hi = f2bf(outv);
        const unsigned short lo = f2bf(outv - bf2f(hi));
        xHi[(size_t)n * 40 + f] = hi;
        xLo[(size_t)n * 40 + f] = lo;
        xh[(size_t)n * 40 + f] = __float2half(outv);
    }
}

// ---------------------------------------------------------------------------
// Per-bucket exact counting sort (LDS only). Runs 24-aligned; pads = byte
// offset N*80 (zero row). sorted[] holds byte offsets src*80.
// ---------------------------------------------------------------------------
__global__ void bucket_sort_kernel(const int* __restrict__ gcur,
                                   const int* __restrict__ pairs,
                                   int* __restrict__ sorted,
                                   int* __restrict__ node_start,
                                   int* __restrict__ node_cnt, int N)
{
    __shared__ int s_cnt[64], s_off[64], s_cur[64];
    const int b = blockIdx.x;
    const int t = threadIdx.x;
    const int cnt = min(gcur[b], CAP);
    const int* __restrict__ pr = pairs + b * CAP;
    int* __restrict__ so = sorted + (size_t)b * CAP;

    if (t < 64) s_cnt[t] = 0;
    __syncthreads();
    for (int i = t; i < cnt; i += 256)
        atomicAdd(&s_cnt[pr[i] >> 22], 1);
    __syncthreads();

    if (t < 64) {   // exclusive scan of 24-aligned counts
        const int c = s_cnt[t];
        const int p = ((c + 23) / 24) * 24;
        int sc = p;
        #pragma unroll
        for (int d = 1; d < 64; d <<= 1) {
            const int u = __shfl_up(sc, d);
            if (t >= d) sc += u;
        }
        const int excl = sc - p;
        s_off[t] = excl;
        s_cur[t] = excl;
        node_start[b * 64 + t] = b * CAP + excl;
        node_cnt[b * 64 + t] = c;
    }
    __syncthreads();

    if (t < 64) {   // pad fill: sentinel byte offset N*80 (zero row in xh)
        const int e0 = s_off[t] + s_cnt[t];
        const int e1 = s_off[t] + ((s_cnt[t] + 23) / 24) * 24;
        for (int i = e0; i < e1 && i < CAP; i++) so[i] = N * 80;
    }
    for (int i = t; i < cnt; i += 256) {
        const int p = pr[i];
        const int pos = atomicAdd(&s_cur[p >> 22], 1);
        if (pos < CAP) so[pos] = p & 0x3FFFFF;
    }
}

// ---------------------------------------------------------------------------
// Segment sum: one wave per node, 6 edge-slots x 10 feature-quads, 8B uint2
// fp16 gathers, byte-offset indices. Writes agg as bf16 hi/lo directly.
// L2-transaction bound (2 lines per 80B row per edge) — structural floor.
// ---------------------------------------------------------------------------
__global__ void gather_sum_kernel(const int* __restrict__ sorted,
                                  const int* __restrict__ node_start,
                                  const int* __restrict__ node_cnt,
                                  const __half* __restrict__ xh,
                                  unsigned short* __restrict__ aggHi,
                                  unsigned short* __restrict__ aggLo, int N)
{
    const int n = blockIdx.x * 4 + (threadIdx.x >> 6);
    const int lane = threadIdx.x & 63;
    if (n >= N) return;

    const int start = node_start[n];
    const int cntp = ((node_cnt[n] + 23) / 24) * 24;
    const int slot = min(lane / 10, 5);          // lanes 60..63 duplicate slot 5
    const int f4 = lane % 10;                    // feature quad (4 halfs)
    const int* __restrict__ srt = sorted + start + slot;
    const char* __restrict__ xb = (const char*)xh + f4 * 8;

    float ax = 0.f, ay = 0.f, az = 0.f, aw = 0.f;
    for (int e = 0; e < cntp; e += 24) {
        const int o0 = srt[e];
        const int o1 = srt[e + 6];
        const int o2 = srt[e + 12];
        const int o3 = srt[e + 18];
        const uint2 u0 = *(const uint2*)(xb + o0);
        const uint2 u1 = *(const uint2*)(xb + o1);
        const uint2 u2 = *(const uint2*)(xb + o2);
        const uint2 u3 = *(const uint2*)(xb + o3);
        union { unsigned u; __half2 h; } c;
        float2 f;
        c.u = u0.x; f = __half22float2(c.h); ax += f.x; ay += f.y;
        c.u = u0.y; f = __half22float2(c.h); az += f.x; aw += f.y;
        c.u = u1.x; f = __half22float2(c.h); ax += f.x; ay += f.y;
        c.u = u1.y; f = __half22float2(c.h); az += f.x; aw += f.y;
        c.u = u2.x; f = __half22float2(c.h); ax += f.x; ay += f.y;
        c.u = u2.y; f = __half22float2(c.h); az += f.x; aw += f.y;
        c.u = u3.x; f = __half22float2(c.h); ax += f.x; ay += f.y;
        c.u = u3.y; f = __half22float2(c.h); az += f.x; aw += f.y;
    }

    float rx = ax, ry = ay, rz = az, rw = aw;
    #pragma unroll
    for (int s = 10; s <= 50; s += 10) {
        rx += __shfl(ax, f4 + s);
        ry += __shfl(ay, f4 + s);
        rz += __shfl(az, f4 + s);
        rw += __shfl(aw, f4 + s);
    }
    if (lane < 10) {
        ushort4 hi, lo;
        hi.x = f2bf(rx); lo.x = f2bf(rx - bf2f(hi.x));
        hi.y = f2bf(ry); lo.y = f2bf(ry - bf2f(hi.y));
        hi.z = f2bf(rz); lo.z = f2bf(rz - bf2f(hi.z));
        hi.w = f2bf(rw); lo.w = f2bf(rw - bf2f(hi.w));
        *(ushort4*)(aggHi + (size_t)n * 40 + f4 * 4) = hi;
        *(ushort4*)(aggLo + (size_t)n * 40 + f4 * 4) = lo;
    }
}

// ---------------------------------------------------------------------------
// FUSED GEMM chain: graphconv (K=160) -> mlp1 -> mlp2 -> mlp3+pred, all in
// one block per 64 rows. h stays in LDS between layers (zero global h
// traffic). Same per-layer bf16 rounding as the unfused version.
// ---------------------------------------------------------------------------
__device__ __forceinline__ void gemm_tile(const unsigned short* __restrict__ aT,
                                          const unsigned short* __restrict__ W,
                                          int wstride, int K,
                                          int wave, int l16, int q,
                                          f32x4 acc[4][4])
{
    for (int k0 = 0; k0 < K; k0 += 32) {
        short8 af[4], wf[4];
        #pragma unroll
        for (int nt = 0; nt < 4; nt++)
            af[nt] = *(const short8*)(aT + (nt * 16 + l16) * 264 + k0 + q * 8);
        #pragma unroll
        for (int mt = 0; mt < 4; mt++)
            wf[mt] = *(const short8*)(W + (wave * 64 + mt * 16 + l16) * wstride + k0 + q * 8);
        #pragma unroll
        for (int nt = 0; nt < 4; nt++)
            #pragma unroll
            for (int mt = 0; mt < 4; mt++)
                acc[nt][mt] = __builtin_amdgcn_mfma_f32_16x16x32_bf16(af[nt], wf[mt], acc[nt][mt], 0, 0, 0);
    }
}

__device__ __forceinline__ void epi_to_lds(f32x4 acc[4][4], const float* __restrict__ b,
                                           unsigned short* __restrict__ aT,
                                           int wave, int l16, int q)
{
    float bias[4];
    #pragma unroll
    for (int mt = 0; mt < 4; mt++) bias[mt] = b[wave * 64 + mt * 16 + l16];
    #pragma unroll
    for (int nt = 0; nt < 4; nt++)
        #pragma unroll
        for (int r = 0; r < 4; r++)
            #pragma unroll
            for (int mt = 0; mt < 4; mt++) {
                const int row = nt * 16 + q * 4 + r;         // C/D: row=quad*4+reg
                const int col = wave * 64 + mt * 16 + l16;   // C/D: col=lane&15
                aT[row * 264 + col] = f2bf(lrelu(acc[nt][mt][r] + bias[mt]));
            }
}

__global__ void fused_gemm_kernel(const unsigned short* __restrict__ aggHi,
                                  const unsigned short* __restrict__ aggLo,
                                  const unsigned short* __restrict__ xHi,
                                  const unsigned short* __restrict__ xLo,
                                  const unsigned short* __restrict__ Wg,
                                  const float* __restrict__ b_rel,
                                  const unsigned short* __restrict__ Wb1,
                                  const float* __restrict__ b_l1,
                                  const unsigned short* __restrict__ Wb2,
                                  const float* __restrict__ b_l2,
                                  const unsigned short* __restrict__ Wb3,
                                  const float* __restrict__ b_l3,
                                  const float* __restrict__ w_pred,
                                  const float* __restrict__ b_pred,
                                  float* __restrict__ out, int N)
{
    __shared__ __align__(16) unsigned short aT[64 * 264];   // 33 KB, reused per layer
    __shared__ float s_part[4][64];
    const int t = threadIdx.x;
    const int n0 = blockIdx.x * 64;
    const int wave = t >> 6, lane = t & 63, q = lane >> 4, l16 = lane & 15;

    // stage graphconv input: [aggHi|xHi|aggLo|xLo], row stride 264
    for (int u = t; u < 640; u += 256) {
        const int row = u / 10, c = (u % 10) * 4;
        const int srow = min(n0 + row, N - 1);
        const size_t off = (size_t)srow * 40 + c;
        unsigned short* rp = aT + row * 264;
        *(ushort4*)(rp + c)       = *(const ushort4*)(aggHi + off);
        *(ushort4*)(rp + 40 + c)  = *(const ushort4*)(xHi + off);
        *(ushort4*)(rp + 80 + c)  = *(const ushort4*)(aggLo + off);
        *(ushort4*)(rp + 120 + c) = *(const ushort4*)(xLo + off);
    }
    __syncthreads();

    // layer 0: graphconv, K=160
    {
        f32x4 acc[4][4] = {};
        gemm_tile(aT, Wg, 160, 160, wave, l16, q, acc);
        __syncthreads();
        epi_to_lds(acc, b_rel, aT, wave, l16, q);
        __syncthreads();
    }
    // layer 1
    {
        f32x4 acc[4][4] = {};
        gemm_tile(aT, Wb1, 256, 256, wave, l16, q, acc);
        __syncthreads();
        epi_to_lds(acc, b_l1, aT, wave, l16, q);
        __syncthreads();
    }
    // layer 2
    {
        f32x4 acc[4][4] = {};
        gemm_tile(aT, Wb2, 256, 256, wave, l16, q, acc);
        __syncthreads();
        epi_to_lds(acc, b_l2, aT, wave, l16, q);
        __syncthreads();
    }
    // layer 3 + pred epilogue (h3 never leaves registers)
    {
        f32x4 acc[4][4] = {};
        gemm_tile(aT, Wb3, 256, 256, wave, l16, q, acc);

        float bias[4], wp[4];
        #pragma unroll
        for (int mt = 0; mt < 4; mt++) {
            const int col = wave * 64 + mt * 16 + l16;
            bias[mt] = b_l3[col];
            wp[mt] = w_pred[col];
        }
        #pragma unroll
        for (int nt = 0; nt < 4; nt++)
            #pragma unroll
            for (int r = 0; r < 4; r++) {
                float p = 0.f;
                #pragma unroll
                for (int mt = 0; mt < 4; mt++)
                    p += lrelu(acc[nt][mt][r] + bias[mt]) * wp[mt];
                p += __shfl_xor(p, 1);
                p += __shfl_xor(p, 2);
                p += __shfl_xor(p, 4);
                p += __shfl_xor(p, 8);
                if (l16 == 0) s_part[wave][nt * 16 + q * 4 + r] = p;
            }
        __syncthreads();

        if (t < 64) {
            const int row = n0 + t;
            if (row < N)
                out[row] = s_part[0][t] + s_part[1][t] + s_part[2][t] + s_part[3][t] + b_pred[0];
        }
    }
}

// ---------------------------------------------------------------------------
extern "C" void kernel_launch(void* const* d_in, const int* in_sizes, int n_in,
                              void* d_out, int out_size, void* d_ws, size_t ws_size,
                              hipStream_t stream)
{
    const float* pose   = (const float*)d_in[0];
    const float* views  = (const float*)d_in[1];
    const int*   ei     = (const int*)d_in[2];
    const float* w_e1   = (const float*)d_in[3];
    const float* b_e1   = (const float*)d_in[4];
    const float* w_e2   = (const float*)d_in[5];
    const float* b_e2   = (const float*)d_in[6];
    const float* w_rel  = (const float*)d_in[7];
    const float* b_rel  = (const float*)d_in[8];
    const float* w_root = (const float*)d_in[9];
    const float* w_l1   = (const float*)d_in[10];
    const float* b_l1   = (const float*)d_in[11];
    const float* w_l2   = (const float*)d_in[12];
    const float* b_l2   = (const float*)d_in[13];
    const float* w_l3   = (const float*)d_in[14];
    const float* b_l3   = (const float*)d_in[15];
    const float* w_pred = (const float*)d_in[16];
    const float* b_pred = (const float*)d_in[17];
    float* out = (float*)d_out;

    const int N = in_sizes[0] / 3;        // 50000
    const int E = in_sizes[2] / 2;        // 4950000
    const int NB = (N + 63) >> 6;         // 782 buckets
    const int NBIN = (E + EPB - 1) / EPB; // 605 bin blocks
    const int ENCB = (N + 7) / 8;         // 6250 encoder blocks
    const int NBLK = (N + 63) / 64;       // 782 GEMM row blocks

    // Workspace layout (no h buffers needed — GEMM chain keeps h in LDS)
    unsigned short* xHi = (unsigned short*)d_ws;     // N*40 bf16
    unsigned short* xLo = xHi + (size_t)N * 40;      // N*40 bf16
    unsigned short* aggHi = xLo + (size_t)N * 40;    // N*40 bf16
    unsigned short* aggLo = aggHi + (size_t)N * 40;  // N*40 bf16
    __half* xh = (__half*)(aggLo + (size_t)N * 40);  // (N+1)*40 fp16; row N = 0
    int* pairs  = (int*)(xh + (size_t)(N + 1) * 40 + 24);   // NB*CAP ints
    int* sorted = pairs + (size_t)NB * CAP;          // NB*CAP ints
    int* gcur       = sorted + (size_t)NB * CAP;     // 1024
    int* node_start = gcur + 1024;                   // NB*64
    int* node_cnt   = node_start + NB * 64;          // NB*64
    unsigned short* Wb1 = (unsigned short*)(node_cnt + NB * 64);  // 256*256
    unsigned short* Wb2 = Wb1 + 256 * 256;
    unsigned short* Wb3 = Wb2 + 256 * 256;
    unsigned short* Wg  = Wb3 + 256 * 256;           // 256*160

    hipMemsetAsync(gcur, 0, 1024 * sizeof(int), stream);

    enc_bin_kernel<<<NBIN + ENCB, 512, 0, stream>>>(
        ei, gcur, pairs, E, NB, NBIN,
        pose, views, w_e1, b_e1, w_e2, b_e2,
        w_l1, w_l2, w_l3, w_rel, w_root,
        Wb1, Wb2, Wb3, Wg,
        xHi, xLo, xh, N);

    bucket_sort_kernel<<<NB, 256, 0, stream>>>(gcur, pairs, sorted, node_start, node_cnt, N);
    gather_sum_kernel<<<NB * 16, 256, 0, stream>>>(sorted, node_start, node_cnt, xh, aggHi, aggLo, N);

    fused_gemm_kernel<<<NBLK, 256, 0, stream>>>(
        aggHi, aggLo, xHi, xLo, Wg, b_rel,
        Wb1, b_l1, Wb2, b_l2, Wb3, b_l3,
        w_pred, b_pred, out, N);
}

// Round 14
// 342.875 us; speedup vs baseline: 6.1496x; 1.0803x over previous
//
#include <hip/hip_runtime.h>
#include <hip/hip_fp16.h>

#define NEG_SLOPE 0.1f
__device__ __forceinline__ float lrelu(float v) { return fmaxf(v, NEG_SLOPE * v); }

constexpr int CAP = 8704;   // per-bucket capacity (mean 6330 + 24-align pads)
constexpr int EPB = 8192;   // edges per bin block (16 per thread, 512 threads)

typedef __attribute__((ext_vector_type(8))) short short8;   // 8 bf16 (4 VGPRs)
typedef __attribute__((ext_vector_type(4))) float f32x4;    // MFMA accum

__device__ __forceinline__ unsigned short f2bf(float f) {   // RNE
    union { float f; unsigned u; } v; v.f = f;
    const unsigned r = v.u + 0x7FFF + ((v.u >> 16) & 1);
    return (unsigned short)(r >> 16);
}
__device__ __forceinline__ float bf2f(unsigned short h) {
    union { unsigned u; float f; } v; v.u = ((unsigned)h) << 16;
    return v.f;
}

// ---------------------------------------------------------------------------
// Encoder (+fused prep in blocks 0..255): 4 nodes per 256-thread block,
// 12 KB LDS (high occupancy — do NOT fuse with bin: its 60 KB LDS halves
// encoder occupancy, measured +22 µs in r13). Prep: bf16 weight conversions,
// Wg build, gcur zero, xh sentinel row.
// ---------------------------------------------------------------------------
__global__ __launch_bounds__(256) void encoder_kernel(
        const float* __restrict__ pose,
        const float* __restrict__ views,
        const float* __restrict__ w1, const float* __restrict__ b1,
        const float* __restrict__ w2, const float* __restrict__ b2,
        const float* __restrict__ w_l1, const float* __restrict__ w_l2,
        const float* __restrict__ w_l3, const float* __restrict__ w_rel,
        const float* __restrict__ w_root,
        unsigned short* __restrict__ Wb1, unsigned short* __restrict__ Wb2,
        unsigned short* __restrict__ Wb3, unsigned short* __restrict__ Wg,
        int* __restrict__ gcur,
        unsigned short* __restrict__ xHi, unsigned short* __restrict__ xLo,
        __half* __restrict__ xh, int N)
{
    __shared__ float s_w1[81];
    __shared__ float s_b1[9];
    __shared__ float s_w2[27];
    __shared__ float s_b2[1];
    __shared__ float s_c1[4][9][80];   // [lnode][oc][(p&1)*40 + (p>>1)]

    const int t = threadIdx.x;

    // fused prep (first 256 blocks); runs before bin in stream order
    if (blockIdx.x < 256) {
        const int i = blockIdx.x * 256 + t;
        Wb1[i] = f2bf(w_l1[i]);
        Wb2[i] = f2bf(w_l2[i]);
        Wb3[i] = f2bf(w_l3[i]);
        if (i < 40960) {   // Wg[256][160] = [w_rel|w_root|w_rel|w_root]
            const int m = i / 160, c = i % 160;
            const int k = c % 80;
            const float v = (k < 40) ? w_rel[m * 40 + k] : w_root[m * 40 + (k - 40)];
            Wg[i] = f2bf(v);
        }
        if (i < 1024) gcur[i] = 0;
        if (i < 40) xh[(size_t)N * 40 + i] = __float2half(0.f);
    }

    if (t < 81) s_w1[t] = w1[t];
    if (t >= 96 && t < 105) s_b1[t - 96] = b1[t - 96];
    if (t >= 128 && t < 155) s_w2[t - 128] = w2[t - 128];
    if (t == 240) s_b2[0] = b2[0];
    __syncthreads();

    const int nb = blockIdx.x * 4;

    // conv1: 300 flat (node,pos) tasks over 2 passes (pass 2: waves 1-3 execz)
    #pragma unroll
    for (int pass = 0; pass < 2; pass++) {
        const int task = pass * 256 + t;
        if (task < 300) {
            const int ln = task / 75;
            const int p  = task % 75;
            const int n  = min(nb + ln, N - 1);
            const float* __restrict__ vin = views + (size_t)n * 453 + 2 * p;
            float e[3], o[3], e1[3];
            #pragma unroll
            for (int ic = 0; ic < 3; ic++) {
                const float* ci = vin + ic * 151;
                e[ic] = ci[0]; o[ic] = ci[1]; e1[ic] = ci[2];
            }
            const int didx = (p & 1) * 40 + (p >> 1);
            #pragma unroll
            for (int oc = 0; oc < 9; oc++) {
                float v = s_b1[oc];
                #pragma unroll
                for (int ic = 0; ic < 3; ic++)
                    v += s_w1[oc * 9 + ic * 3 + 0] * e[ic]
                       + s_w1[oc * 9 + ic * 3 + 1] * o[ic]
                       + s_w1[oc * 9 + ic * 3 + 2] * e1[ic];
                s_c1[ln][oc][didx] = lrelu(v);
            }
        }
    }
    __syncthreads();

    // conv2 + pose passthrough: 160 flat tasks, coalesced stores
    if (t < 160) {
        const int ln = t / 40, f = t % 40;
        const int n  = min(nb + ln, N - 1);
        float outv;
        if (f < 3) {
            outv = pose[(size_t)n * 3 + f];
        } else {
            const int ow = f - 3;
            float v = s_b2[0];
            #pragma unroll
            for (int ic = 0; ic < 9; ic++)
                v += s_w2[ic * 3 + 0] * s_c1[ln][ic][ow]
                   + s_w2[ic * 3 + 1] * s_c1[ln][ic][40 + ow]
                   + s_w2[ic * 3 + 2] * s_c1[ln][ic][ow + 1];
            outv = lrelu(v);
        }
        const unsigned short hi = f2bf(outv);
        const unsigned short lo = f2bf(outv - bf2f(hi));
        xHi[(size_t)n * 40 + f] = hi;
        xLo[(size_t)n * 40 + f] = lo;
        xh[(size_t)n * 40 + f] = __float2half(outv);
    }
}

// ---------------------------------------------------------------------------
// Coarse binning (512 thr, 8192 edges/block): rank via LDS histogram, stage
// bucket-ordered in LDS, linear write-out. Packed entry = src*80 | dloc<<22.
// ---------------------------------------------------------------------------
__global__ __launch_bounds__(512) void bin_kernel(
        const int* __restrict__ ei, int* __restrict__ gcur,
        int* __restrict__ pairs, int E, int NB)
{
    __shared__ int s_hist[1024];
    __shared__ int s_loff[1024];
    __shared__ int s_base[1024];
    __shared__ int s_wave8[8];
    __shared__ int s_pk[EPB];                 // 32 KB
    __shared__ unsigned short s_bkt[EPB];     // 16 KB
    const int t = threadIdx.x;
    const int lane = t & 63, wid = t >> 6;    // 8 waves
    const int e0 = blockIdx.x * EPB + t * 16;
    const int tot = min(E - (int)blockIdx.x * EPB, EPB);

    for (int i = t; i < 1024; i += 512) s_hist[i] = 0;
    __syncthreads();

    int pk[16], mt[16];
    auto proc = [&](int j, int sv, int dv) {
        const int b = dv >> 6;
        const int r = atomicAdd(&s_hist[b], 1);
        pk[j] = sv * 80 | ((dv & 63) << 22);
        mt[j] = b | (r << 10);
    };

    if (e0 + 16 <= E) {
        #pragma unroll
        for (int q = 0; q < 4; q++) {
            const int4 sv = *(const int4*)(ei + e0 + 4 * q);
            const int4 dv = *(const int4*)(ei + E + e0 + 4 * q);
            proc(4 * q + 0, sv.x, dv.x);
            proc(4 * q + 1, sv.y, dv.y);
            proc(4 * q + 2, sv.z, dv.z);
            proc(4 * q + 3, sv.w, dv.w);
        }
    } else {
        #pragma unroll
        for (int j = 0; j < 16; j++) {
            mt[j] = -1;
            const int e = e0 + j;
            if (e < E) proc(j, ei[e], ei[E + e]);
        }
    }
    __syncthreads();

    // exclusive scan of s_hist[0..1023] -> s_loff
    int carry = 0;
    #pragma unroll
    for (int base = 0; base < 1024; base += 512) {
        const int i = base + t;
        const int v = s_hist[i];
        int sc = v;
        #pragma unroll
        for (int d = 1; d < 64; d <<= 1) {
            const int u = __shfl_up(sc, d);
            if (lane >= d) sc += u;
        }
        if (lane == 63) s_wave8[wid] = sc;
        __syncthreads();
        if (wid == 0) {
            int wv = (lane < 8) ? s_wave8[lane] : 0;
            #pragma unroll
            for (int d = 1; d < 8; d <<= 1) {
                const int u = __shfl_up(wv, d);
                if (lane >= d) wv += u;
            }
            if (lane < 8) s_wave8[lane] = wv;
        }
        __syncthreads();
        const int waveoff = (wid > 0) ? s_wave8[wid - 1] : 0;
        s_loff[i] = carry + waveoff + sc - v;
        const int chunk_tot = s_wave8[7];
        __syncthreads();
        carry += chunk_tot;
    }

    for (int i = t; i < NB; i += 512) {
        const int c = s_hist[i];
        if (c > 0) s_base[i] = atomicAdd(&gcur[i], c);
    }
    __syncthreads();

    #pragma unroll
    for (int j = 0; j < 16; j++) {
        if (mt[j] >= 0) {
            const int b = mt[j] & 1023;
            const int pos = s_loff[b] + (mt[j] >> 10);
            s_pk[pos] = pk[j];
            s_bkt[pos] = (unsigned short)b;
        }
    }
    __syncthreads();

    for (int i = t; i < tot; i += 512) {
        const int b = s_bkt[i];
        const int p = s_base[b] + (i - s_loff[b]);
        if (p < CAP) pairs[b * CAP + p] = s_pk[i];
    }
}

// ---------------------------------------------------------------------------
// FUSED per-bucket sort + gather (512 thr, one block per bucket): counting
// sort scatters byte-offset edges into an LDS sorted list (runs 24-aligned,
// sentinel N*80 = zero row), then 8 waves gather 8 nodes each with the
// 6-slot x 10-quad fp16 layout. Eliminates the global sorted round-trip.
// ---------------------------------------------------------------------------
__global__ __launch_bounds__(512) void sort_gather_kernel(
        const int* __restrict__ gcur,
        const int* __restrict__ pairs,
        const __half* __restrict__ xh,
        unsigned short* __restrict__ aggHi,
        unsigned short* __restrict__ aggLo, int N)
{
    __shared__ int s_sorted[CAP];             // 34.8 KB
    __shared__ int s_cnt[64], s_off[64], s_cur[64];
    const int b = blockIdx.x;
    const int t = threadIdx.x;
    const int cnt = min(gcur[b], CAP);
    const int* __restrict__ pr = pairs + (size_t)b * CAP;

    if (t < 64) s_cnt[t] = 0;
    __syncthreads();
    for (int i = t; i < cnt; i += 512)
        atomicAdd(&s_cnt[pr[i] >> 22], 1);
    __syncthreads();

    if (t < 64) {   // wave 0: exclusive scan of 24-aligned counts
        const int c = s_cnt[t];
        const int p = ((c + 23) / 24) * 24;
        int sc = p;
        #pragma unroll
        for (int d = 1; d < 64; d <<= 1) {
            const int u = __shfl_up(sc, d);
            if (t >= d) sc += u;
        }
        const int excl = sc - p;
        s_off[t] = excl;
        s_cur[t] = excl;
    }
    __syncthreads();

    if (t < 64) {   // pad fill: sentinel byte offset N*80 (zero row in xh)
        const int e0 = s_off[t] + s_cnt[t];
        const int e1 = s_off[t] + ((s_cnt[t] + 23) / 24) * 24;
        for (int i = e0; i < e1 && i < CAP; i++) s_sorted[i] = N * 80;
    }
    for (int i = t; i < cnt; i += 512) {
        const int p = pr[i];
        const int pos = atomicAdd(&s_cur[p >> 22], 1);
        if (pos < CAP) s_sorted[pos] = p & 0x3FFFFF;
    }
    __syncthreads();

    // gather: wave w handles local nodes w*8 .. w*8+7
    const int wave = t >> 6, lane = t & 63;
    const int slot = min(lane / 10, 5);       // lanes 60..63 duplicate slot 5
    const int f4 = lane % 10;                 // feature quad (4 halfs)
    const char* __restrict__ xb = (const char*)xh + f4 * 8;

    #pragma unroll 1
    for (int i = 0; i < 8; i++) {
        const int ln = wave * 8 + i;
        const int n = b * 64 + ln;
        if (n >= N) break;                    // wave-uniform
        const int c = s_cnt[ln];
        const int cntp = ((c + 23) / 24) * 24;
        const int* __restrict__ srt = s_sorted + s_off[ln] + slot;

        float ax = 0.f, ay = 0.f, az = 0.f, aw = 0.f;
        for (int e = 0; e < cntp; e += 24) {
            const int o0 = srt[e];
            const int o1 = srt[e + 6];
            const int o2 = srt[e + 12];
            const int o3 = srt[e + 18];
            const uint2 u0 = *(const uint2*)(xb + o0);
            const uint2 u1 = *(const uint2*)(xb + o1);
            const uint2 u2 = *(const uint2*)(xb + o2);
            const uint2 u3 = *(const uint2*)(xb + o3);
            union { unsigned u; __half2 h; } cv;
            float2 f;
            cv.u = u0.x; f = __half22float2(cv.h); ax += f.x; ay += f.y;
            cv.u = u0.y; f = __half22float2(cv.h); az += f.x; aw += f.y;
            cv.u = u1.x; f = __half22float2(cv.h); ax += f.x; ay += f.y;
            cv.u = u1.y; f = __half22float2(cv.h); az += f.x; aw += f.y;
            cv.u = u2.x; f = __half22float2(cv.h); ax += f.x; ay += f.y;
            cv.u = u2.y; f = __half22float2(cv.h); az += f.x; aw += f.y;
            cv.u = u3.x; f = __half22float2(cv.h); ax += f.x; ay += f.y;
            cv.u = u3.y; f = __half22float2(cv.h); az += f.x; aw += f.y;
        }

        float rx = ax, ry = ay, rz = az, rw = aw;
        #pragma unroll
        for (int s = 10; s <= 50; s += 10) {
            rx += __shfl(ax, f4 + s);
            ry += __shfl(ay, f4 + s);
            rz += __shfl(az, f4 + s);
            rw += __shfl(aw, f4 + s);
        }
        if (lane < 10) {
            ushort4 hi, lo;
            hi.x = f2bf(rx); lo.x = f2bf(rx - bf2f(hi.x));
            hi.y = f2bf(ry); lo.y = f2bf(ry - bf2f(hi.y));
            hi.z = f2bf(rz); lo.z = f2bf(rz - bf2f(hi.z));
            hi.w = f2bf(rw); lo.w = f2bf(rw - bf2f(hi.w));
            *(ushort4*)(aggHi + (size_t)n * 40 + f4 * 4) = hi;
            *(ushort4*)(aggLo + (size_t)n * 40 + f4 * 4) = lo;
        }
    }
}

// ---------------------------------------------------------------------------
// FUSED GEMM chain: graphconv (K=160) -> mlp1 -> mlp2 -> mlp3+pred, one
// block per 64 rows; h stays in LDS between layers.
// ---------------------------------------------------------------------------
__device__ __forceinline__ void gemm_tile(const unsigned short* __restrict__ aT,
                                          const unsigned short* __restrict__ W,
                                          int wstride, int K,
                                          int wave, int l16, int q,
                                          f32x4 acc[4][4])
{
    for (int k0 = 0; k0 < K; k0 += 32) {
        short8 af[4], wf[4];
        #pragma unroll
        for (int nt = 0; nt < 4; nt++)
            af[nt] = *(const short8*)(aT + (nt * 16 + l16) * 264 + k0 + q * 8);
        #pragma unroll
        for (int mt = 0; mt < 4; mt++)
            wf[mt] = *(const short8*)(W + (wave * 64 + mt * 16 + l16) * wstride + k0 + q * 8);
        #pragma unroll
        for (int nt = 0; nt < 4; nt++)
            #pragma unroll
            for (int mt = 0; mt < 4; mt++)
                acc[nt][mt] = __builtin_amdgcn_mfma_f32_16x16x32_bf16(af[nt], wf[mt], acc[nt][mt], 0, 0, 0);
    }
}

__device__ __forceinline__ void epi_to_lds(f32x4 acc[4][4], const float* __restrict__ b,
                                           unsigned short* __restrict__ aT,
                                           int wave, int l16, int q)
{
    float bias[4];
    #pragma unroll
    for (int mt = 0; mt < 4; mt++) bias[mt] = b[wave * 64 + mt * 16 + l16];
    #pragma unroll
    for (int nt = 0; nt < 4; nt++)
        #pragma unroll
        for (int r = 0; r < 4; r++)
            #pragma unroll
            for (int mt = 0; mt < 4; mt++) {
                const int row = nt * 16 + q * 4 + r;         // C/D: row=quad*4+reg
                const int col = wave * 64 + mt * 16 + l16;   // C/D: col=lane&15
                aT[row * 264 + col] = f2bf(lrelu(acc[nt][mt][r] + bias[mt]));
            }
}

__global__ void fused_gemm_kernel(const unsigned short* __restrict__ aggHi,
                                  const unsigned short* __restrict__ aggLo,
                                  const unsigned short* __restrict__ xHi,
                                  const unsigned short* __restrict__ xLo,
                                  const unsigned short* __restrict__ Wg,
                                  const float* __restrict__ b_rel,
                                  const unsigned short* __restrict__ Wb1,
                                  const float* __restrict__ b_l1,
                                  const unsigned short* __restrict__ Wb2,
                                  const float* __restrict__ b_l2,
                                  const unsigned short* __restrict__ Wb3,
                                  const float* __restrict__ b_l3,
                                  const float* __restrict__ w_pred,
                                  const float* __restrict__ b_pred,
                                  float* __restrict__ out, int N)
{
    __shared__ __align__(16) unsigned short aT[64 * 264];   // 33 KB, reused per layer
    __shared__ float s_part[4][64];
    const int t = threadIdx.x;
    const int n0 = blockIdx.x * 64;
    const int wave = t >> 6, lane = t & 63, q = lane >> 4, l16 = lane & 15;

    for (int u = t; u < 640; u += 256) {
        const int row = u / 10, c = (u % 10) * 4;
        const int srow = min(n0 + row, N - 1);
        const size_t off = (size_t)srow * 40 + c;
        unsigned short* rp = aT + row * 264;
        *(ushort4*)(rp + c)       = *(const ushort4*)(aggHi + off);
        *(ushort4*)(rp + 40 + c)  = *(const ushort4*)(xHi + off);
        *(ushort4*)(rp + 80 + c)  = *(const ushort4*)(aggLo + off);
        *(ushort4*)(rp + 120 + c) = *(const ushort4*)(xLo + off);
    }
    __syncthreads();

    {   // layer 0: graphconv, K=160
        f32x4 acc[4][4] = {};
        gemm_tile(aT, Wg, 160, 160, wave, l16, q, acc);
        __syncthreads();
        epi_to_lds(acc, b_rel, aT, wave, l16, q);
        __syncthreads();
    }
    {   // layer 1
        f32x4 acc[4][4] = {};
        gemm_tile(aT, Wb1, 256, 256, wave, l16, q, acc);
        __syncthreads();
        epi_to_lds(acc, b_l1, aT, wave, l16, q);
        __syncthreads();
    }
    {   // layer 2
        f32x4 acc[4][4] = {};
        gemm_tile(aT, Wb2, 256, 256, wave, l16, q, acc);
        __syncthreads();
        epi_to_lds(acc, b_l2, aT, wave, l16, q);
        __syncthreads();
    }
    {   // layer 3 + pred epilogue (h3 never leaves registers)
        f32x4 acc[4][4] = {};
        gemm_tile(aT, Wb3, 256, 256, wave, l16, q, acc);

        float bias[4], wp[4];
        #pragma unroll
        for (int mt = 0; mt < 4; mt++) {
            const int col = wave * 64 + mt * 16 + l16;
            bias[mt] = b_l3[col];
            wp[mt] = w_pred[col];
        }
        #pragma unroll
        for (int nt = 0; nt < 4; nt++)
            #pragma unroll
            for (int r = 0; r < 4; r++) {
                float p = 0.f;
                #pragma unroll
                for (int mt = 0; mt < 4; mt++)
                    p += lrelu(acc[nt][mt][r] + bias[mt]) * wp[mt];
                p += __shfl_xor(p, 1);
                p += __shfl_xor(p, 2);
                p += __shfl_xor(p, 4);
                p += __shfl_xor(p, 8);
                if (l16 == 0) s_part[wave][nt * 16 + q * 4 + r] = p;
            }
        __syncthreads();

        if (t < 64) {
            const int row = n0 + t;
            if (row < N)
                out[row] = s_part[0][t] + s_part[1][t] + s_part[2][t] + s_part[3][t] + b_pred[0];
        }
    }
}

// ---------------------------------------------------------------------------
extern "C" void kernel_launch(void* const* d_in, const int* in_sizes, int n_in,
                              void* d_out, int out_size, void* d_ws, size_t ws_size,
                              hipStream_t stream)
{
    const float* pose   = (const float*)d_in[0];
    const float* views  = (const float*)d_in[1];
    const int*   ei     = (const int*)d_in[2];
    const float* w_e1   = (const float*)d_in[3];
    const float* b_e1   = (const float*)d_in[4];
    const float* w_e2   = (const float*)d_in[5];
    const float* b_e2   = (const float*)d_in[6];
    const float* w_rel  = (const float*)d_in[7];
    const float* b_rel  = (const float*)d_in[8];
    const float* w_root = (const float*)d_in[9];
    const float* w_l1   = (const float*)d_in[10];
    const float* b_l1   = (const float*)d_in[11];
    const float* w_l2   = (const float*)d_in[12];
    const float* b_l2   = (const float*)d_in[13];
    const float* w_l3   = (const float*)d_in[14];
    const float* b_l3   = (const float*)d_in[15];
    const float* w_pred = (const float*)d_in[16];
    const float* b_pred = (const float*)d_in[17];
    float* out = (float*)d_out;

    const int N = in_sizes[0] / 3;        // 50000
    const int E = in_sizes[2] / 2;        // 4950000
    const int NB = (N + 63) >> 6;         // 782 buckets
    const int NBLK = (N + 63) / 64;       // 782 GEMM row blocks

    // Workspace layout (no sorted / node_start / node_cnt / h buffers)
    unsigned short* xHi = (unsigned short*)d_ws;     // N*40 bf16
    unsigned short* xLo = xHi + (size_t)N * 40;      // N*40 bf16
    unsigned short* aggHi = xLo + (size_t)N * 40;    // N*40 bf16
    unsigned short* aggLo = aggHi + (size_t)N * 40;  // N*40 bf16
    __half* xh = (__half*)(aggLo + (size_t)N * 40);  // (N+1)*40 fp16; row N = 0
    int* pairs = (int*)(xh + (size_t)(N + 1) * 40 + 24);   // NB*CAP ints
    int* gcur  = pairs + (size_t)NB * CAP;           // 1024
    unsigned short* Wb1 = (unsigned short*)(gcur + 1024);  // 256*256
    unsigned short* Wb2 = Wb1 + 256 * 256;
    unsigned short* Wb3 = Wb2 + 256 * 256;
    unsigned short* Wg  = Wb3 + 256 * 256;           // 256*160

    encoder_kernel<<<(N + 3) / 4, 256, 0, stream>>>(
        pose, views, w_e1, b_e1, w_e2, b_e2,
        w_l1, w_l2, w_l3, w_rel, w_root,
        Wb1, Wb2, Wb3, Wg, gcur, xHi, xLo, xh, N);

    bin_kernel<<<(E + EPB - 1) / EPB, 512, 0, stream>>>(ei, gcur, pairs, E, NB);

    sort_gather_kernel<<<NB, 512, 0, stream>>>(gcur, pairs, xh, aggHi, aggLo, N);

    fused_gemm_kernel<<<NBLK, 256, 0, stream>>>(
        aggHi, aggLo, xHi, xLo, Wg, b_rel,
        Wb1, b_l1, Wb2, b_l2, Wb3, b_l3,
        w_pred, b_pred, out, N);
}